// Round 1
// 633.851 us; speedup vs baseline: 1.0559x; 1.0559x over previous
//
#include <hip/hip_runtime.h>
#include <hip/hip_bf16.h>

using bf16 = __hip_bfloat16;

#define D_DIM   192
#define N_DIM   3072
#define NHEAD   4
#define T_SEQ   1024
#define HN      12288      // NHEAD * N_DIM
#define NP2     1536       // N_DIM/2
#define VOCABSZ 256
#define NLAYER  4
#define LN_EPS  1e-5f
#define TWO_PI  6.2831853071795864f

typedef __attribute__((ext_vector_type(8))) short          s16x8;
typedef __attribute__((ext_vector_type(8))) unsigned short u16x8;
typedef __attribute__((ext_vector_type(4))) float          f32x4;

__device__ __forceinline__ float b2f(bf16 v) { return __bfloat162float(v); }
__device__ __forceinline__ float us2f(unsigned short u) {
    unsigned int x = ((unsigned int)u) << 16;
    return __builtin_bit_cast(float, x);
}
__device__ __forceinline__ unsigned short f2us(float f) {
    bf16 b = __float2bfloat16(f);
    return __builtin_bit_cast(unsigned short, b);
}

// sentinel: encode ws_size into output (fires only if ws too small)
__global__ void fill_out(float* __restrict__ out, float val, int nelem) {
    int i = blockIdx.x * 256 + threadIdx.x;
    if (i < nelem) out[i] = val;
}

// ---------------------------------------------------------------------------
// Tiled transpose + fp32->bf16: in fp32 [R][C] -> out bf16 [C][R].
// ---------------------------------------------------------------------------
__global__ void t_cvt(const float* __restrict__ in, bf16* __restrict__ out,
                      int R, int C, long inZ, long outZ) {
    __shared__ float tile[64][65];
    in  += inZ  * blockIdx.z;
    out += outZ * blockIdx.z;
    const int tx = threadIdx.x & 63, ty = threadIdx.x >> 6;
    const int r0 = blockIdx.y * 64, c0 = blockIdx.x * 64;
    #pragma unroll
    for (int rr = 0; rr < 16; rr++) {
        int row = ty * 16 + rr;
        tile[row][tx] = in[(size_t)(r0 + row) * C + c0 + tx];
    }
    __syncthreads();
    #pragma unroll
    for (int rr = 0; rr < 16; rr++) {
        int row = ty * 16 + rr;
        out[(size_t)(c0 + row) * R + r0 + tx] = __float2bfloat16(tile[tx][row]);
    }
}

// ---------------------------------------------------------------------------
// Wave-per-row LN family (64 threads/block, 3 elems/lane, butterfly reduce)
// ---------------------------------------------------------------------------
__device__ __forceinline__ void wave_sum2(float& s, float& ss) {
    #pragma unroll
    for (int off = 1; off < 64; off <<= 1) {
        s  += __shfl_xor(s,  off, 64);
        ss += __shfl_xor(ss, off, 64);
    }
}

__global__ void k_embed(const int* __restrict__ idx, const float* __restrict__ emb,
                        const float* __restrict__ pos, float* __restrict__ x) {
    int t = blockIdx.x, l = threadIdx.x;
    int tok = idx[t];
    const float* e = emb + tok * D_DIM;
    const float* p = pos + t * D_DIM;
    float v0 = e[l] + p[l], v1 = e[l + 64] + p[l + 64], v2 = e[l + 128] + p[l + 128];
    float s = v0 + v1 + v2, ss = v0 * v0 + v1 * v1 + v2 * v2;
    wave_sum2(s, ss);
    float m = s / D_DIM, r = rsqrtf(ss / D_DIM - m * m + LN_EPS);
    float* xr = x + t * D_DIM;
    xr[l] = (v0 - m) * r; xr[l + 64] = (v1 - m) * r; xr[l + 128] = (v2 - m) * r;
}

__global__ void k_ln(float* __restrict__ buf) {
    int l = threadIdx.x;
    float* row = buf + (size_t)blockIdx.x * D_DIM;
    float v0 = row[l], v1 = row[l + 64], v2 = row[l + 128];
    float s = v0 + v1 + v2, ss = v0 * v0 + v1 * v1 + v2 * v2;
    wave_sum2(s, ss);
    float m = s / D_DIM, r = rsqrtf(ss / D_DIM - m * m + LN_EPS);
    row[l] = (v0 - m) * r; row[l + 64] = (v1 - m) * r; row[l + 128] = (v2 - m) * r;
}

// x = LN(x + LN(sum of 8 split-K partial slabs))
__global__ void k_resid8(float* __restrict__ x, const float* __restrict__ P) {
    int l = threadIdx.x, t = blockIdx.x;
    float y0 = 0.f, y1 = 0.f, y2 = 0.f;
    #pragma unroll
    for (int p = 0; p < 8; p++) {
        const float* r = P + (size_t)p * T_SEQ * D_DIM + (size_t)t * D_DIM;
        y0 += r[l]; y1 += r[l + 64]; y2 += r[l + 128];
    }
    float* xr = x + (size_t)t * D_DIM;
    float s = y0 + y1 + y2, ss = y0 * y0 + y1 * y1 + y2 * y2;
    wave_sum2(s, ss);
    float m1 = s / D_DIM, r1 = rsqrtf(ss / D_DIM - m1 * m1 + LN_EPS);
    float v0 = xr[l] + (y0 - m1) * r1;
    float v1 = xr[l + 64] + (y1 - m1) * r1;
    float v2 = xr[l + 128] + (y2 - m1) * r1;
    s = v0 + v1 + v2; ss = v0 * v0 + v1 * v1 + v2 * v2;
    wave_sum2(s, ss);
    float m2 = s / D_DIM, r2 = rsqrtf(ss / D_DIM - m2 * m2 + LN_EPS);
    xr[l] = (v0 - m2) * r2; xr[l + 64] = (v1 - m2) * r2; xr[l + 128] = (v2 - m2) * r2;
}

// RoPE cos/sin tables, interleaved bf16 pairs csT[t][p] = (cos, sin)
__global__ void k_tables(ushort2* __restrict__ csT) {
    int gid = blockIdx.x * 256 + threadIdx.x;
    int t = gid / NP2, p = gid % NP2;
    float qf = (float)(2 * p);
    float f = 1.0f / powf(65536.0f, qf / 3072.0f) / (float)TWO_PI;
    float ph = fmodf((float)t * f, 1.0f) * (float)TWO_PI;
    ushort2 cs;
    cs.x = f2us(cosf(ph));
    cs.y = f2us(sinf(ph));
    csT[gid] = cs;
}

// ---------------------------------------------------------------------------
// scores64: sc[h,t,s] = dot(qr[t,h], qr[s,h]) for s<t, else 0.
// 64x64 tile, 4 waves x (32x32), BK=32, triangular grid (136 tiles/head),
// double-buffered LDS pipeline, register prefetch, ONE barrier per K-iter.
// Replaces 128x128 scores128: 144 -> 544 workgroups (2.1 blocks/CU) to fix
// the 5.5% occupancy / 8.9% MfmaUtil latency pathology.
// ---------------------------------------------------------------------------
__launch_bounds__(256)
__global__ void scores64(const bf16* __restrict__ qr, bf16* __restrict__ sc) {
    const int h = blockIdx.z;
    int L = blockIdx.x;
    int i = 0;
    while (((i + 1) * (i + 2)) >> 1 <= L) ++i;
    int j = L - ((i * (i + 1)) >> 1);
    const int t0 = i * 64, s0 = j * 64;

    __shared__ short As[2][64][40];
    __shared__ short Bs[2][64][40];

    const int tid = threadIdx.x;
    const int lane = tid & 63, w = tid >> 6, qd = lane >> 4, lc = lane & 15;
    const int wtm = (w >> 1) * 32, wtn = (w & 1) * 32;
    const int r0 = tid >> 2;                     // staging row 0..63
    const int kq = (tid & 3) * 8;                // staging k-offset

    const bf16* gA = qr + (size_t)(t0 + r0) * HN + h * N_DIM + kq;
    const bf16* gB = qr + (size_t)(s0 + r0) * HN + h * N_DIM + kq;

    u16x8 pa, pb;
    auto prefetch = [&](int k0) {
        pa = *(const u16x8*)(gA + k0);
        pb = *(const u16x8*)(gB + k0);
    };
    auto deposit = [&](int buf) {
        *(u16x8*)&As[buf][r0][kq] = pa;
        *(u16x8*)&Bs[buf][r0][kq] = pb;
    };

    f32x4 acc[2][2] = {};

    prefetch(0);
    deposit(0);
    __syncthreads();

    const int NIT = N_DIM / 32;
    for (int k = 0; k < NIT; k++) {
        const int buf = k & 1;
        const bool more = (k + 1 < NIT);
        if (more) prefetch((k + 1) * 32);
        s16x8 a[2], b[2];
        #pragma unroll
        for (int m = 0; m < 2; m++) a[m] = *(const s16x8*)&As[buf][wtm + m * 16 + lc][qd * 8];
        #pragma unroll
        for (int n = 0; n < 2; n++) b[n] = *(const s16x8*)&Bs[buf][wtn + n * 16 + lc][qd * 8];
        #pragma unroll
        for (int m = 0; m < 2; m++)
            #pragma unroll
            for (int n = 0; n < 2; n++)
                acc[m][n] = __builtin_amdgcn_mfma_f32_16x16x32_bf16(a[m], b[n], acc[m][n], 0, 0, 0);
        if (more) {
            deposit(buf ^ 1);
            __syncthreads();
        }
    }

    bf16* C = sc + (size_t)h * T_SEQ * T_SEQ;
    const bool diag = (i == j);
    #pragma unroll
    for (int m = 0; m < 2; m++) {
        #pragma unroll
        for (int r = 0; r < 4; r++) {
            int t = t0 + wtm + m * 16 + qd * 4 + r;
            #pragma unroll
            for (int n = 0; n < 2; n++) {
                int s = s0 + wtn + n * 16 + lc;
                float v = (diag && s >= t) ? 0.f : acc[m][n][r];
                C[(size_t)t * T_SEQ + s] = __float2bfloat16(v);
            }
        }
    }
}

// ---------------------------------------------------------------------------
// scores fallback (no qr buffer): 64x64, rope fused into staging.
// ---------------------------------------------------------------------------
__device__ __forceinline__ void stage_rope8(short* dst, const bf16* src,
                                            const ushort2* csP) {
    u16x8 v  = *(const u16x8*)src;
    u16x8 cs = *(const u16x8*)csP;
    u16x8 o;
    #pragma unroll
    for (int i = 0; i < 4; i++) {
        float e  = us2f(v[2 * i]), od = us2f(v[2 * i + 1]);
        float c  = us2f(cs[2 * i]), s = us2f(cs[2 * i + 1]);
        o[2 * i]     = f2us(e * c - od * s);
        o[2 * i + 1] = f2us(od * c + e * s);
    }
    *(u16x8*)dst = o;
}

__launch_bounds__(256)
__global__ void scores_fused(const bf16* __restrict__ xs,
                             const ushort2* __restrict__ csT,
                             bf16* __restrict__ sc) {
    const int h  = blockIdx.z;
    const int s0 = blockIdx.x * 64, t0 = blockIdx.y * 64;
    if (s0 > t0) return;
    __shared__ short As[64][40];
    __shared__ short Bs[64][40];
    const int tid  = threadIdx.x;
    const int srow = tid >> 2, kq = (tid & 3) * 8;
    const int lane = tid & 63, w = tid >> 6, qd = lane >> 4, lc = lane & 15;
    const int tA = t0 + srow, tB = s0 + srow;
    const bf16* gA = xs + (size_t)tA * HN + h * N_DIM + kq;
    const bf16* gB = xs + (size_t)tB * HN + h * N_DIM + kq;
    const ushort2* cA = csT + (size_t)tA * NP2 + (kq >> 1);
    const ushort2* cB = csT + (size_t)tB * NP2 + (kq >> 1);
    f32x4 acc[4] = {{0.f,0.f,0.f,0.f},{0.f,0.f,0.f,0.f},
                    {0.f,0.f,0.f,0.f},{0.f,0.f,0.f,0.f}};
    for (int k0 = 0; k0 < N_DIM; k0 += 32) {
        stage_rope8(&As[srow][kq], gA + k0, cA + (k0 >> 1));
        stage_rope8(&Bs[srow][kq], gB + k0, cB + (k0 >> 1));
        __syncthreads();
        s16x8 a = *(const s16x8*)&As[w * 16 + lc][qd * 8];
        #pragma unroll
        for (int j = 0; j < 4; j++) {
            s16x8 b = *(const s16x8*)&Bs[j * 16 + lc][qd * 8];
            acc[j] = __builtin_amdgcn_mfma_f32_16x16x32_bf16(a, b, acc[j], 0, 0, 0);
        }
        __syncthreads();
    }
    bf16* C = sc + (size_t)h * T_SEQ * T_SEQ;
    const bool diag = (s0 == t0);
    const int tbase = t0 + w * 16 + qd * 4;
    #pragma unroll
    for (int j = 0; j < 4; j++) {
        int s = s0 + j * 16 + lc;
        #pragma unroll
        for (int r = 0; r < 4; r++) {
            int t = tbase + r;
            C[(size_t)t * T_SEQ + s] =
                __float2bfloat16((!diag || s < t) ? acc[j][r] : 0.f);
        }
    }
}

// ---------------------------------------------------------------------------
// dgemm128: 128x128 tile, 4 waves x (64x64), K=192, double-buffered pipeline.
// EPI 1: xs = relu(acc); if WQR also qr = rope(relu(acc)) via shfl_xor pair.
// EPI 2: xs *= relu(acc) in place; A advanced to head slab of ykv.
// ---------------------------------------------------------------------------
template <int EPI, bool WQR>
__launch_bounds__(256)
__global__ void dgemm128(const float* __restrict__ A, const bf16* __restrict__ Bt,
                         bf16* __restrict__ xs, bf16* __restrict__ qr,
                         const ushort2* __restrict__ csT) {
    __shared__ short As[2][128][40];
    __shared__ short Bs[2][128][40];

    const int tid = threadIdx.x;
    const int lane = tid & 63, w = tid >> 6, qd = lane >> 4, lc = lane & 15;
    const int wtm = (w >> 1) * 64, wtn = (w & 1) * 64;
    const int n0 = blockIdx.x * 128, m0 = blockIdx.y * 128;
    if constexpr (EPI == 2) A += (size_t)(n0 / N_DIM) * T_SEQ * D_DIM;

    const int r0 = tid >> 2, r1 = r0 + 64;
    const int kq = (tid & 3) * 8;

    const float* gA = A  + kq;
    const bf16*  gB = Bt + kq;

    float4 fa0, fa1, fa2, fa3;
    u16x8 pb0, pb1;
    auto prefetch = [&](int k0) {
        const float* a0 = gA + (size_t)(m0 + r0) * D_DIM + k0;
        const float* a1 = gA + (size_t)(m0 + r1) * D_DIM + k0;
        fa0 = *(const float4*)a0; fa1 = *(const float4*)(a0 + 4);
        fa2 = *(const float4*)a1; fa3 = *(const float4*)(a1 + 4);
        pb0 = *(const u16x8*)(gB + (size_t)(n0 + r0) * D_DIM + k0);
        pb1 = *(const u16x8*)(gB + (size_t)(n0 + r1) * D_DIM + k0);
    };
    auto deposit = [&](int buf) {
        u16x8 o0, o1;
        o0[0] = f2us(fa0.x); o0[1] = f2us(fa0.y); o0[2] = f2us(fa0.z); o0[3] = f2us(fa0.w);
        o0[4] = f2us(fa1.x); o0[5] = f2us(fa1.y); o0[6] = f2us(fa1.z); o0[7] = f2us(fa1.w);
        o1[0] = f2us(fa2.x); o1[1] = f2us(fa2.y); o1[2] = f2us(fa2.z); o1[3] = f2us(fa2.w);
        o1[4] = f2us(fa3.x); o1[5] = f2us(fa3.y); o1[6] = f2us(fa3.z); o1[7] = f2us(fa3.w);
        *(u16x8*)&As[buf][r0][kq] = o0;
        *(u16x8*)&As[buf][r1][kq] = o1;
        *(u16x8*)&Bs[buf][r0][kq] = pb0;
        *(u16x8*)&Bs[buf][r1][kq] = pb1;
    };

    f32x4 acc[4][4] = {};

    prefetch(0);
    deposit(0);
    __syncthreads();

    const int NIT = D_DIM / 32;
    for (int k = 0; k < NIT; k++) {
        const int buf = k & 1;
        const bool more = (k + 1 < NIT);
        if (more) prefetch((k + 1) * 32);
        s16x8 a[4], b[4];
        #pragma unroll
        for (int m = 0; m < 4; m++) a[m] = *(const s16x8*)&As[buf][wtm + m * 16 + lc][qd * 8];
        #pragma unroll
        for (int n = 0; n < 4; n++) b[n] = *(const s16x8*)&Bs[buf][wtn + n * 16 + lc][qd * 8];
        #pragma unroll
        for (int m = 0; m < 4; m++)
            #pragma unroll
            for (int n = 0; n < 4; n++)
                acc[m][n] = __builtin_amdgcn_mfma_f32_16x16x32_bf16(a[m], b[n], acc[m][n], 0, 0, 0);
        if (more) {
            deposit(buf ^ 1);
            __syncthreads();
        }
    }

    #pragma unroll
    for (int m = 0; m < 4; m++) {
        #pragma unroll
        for (int r = 0; r < 4; r++) {
            int t = m0 + wtm + m * 16 + qd * 4 + r;
            #pragma unroll
            for (int n = 0; n < 4; n++) {
                int ng = n0 + wtn + n * 16 + lc;
                size_t ci = (size_t)t * HN + ng;
                float v = fmaxf(acc[m][n][r], 0.f);
                if constexpr (EPI == 1) {
                    xs[ci] = __float2bfloat16(v);
                    if constexpr (WQR) {
                        float pv = __shfl_xor(v, 1, 64);
                        int p = (ng % N_DIM) >> 1;
                        ushort2 cs = csT[(size_t)t * NP2 + p];
                        float c = us2f(cs.x), s = us2f(cs.y);
                        float o = (lc & 1) ? (v * c + pv * s) : (v * c - pv * s);
                        qr[ci] = __float2bfloat16(o);
                    }
                } else {
                    bf16* cp = xs + ci;
                    *cp = __float2bfloat16(b2f(*cp) * v);
                }
            }
        }
    }
}

// ---------------------------------------------------------------------------
// mfma_gemm (64x64, double-buffered): ykv (causal), ymlp slabs, logits.
// ---------------------------------------------------------------------------
template <typename TA, bool CAUSAL, bool SPLITK>
__launch_bounds__(256)
__global__ void mfma_gemm(const TA* __restrict__ A, const bf16* __restrict__ Bt,
                          float* __restrict__ C,
                          int K, int kSeg, int lda, int ldb, int ldc,
                          long aZ, long bZ, long cZ) {
    __shared__ short As[2][64][40];
    __shared__ short Bs[2][64][40];

    const int z = blockIdx.z;
    A += aZ * z;  Bt += bZ * z;  C += cZ * z;

    const int tid = threadIdx.x;
    const int n0 = blockIdx.x * 64, m0 = blockIdx.y * 64;
    const int srow = tid >> 2, sk = (tid & 3) * 8;
    const int lane = tid & 63, w = tid >> 6, qd = lane >> 4, lc = lane & 15;

    int kBeg, kEnd;
    if (SPLITK) { kBeg = z * kSeg; kEnd = kBeg + kSeg; }
    else        { kBeg = 0; kEnd = CAUSAL ? (m0 + 64 < K ? m0 + 64 : K) : K; }

    const TA*   ga = A  + (size_t)(m0 + srow) * lda + sk;
    const bf16* gb = Bt + (size_t)(n0 + srow) * ldb + sk;

    float4 f0, f1;
    u16x8 paw, pbw;
    auto prefetch = [&](int k0) {
        if constexpr (__is_same(TA, float)) {
            f0 = *(const float4*)(ga + k0);
            f1 = *(const float4*)(ga + k0 + 4);
        } else {
            paw = *(const u16x8*)(ga + k0);
        }
        pbw = *(const u16x8*)(gb + k0);
    };
    auto deposit = [&](int buf) {
        if constexpr (__is_same(TA, float)) {
            u16x8 o;
            o[0] = f2us(f0.x); o[1] = f2us(f0.y); o[2] = f2us(f0.z); o[3] = f2us(f0.w);
            o[4] = f2us(f1.x); o[5] = f2us(f1.y); o[6] = f2us(f1.z); o[7] = f2us(f1.w);
            *(u16x8*)&As[buf][srow][sk] = o;
        } else {
            *(u16x8*)&As[buf][srow][sk] = paw;
        }
        *(u16x8*)&Bs[buf][srow][sk] = pbw;
    };

    f32x4 acc[4] = {{0.f,0.f,0.f,0.f},{0.f,0.f,0.f,0.f},
                    {0.f,0.f,0.f,0.f},{0.f,0.f,0.f,0.f}};

    const int NIT = (kEnd - kBeg) / 32;
    prefetch(kBeg);
    deposit(0);
    __syncthreads();

    for (int k = 0; k < NIT; k++) {
        const int buf = k & 1;
        const bool more = (k + 1 < NIT);
        if (more) prefetch(kBeg + (k + 1) * 32);
        s16x8 a = *(const s16x8*)&As[buf][w * 16 + lc][qd * 8];
        s16x8 b[4];
        #pragma unroll
        for (int j = 0; j < 4; j++) b[j] = *(const s16x8*)&Bs[buf][j * 16 + lc][qd * 8];
        #pragma unroll
        for (int j = 0; j < 4; j++)
            acc[j] = __builtin_amdgcn_mfma_f32_16x16x32_bf16(a, b[j], acc[j], 0, 0, 0);
        if (more) {
            deposit(buf ^ 1);
            __syncthreads();
        }
    }

    #pragma unroll
    for (int j = 0; j < 4; j++) {
        int n = n0 + j * 16 + lc;
        #pragma unroll
        for (int r = 0; r < 4; r++) {
            int m = m0 + w * 16 + qd * 4 + r;
            C[(size_t)m * ldc + n] = acc[j][r];
        }
    }
}

extern "C" void kernel_launch(void* const* d_in, const int* in_sizes, int n_in,
                              void* d_out, int out_size, void* d_ws, size_t ws_size,
                              hipStream_t stream) {
    const int*   idx   = (const int*)  d_in[0];
    const float* dec_x = (const float*)d_in[1];   // (NH, D, N)
    const float* dec_y = (const float*)d_in[2];   // (NH, D, N)
    const float* enc   = (const float*)d_in[3];   // (NH*N, D)
    const float* emb   = (const float*)d_in[4];   // (VOCAB, D)
    const float* pose  = (const float*)d_in[5];   // (BLOCK, D)
    const float* lmh   = (const float*)d_in[6];   // (D, VOCAB)
    float* out = (float*)d_out;                   // (T, VOCAB) fp32

    // workspace layout — identical to passing r11 (ws >= 84,377,600 proven)
    char* wp = (char*)d_ws;
    float*   x    = (float*)wp;              wp += (size_t)T_SEQ * D_DIM * 4;
    bf16*    xs   = (bf16*)wp;               wp += (size_t)T_SEQ * HN * 2;
    ushort2* csT  = (ushort2*)wp;            wp += (size_t)T_SEQ * NP2 * 4;
    bf16*    sc   = (bf16*)wp;               wp += (size_t)NHEAD * T_SEQ * T_SEQ * 2;
    float*   ykv  = (float*)wp;              wp += (size_t)NHEAD * T_SEQ * D_DIM * 4;
    float*   ymlp = (float*)wp;              wp += (size_t)T_SEQ * D_DIM * 4;   // layout keeper
    bf16*    xT   = (bf16*)wp;               wp += (size_t)D_DIM * T_SEQ * 2;
    bf16*    wX   = (bf16*)wp;               wp += (size_t)NHEAD * N_DIM * D_DIM * 2;
    bf16*    wY   = (bf16*)wp;               wp += (size_t)NHEAD * N_DIM * D_DIM * 2;
    bf16*    wE   = (bf16*)wp;               wp += (size_t)D_DIM * HN * 2;
    bf16*    wL   = (bf16*)wp;               wp += (size_t)VOCABSZ * D_DIM * 2;
    const size_t BASE_NEED = (size_t)(wp - (char*)d_ws);
    bf16*    qr   = (bf16*)wp;
    const size_t FULL_NEED = BASE_NEED + (size_t)T_SEQ * HN * 2;
    float* ymlpP = (float*)sc;     // 8 slabs x T*D x 4B overlay on dead sc region

    if (ws_size < BASE_NEED) {
        fill_out<<<(out_size + 255) / 256, 256, 0, stream>>>(out, (float)ws_size, out_size);
        return;
    }
    const bool USE_QR = (ws_size >= FULL_NEED);

    // weight mirrors (bf16, [n][k])
    t_cvt<<<dim3(48, 3, 4), 256, 0, stream>>>(dec_x, wX, D_DIM, N_DIM,
                                              (long)D_DIM * N_DIM, (long)N_DIM * D_DIM);
    t_cvt<<<dim3(48, 3, 4), 256, 0, stream>>>(dec_y, wY, D_DIM, N_DIM,
                                              (long)D_DIM * N_DIM, (long)N_DIM * D_DIM);
    t_cvt<<<dim3(3, 192, 1), 256, 0, stream>>>(enc, wE, HN, D_DIM, 0L, 0L);
    t_cvt<<<dim3(4, 3, 1), 256, 0, stream>>>(lmh, wL, D_DIM, VOCABSZ, 0L, 0L);

    k_tables<<<(T_SEQ * NP2) / 256, 256, 0, stream>>>(csT);
    k_embed<<<T_SEQ, 64, 0, stream>>>(idx, emb, pose, x);

    for (int l = 0; l < NLAYER; ++l) {
        // xT = x^T (bf16) for ykv's B operand
        t_cvt<<<dim3(3, 16, 1), 256, 0, stream>>>(x, xT, T_SEQ, D_DIM, 0L, 0L);
        // xs = relu(x @ dec_x)  (+ fused qr when available)
        if (USE_QR) {
            dgemm128<1, true><<<dim3(96, 8), 256, 0, stream>>>(x, wX, xs, qr, csT);
            scores64<<<dim3(136, 1, NHEAD), 256, 0, stream>>>(qr, sc);
        } else {
            dgemm128<1, false><<<dim3(96, 8), 256, 0, stream>>>(x, wX, xs, qr, csT);
            scores_fused<<<dim3(16, 16, NHEAD), 256, 0, stream>>>(xs, csT, sc);
        }
        // ykv = sc @ x   (causal)
        mfma_gemm<bf16, true, false><<<dim3(3, 16, NHEAD), 256, 0, stream>>>(
            sc, xT, ykv, T_SEQ, 0, T_SEQ, T_SEQ, D_DIM,
            (long)T_SEQ * T_SEQ, 0L, (long)T_SEQ * D_DIM);
        // ykv = LN(ykv)
        k_ln<<<NHEAD * T_SEQ, 64, 0, stream>>>(ykv);
        // xs *= relu(ykv @ dec_y)   (gate; head slab picked inside kernel)
        dgemm128<2, false><<<dim3(96, 8), 256, 0, stream>>>(
            (const float*)ykv, wY, xs, nullptr, nullptr);
        // ymlp partials = xy @ enc   (split-K=8 -> slabs in sc region)
        mfma_gemm<bf16, false, true><<<dim3(3, 16, 8), 256, 0, stream>>>(
            xs, wE, ymlpP, HN, HN / 8, HN, HN, D_DIM,
            0L, 0L, (long)T_SEQ * D_DIM);
        // x = LN(x + LN(sum partials))
        k_resid8<<<T_SEQ, 64, 0, stream>>>(x, ymlpP);
        (void)ymlp;
    }

    // logits = x @ lm_head
    mfma_gemm<float, false, false><<<dim3(4, 16, 1), 256, 0, stream>>>(
        x, wL, out, D_DIM, 0, D_DIM, D_DIM, VOCABSZ, 0L, 0L, 0L);
}

// Round 2
// 606.069 us; speedup vs baseline: 1.1043x; 1.0458x over previous
//
#include <hip/hip_runtime.h>
#include <hip/hip_bf16.h>

using bf16 = __hip_bfloat16;

#define D_DIM   192
#define N_DIM   3072
#define NHEAD   4
#define T_SEQ   1024
#define HN      12288      // NHEAD * N_DIM
#define NP2     1536       // N_DIM/2
#define VOCABSZ 256
#define NLAYER  4
#define LN_EPS  1e-5f
#define TWO_PI  6.2831853071795864f

typedef __attribute__((ext_vector_type(8))) short          s16x8;
typedef __attribute__((ext_vector_type(8))) unsigned short u16x8;
typedef __attribute__((ext_vector_type(4))) float          f32x4;

__device__ __forceinline__ float b2f(bf16 v) { return __bfloat162float(v); }
__device__ __forceinline__ float us2f(unsigned short u) {
    unsigned int x = ((unsigned int)u) << 16;
    return __builtin_bit_cast(float, x);
}
__device__ __forceinline__ unsigned short f2us(float f) {
    bf16 b = __float2bfloat16(f);
    return __builtin_bit_cast(unsigned short, b);
}

// sentinel: encode ws_size into output (fires only if ws too small)
__global__ void fill_out(float* __restrict__ out, float val, int nelem) {
    int i = blockIdx.x * 256 + threadIdx.x;
    if (i < nelem) out[i] = val;
}

// ---------------------------------------------------------------------------
// Tiled transpose + fp32->bf16: in fp32 [R][C] -> out bf16 [C][R].
// ---------------------------------------------------------------------------
__global__ void t_cvt(const float* __restrict__ in, bf16* __restrict__ out,
                      int R, int C, long inZ, long outZ) {
    __shared__ float tile[64][65];
    in  += inZ  * blockIdx.z;
    out += outZ * blockIdx.z;
    const int tx = threadIdx.x & 63, ty = threadIdx.x >> 6;
    const int r0 = blockIdx.y * 64, c0 = blockIdx.x * 64;
    #pragma unroll
    for (int rr = 0; rr < 16; rr++) {
        int row = ty * 16 + rr;
        tile[row][tx] = in[(size_t)(r0 + row) * C + c0 + tx];
    }
    __syncthreads();
    #pragma unroll
    for (int rr = 0; rr < 16; rr++) {
        int row = ty * 16 + rr;
        out[(size_t)(c0 + row) * R + r0 + tx] = __float2bfloat16(tile[tx][row]);
    }
}

// ---------------------------------------------------------------------------
// Wave-per-row LN family (64 threads/block, 3 elems/lane, butterfly reduce)
// ---------------------------------------------------------------------------
__device__ __forceinline__ void wave_sum2(float& s, float& ss) {
    #pragma unroll
    for (int off = 1; off < 64; off <<= 1) {
        s  += __shfl_xor(s,  off, 64);
        ss += __shfl_xor(ss, off, 64);
    }
}

__global__ void k_embed(const int* __restrict__ idx, const float* __restrict__ emb,
                        const float* __restrict__ pos, float* __restrict__ x) {
    int t = blockIdx.x, l = threadIdx.x;
    int tok = idx[t];
    const float* e = emb + tok * D_DIM;
    const float* p = pos + t * D_DIM;
    float v0 = e[l] + p[l], v1 = e[l + 64] + p[l + 64], v2 = e[l + 128] + p[l + 128];
    float s = v0 + v1 + v2, ss = v0 * v0 + v1 * v1 + v2 * v2;
    wave_sum2(s, ss);
    float m = s / D_DIM, r = rsqrtf(ss / D_DIM - m * m + LN_EPS);
    float* xr = x + t * D_DIM;
    xr[l] = (v0 - m) * r; xr[l + 64] = (v1 - m) * r; xr[l + 128] = (v2 - m) * r;
}

__global__ void k_ln(float* __restrict__ buf) {
    int l = threadIdx.x;
    float* row = buf + (size_t)blockIdx.x * D_DIM;
    float v0 = row[l], v1 = row[l + 64], v2 = row[l + 128];
    float s = v0 + v1 + v2, ss = v0 * v0 + v1 * v1 + v2 * v2;
    wave_sum2(s, ss);
    float m = s / D_DIM, r = rsqrtf(ss / D_DIM - m * m + LN_EPS);
    row[l] = (v0 - m) * r; row[l + 64] = (v1 - m) * r; row[l + 128] = (v2 - m) * r;
}

// x = LN(x + LN(sum of 8 split-K partial slabs))
__global__ void k_resid8(float* __restrict__ x, const float* __restrict__ P) {
    int l = threadIdx.x, t = blockIdx.x;
    float y0 = 0.f, y1 = 0.f, y2 = 0.f;
    #pragma unroll
    for (int p = 0; p < 8; p++) {
        const float* r = P + (size_t)p * T_SEQ * D_DIM + (size_t)t * D_DIM;
        y0 += r[l]; y1 += r[l + 64]; y2 += r[l + 128];
    }
    float* xr = x + (size_t)t * D_DIM;
    float s = y0 + y1 + y2, ss = y0 * y0 + y1 * y1 + y2 * y2;
    wave_sum2(s, ss);
    float m1 = s / D_DIM, r1 = rsqrtf(ss / D_DIM - m1 * m1 + LN_EPS);
    float v0 = xr[l] + (y0 - m1) * r1;
    float v1 = xr[l + 64] + (y1 - m1) * r1;
    float v2 = xr[l + 128] + (y2 - m1) * r1;
    s = v0 + v1 + v2; ss = v0 * v0 + v1 * v1 + v2 * v2;
    wave_sum2(s, ss);
    float m2 = s / D_DIM, r2 = rsqrtf(ss / D_DIM - m2 * m2 + LN_EPS);
    xr[l] = (v0 - m2) * r2; xr[l + 64] = (v1 - m2) * r2; xr[l + 128] = (v2 - m2) * r2;
}

// RoPE cos/sin tables, interleaved bf16 pairs csT[t][p] = (cos, sin)
__global__ void k_tables(ushort2* __restrict__ csT) {
    int gid = blockIdx.x * 256 + threadIdx.x;
    int t = gid / NP2, p = gid % NP2;
    float qf = (float)(2 * p);
    float f = 1.0f / powf(65536.0f, qf / 3072.0f) / (float)TWO_PI;
    float ph = fmodf((float)t * f, 1.0f) * (float)TWO_PI;
    ushort2 cs;
    cs.x = f2us(cosf(ph));
    cs.y = f2us(sinf(ph));
    csT[gid] = cs;
}

// ---------------------------------------------------------------------------
// scores64: sc[h,t,s] = dot(qr[t,h], qr[s,h]) for s<t, else 0.
// 64x64 tile, 4 waves x (32x32), BK=64, triangular grid (136 tiles/head),
// double-buffered LDS, ONE barrier per 64-wide K-step (48 iters).
// LDS = 36.9 KB/block -> 4 blocks/CU co-resident (all 544 blocks on chip):
// inter-block overlap hides the load latency the barrier-synced pipeline
// cannot. Rows padded to 72 shorts (stride 4 dwords mod 32 -> <=2-way,
// free). XCD-chunked L remap (136 = 8*17) for L2 panel reuse.
// ---------------------------------------------------------------------------
__launch_bounds__(256)
__global__ void scores64(const bf16* __restrict__ qr, bf16* __restrict__ sc) {
    const int h = blockIdx.z;
    const int orig = blockIdx.x;
    const int L = (orig & 7) * 17 + (orig >> 3);   // bijective: 136 = 8*17
    int i = 0;
    while (((i + 1) * (i + 2)) >> 1 <= L) ++i;
    int j = L - ((i * (i + 1)) >> 1);
    const int t0 = i * 64, s0 = j * 64;

    __shared__ short As[2][64][72];
    __shared__ short Bs[2][64][72];

    const int tid = threadIdx.x;
    const int lane = tid & 63, w = tid >> 6, qd = lane >> 4, lc = lane & 15;
    const int wtm = (w >> 1) * 32, wtn = (w & 1) * 32;
    const int r0 = tid >> 2;                     // staging row 0..63
    const int kq = (tid & 3) * 16;               // staging k-offset (0,16,32,48)

    const bf16* gA = qr + (size_t)(t0 + r0) * HN + h * N_DIM + kq;
    const bf16* gB = qr + (size_t)(s0 + r0) * HN + h * N_DIM + kq;

    u16x8 pa0, pa1, pb0, pb1;
    auto prefetch = [&](int k0) {
        pa0 = *(const u16x8*)(gA + k0);
        pa1 = *(const u16x8*)(gA + k0 + 8);
        pb0 = *(const u16x8*)(gB + k0);
        pb1 = *(const u16x8*)(gB + k0 + 8);
    };
    auto deposit = [&](int buf) {
        *(u16x8*)&As[buf][r0][kq]     = pa0;
        *(u16x8*)&As[buf][r0][kq + 8] = pa1;
        *(u16x8*)&Bs[buf][r0][kq]     = pb0;
        *(u16x8*)&Bs[buf][r0][kq + 8] = pb1;
    };

    f32x4 acc[2][2] = {};

    prefetch(0);
    deposit(0);
    __syncthreads();

    const int NIT = N_DIM / 64;   // 48
    for (int k = 0; k < NIT; k++) {
        const int buf = k & 1;
        const bool more = (k + 1 < NIT);
        if (more) prefetch((k + 1) * 64);
        #pragma unroll
        for (int half = 0; half < 2; half++) {
            s16x8 a[2], b[2];
            #pragma unroll
            for (int m = 0; m < 2; m++)
                a[m] = *(const s16x8*)&As[buf][wtm + m * 16 + lc][qd * 8 + half * 32];
            #pragma unroll
            for (int n = 0; n < 2; n++)
                b[n] = *(const s16x8*)&Bs[buf][wtn + n * 16 + lc][qd * 8 + half * 32];
            #pragma unroll
            for (int m = 0; m < 2; m++)
                #pragma unroll
                for (int n = 0; n < 2; n++)
                    acc[m][n] = __builtin_amdgcn_mfma_f32_16x16x32_bf16(a[m], b[n], acc[m][n], 0, 0, 0);
        }
        if (more) {
            deposit(buf ^ 1);
            __syncthreads();
        }
    }

    bf16* C = sc + (size_t)h * T_SEQ * T_SEQ;
    const bool diag = (i == j);
    #pragma unroll
    for (int m = 0; m < 2; m++) {
        #pragma unroll
        for (int r = 0; r < 4; r++) {
            int t = t0 + wtm + m * 16 + qd * 4 + r;
            #pragma unroll
            for (int n = 0; n < 2; n++) {
                int s = s0 + wtn + n * 16 + lc;
                float v = (diag && s >= t) ? 0.f : acc[m][n][r];
                C[(size_t)t * T_SEQ + s] = __float2bfloat16(v);
            }
        }
    }
}

// ---------------------------------------------------------------------------
// scores fallback (no qr buffer): 64x64, rope fused into staging.
// ---------------------------------------------------------------------------
__device__ __forceinline__ void stage_rope8(short* dst, const bf16* src,
                                            const ushort2* csP) {
    u16x8 v  = *(const u16x8*)src;
    u16x8 cs = *(const u16x8*)csP;
    u16x8 o;
    #pragma unroll
    for (int i = 0; i < 4; i++) {
        float e  = us2f(v[2 * i]), od = us2f(v[2 * i + 1]);
        float c  = us2f(cs[2 * i]), s = us2f(cs[2 * i + 1]);
        o[2 * i]     = f2us(e * c - od * s);
        o[2 * i + 1] = f2us(od * c + e * s);
    }
    *(u16x8*)dst = o;
}

__launch_bounds__(256)
__global__ void scores_fused(const bf16* __restrict__ xs,
                             const ushort2* __restrict__ csT,
                             bf16* __restrict__ sc) {
    const int h  = blockIdx.z;
    const int s0 = blockIdx.x * 64, t0 = blockIdx.y * 64;
    if (s0 > t0) return;
    __shared__ short As[64][40];
    __shared__ short Bs[64][40];
    const int tid  = threadIdx.x;
    const int srow = tid >> 2, kq = (tid & 3) * 8;
    const int lane = tid & 63, w = tid >> 6, qd = lane >> 4, lc = lane & 15;
    const int tA = t0 + srow, tB = s0 + srow;
    const bf16* gA = xs + (size_t)tA * HN + h * N_DIM + kq;
    const bf16* gB = xs + (size_t)tB * HN + h * N_DIM + kq;
    const ushort2* cA = csT + (size_t)tA * NP2 + (kq >> 1);
    const ushort2* cB = csT + (size_t)tB * NP2 + (kq >> 1);
    f32x4 acc[4] = {{0.f,0.f,0.f,0.f},{0.f,0.f,0.f,0.f},
                    {0.f,0.f,0.f,0.f},{0.f,0.f,0.f,0.f}};
    for (int k0 = 0; k0 < N_DIM; k0 += 32) {
        stage_rope8(&As[srow][kq], gA + k0, cA + (k0 >> 1));
        stage_rope8(&Bs[srow][kq], gB + k0, cB + (k0 >> 1));
        __syncthreads();
        s16x8 a = *(const s16x8*)&As[w * 16 + lc][qd * 8];
        #pragma unroll
        for (int j = 0; j < 4; j++) {
            s16x8 b = *(const s16x8*)&Bs[j * 16 + lc][qd * 8];
            acc[j] = __builtin_amdgcn_mfma_f32_16x16x32_bf16(a, b, acc[j], 0, 0, 0);
        }
        __syncthreads();
    }
    bf16* C = sc + (size_t)h * T_SEQ * T_SEQ;
    const bool diag = (s0 == t0);
    const int tbase = t0 + w * 16 + qd * 4;
    #pragma unroll
    for (int j = 0; j < 4; j++) {
        int s = s0 + j * 16 + lc;
        #pragma unroll
        for (int r = 0; r < 4; r++) {
            int t = tbase + r;
            C[(size_t)t * T_SEQ + s] =
                __float2bfloat16((!diag || s < t) ? acc[j][r] : 0.f);
        }
    }
}

// ---------------------------------------------------------------------------
// dgemm128: 128x128 tile, 4 waves x (64x64), K=192, double-buffered pipeline.
// EPI 1: xs = relu(acc); if WQR also qr = rope(relu(acc)) via shfl_xor pair.
// EPI 2: xs *= relu(acc) in place; A advanced to head slab of ykv.
// ---------------------------------------------------------------------------
template <int EPI, bool WQR>
__launch_bounds__(256)
__global__ void dgemm128(const float* __restrict__ A, const bf16* __restrict__ Bt,
                         bf16* __restrict__ xs, bf16* __restrict__ qr,
                         const ushort2* __restrict__ csT) {
    __shared__ short As[2][128][40];
    __shared__ short Bs[2][128][40];

    const int tid = threadIdx.x;
    const int lane = tid & 63, w = tid >> 6, qd = lane >> 4, lc = lane & 15;
    const int wtm = (w >> 1) * 64, wtn = (w & 1) * 64;
    const int n0 = blockIdx.x * 128, m0 = blockIdx.y * 128;
    if constexpr (EPI == 2) A += (size_t)(n0 / N_DIM) * T_SEQ * D_DIM;

    const int r0 = tid >> 2, r1 = r0 + 64;
    const int kq = (tid & 3) * 8;

    const float* gA = A  + kq;
    const bf16*  gB = Bt + kq;

    float4 fa0, fa1, fa2, fa3;
    u16x8 pb0, pb1;
    auto prefetch = [&](int k0) {
        const float* a0 = gA + (size_t)(m0 + r0) * D_DIM + k0;
        const float* a1 = gA + (size_t)(m0 + r1) * D_DIM + k0;
        fa0 = *(const float4*)a0; fa1 = *(const float4*)(a0 + 4);
        fa2 = *(const float4*)a1; fa3 = *(const float4*)(a1 + 4);
        pb0 = *(const u16x8*)(gB + (size_t)(n0 + r0) * D_DIM + k0);
        pb1 = *(const u16x8*)(gB + (size_t)(n0 + r1) * D_DIM + k0);
    };
    auto deposit = [&](int buf) {
        u16x8 o0, o1;
        o0[0] = f2us(fa0.x); o0[1] = f2us(fa0.y); o0[2] = f2us(fa0.z); o0[3] = f2us(fa0.w);
        o0[4] = f2us(fa1.x); o0[5] = f2us(fa1.y); o0[6] = f2us(fa1.z); o0[7] = f2us(fa1.w);
        o1[0] = f2us(fa2.x); o1[1] = f2us(fa2.y); o1[2] = f2us(fa2.z); o1[3] = f2us(fa2.w);
        o1[4] = f2us(fa3.x); o1[5] = f2us(fa3.y); o1[6] = f2us(fa3.z); o1[7] = f2us(fa3.w);
        *(u16x8*)&As[buf][r0][kq] = o0;
        *(u16x8*)&As[buf][r1][kq] = o1;
        *(u16x8*)&Bs[buf][r0][kq] = pb0;
        *(u16x8*)&Bs[buf][r1][kq] = pb1;
    };

    f32x4 acc[4][4] = {};

    prefetch(0);
    deposit(0);
    __syncthreads();

    const int NIT = D_DIM / 32;
    for (int k = 0; k < NIT; k++) {
        const int buf = k & 1;
        const bool more = (k + 1 < NIT);
        if (more) prefetch((k + 1) * 32);
        s16x8 a[4], b[4];
        #pragma unroll
        for (int m = 0; m < 4; m++) a[m] = *(const s16x8*)&As[buf][wtm + m * 16 + lc][qd * 8];
        #pragma unroll
        for (int n = 0; n < 4; n++) b[n] = *(const s16x8*)&Bs[buf][wtn + n * 16 + lc][qd * 8];
        #pragma unroll
        for (int m = 0; m < 4; m++)
            #pragma unroll
            for (int n = 0; n < 4; n++)
                acc[m][n] = __builtin_amdgcn_mfma_f32_16x16x32_bf16(a[m], b[n], acc[m][n], 0, 0, 0);
        if (more) {
            deposit(buf ^ 1);
            __syncthreads();
        }
    }

    #pragma unroll
    for (int m = 0; m < 4; m++) {
        #pragma unroll
        for (int r = 0; r < 4; r++) {
            int t = m0 + wtm + m * 16 + qd * 4 + r;
            #pragma unroll
            for (int n = 0; n < 4; n++) {
                int ng = n0 + wtn + n * 16 + lc;
                size_t ci = (size_t)t * HN + ng;
                float v = fmaxf(acc[m][n][r], 0.f);
                if constexpr (EPI == 1) {
                    xs[ci] = __float2bfloat16(v);
                    if constexpr (WQR) {
                        float pv = __shfl_xor(v, 1, 64);
                        int p = (ng % N_DIM) >> 1;
                        ushort2 cs = csT[(size_t)t * NP2 + p];
                        float c = us2f(cs.x), s = us2f(cs.y);
                        float o = (lc & 1) ? (v * c + pv * s) : (v * c - pv * s);
                        qr[ci] = __float2bfloat16(o);
                    }
                } else {
                    bf16* cp = xs + ci;
                    *cp = __float2bfloat16(b2f(*cp) * v);
                }
            }
        }
    }
}

// ---------------------------------------------------------------------------
// mfma_gemm (64x64, double-buffered): ykv (causal), ymlp slabs, logits.
// ---------------------------------------------------------------------------
template <typename TA, bool CAUSAL, bool SPLITK>
__launch_bounds__(256)
__global__ void mfma_gemm(const TA* __restrict__ A, const bf16* __restrict__ Bt,
                          float* __restrict__ C,
                          int K, int kSeg, int lda, int ldb, int ldc,
                          long aZ, long bZ, long cZ) {
    __shared__ short As[2][64][40];
    __shared__ short Bs[2][64][40];

    const int z = blockIdx.z;
    A += aZ * z;  Bt += bZ * z;  C += cZ * z;

    const int tid = threadIdx.x;
    const int n0 = blockIdx.x * 64, m0 = blockIdx.y * 64;
    const int srow = tid >> 2, sk = (tid & 3) * 8;
    const int lane = tid & 63, w = tid >> 6, qd = lane >> 4, lc = lane & 15;

    int kBeg, kEnd;
    if (SPLITK) { kBeg = z * kSeg; kEnd = kBeg + kSeg; }
    else        { kBeg = 0; kEnd = CAUSAL ? (m0 + 64 < K ? m0 + 64 : K) : K; }

    const TA*   ga = A  + (size_t)(m0 + srow) * lda + sk;
    const bf16* gb = Bt + (size_t)(n0 + srow) * ldb + sk;

    float4 f0, f1;
    u16x8 paw, pbw;
    auto prefetch = [&](int k0) {
        if constexpr (__is_same(TA, float)) {
            f0 = *(const float4*)(ga + k0);
            f1 = *(const float4*)(ga + k0 + 4);
        } else {
            paw = *(const u16x8*)(ga + k0);
        }
        pbw = *(const u16x8*)(gb + k0);
    };
    auto deposit = [&](int buf) {
        if constexpr (__is_same(TA, float)) {
            u16x8 o;
            o[0] = f2us(f0.x); o[1] = f2us(f0.y); o[2] = f2us(f0.z); o[3] = f2us(f0.w);
            o[4] = f2us(f1.x); o[5] = f2us(f1.y); o[6] = f2us(f1.z); o[7] = f2us(f1.w);
            *(u16x8*)&As[buf][srow][sk] = o;
        } else {
            *(u16x8*)&As[buf][srow][sk] = paw;
        }
        *(u16x8*)&Bs[buf][srow][sk] = pbw;
    };

    f32x4 acc[4] = {{0.f,0.f,0.f,0.f},{0.f,0.f,0.f,0.f},
                    {0.f,0.f,0.f,0.f},{0.f,0.f,0.f,0.f}};

    const int NIT = (kEnd - kBeg) / 32;
    prefetch(kBeg);
    deposit(0);
    __syncthreads();

    for (int k = 0; k < NIT; k++) {
        const int buf = k & 1;
        const bool more = (k + 1 < NIT);
        if (more) prefetch(kBeg + (k + 1) * 32);
        s16x8 a = *(const s16x8*)&As[buf][w * 16 + lc][qd * 8];
        s16x8 b[4];
        #pragma unroll
        for (int j = 0; j < 4; j++) b[j] = *(const s16x8*)&Bs[buf][j * 16 + lc][qd * 8];
        #pragma unroll
        for (int j = 0; j < 4; j++)
            acc[j] = __builtin_amdgcn_mfma_f32_16x16x32_bf16(a, b[j], acc[j], 0, 0, 0);
        if (more) {
            deposit(buf ^ 1);
            __syncthreads();
        }
    }

    #pragma unroll
    for (int j = 0; j < 4; j++) {
        int n = n0 + j * 16 + lc;
        #pragma unroll
        for (int r = 0; r < 4; r++) {
            int m = m0 + w * 16 + qd * 4 + r;
            C[(size_t)m * ldc + n] = acc[j][r];
        }
    }
}

extern "C" void kernel_launch(void* const* d_in, const int* in_sizes, int n_in,
                              void* d_out, int out_size, void* d_ws, size_t ws_size,
                              hipStream_t stream) {
    const int*   idx   = (const int*)  d_in[0];
    const float* dec_x = (const float*)d_in[1];   // (NH, D, N)
    const float* dec_y = (const float*)d_in[2];   // (NH, D, N)
    const float* enc   = (const float*)d_in[3];   // (NH*N, D)
    const float* emb   = (const float*)d_in[4];   // (VOCAB, D)
    const float* pose  = (const float*)d_in[5];   // (BLOCK, D)
    const float* lmh   = (const float*)d_in[6];   // (D, VOCAB)
    float* out = (float*)d_out;                   // (T, VOCAB) fp32

    // workspace layout — identical to passing r11 (ws >= 84,377,600 proven)
    char* wp = (char*)d_ws;
    float*   x    = (float*)wp;              wp += (size_t)T_SEQ * D_DIM * 4;
    bf16*    xs   = (bf16*)wp;               wp += (size_t)T_SEQ * HN * 2;
    ushort2* csT  = (ushort2*)wp;            wp += (size_t)T_SEQ * NP2 * 4;
    bf16*    sc   = (bf16*)wp;               wp += (size_t)NHEAD * T_SEQ * T_SEQ * 2;
    float*   ykv  = (float*)wp;              wp += (size_t)NHEAD * T_SEQ * D_DIM * 4;
    float*   ymlp = (float*)wp;              wp += (size_t)T_SEQ * D_DIM * 4;   // layout keeper
    bf16*    xT   = (bf16*)wp;               wp += (size_t)D_DIM * T_SEQ * 2;
    bf16*    wX   = (bf16*)wp;               wp += (size_t)NHEAD * N_DIM * D_DIM * 2;
    bf16*    wY   = (bf16*)wp;               wp += (size_t)NHEAD * N_DIM * D_DIM * 2;
    bf16*    wE   = (bf16*)wp;               wp += (size_t)D_DIM * HN * 2;
    bf16*    wL   = (bf16*)wp;               wp += (size_t)VOCABSZ * D_DIM * 2;
    const size_t BASE_NEED = (size_t)(wp - (char*)d_ws);
    bf16*    qr   = (bf16*)wp;
    const size_t FULL_NEED = BASE_NEED + (size_t)T_SEQ * HN * 2;
    float* ymlpP = (float*)sc;     // 8 slabs x T*D x 4B overlay on dead sc region

    if (ws_size < BASE_NEED) {
        fill_out<<<(out_size + 255) / 256, 256, 0, stream>>>(out, (float)ws_size, out_size);
        return;
    }
    const bool USE_QR = (ws_size >= FULL_NEED);

    // weight mirrors (bf16, [n][k])
    t_cvt<<<dim3(48, 3, 4), 256, 0, stream>>>(dec_x, wX, D_DIM, N_DIM,
                                              (long)D_DIM * N_DIM, (long)N_DIM * D_DIM);
    t_cvt<<<dim3(48, 3, 4), 256, 0, stream>>>(dec_y, wY, D_DIM, N_DIM,
                                              (long)D_DIM * N_DIM, (long)N_DIM * D_DIM);
    t_cvt<<<dim3(3, 192, 1), 256, 0, stream>>>(enc, wE, HN, D_DIM, 0L, 0L);
    t_cvt<<<dim3(4, 3, 1), 256, 0, stream>>>(lmh, wL, D_DIM, VOCABSZ, 0L, 0L);

    k_tables<<<(T_SEQ * NP2) / 256, 256, 0, stream>>>(csT);
    k_embed<<<T_SEQ, 64, 0, stream>>>(idx, emb, pose, x);

    for (int l = 0; l < NLAYER; ++l) {
        // xT = x^T (bf16) for ykv's B operand
        t_cvt<<<dim3(3, 16, 1), 256, 0, stream>>>(x, xT, T_SEQ, D_DIM, 0L, 0L);
        // xs = relu(x @ dec_x)  (+ fused qr when available)
        if (USE_QR) {
            dgemm128<1, true><<<dim3(96, 8), 256, 0, stream>>>(x, wX, xs, qr, csT);
            scores64<<<dim3(136, 1, NHEAD), 256, 0, stream>>>(qr, sc);
        } else {
            dgemm128<1, false><<<dim3(96, 8), 256, 0, stream>>>(x, wX, xs, qr, csT);
            scores_fused<<<dim3(16, 16, NHEAD), 256, 0, stream>>>(xs, csT, sc);
        }
        // ykv = sc @ x   (causal)
        mfma_gemm<bf16, true, false><<<dim3(3, 16, NHEAD), 256, 0, stream>>>(
            sc, xT, ykv, T_SEQ, 0, T_SEQ, T_SEQ, D_DIM,
            (long)T_SEQ * T_SEQ, 0L, (long)T_SEQ * D_DIM);
        // ykv = LN(ykv)
        k_ln<<<NHEAD * T_SEQ, 64, 0, stream>>>(ykv);
        // xs *= relu(ykv @ dec_y)   (gate; head slab picked inside kernel)
        dgemm128<2, false><<<dim3(96, 8), 256, 0, stream>>>(
            (const float*)ykv, wY, xs, nullptr, nullptr);
        // ymlp partials = xy @ enc   (split-K=8 -> slabs in sc region)
        mfma_gemm<bf16, false, true><<<dim3(3, 16, 8), 256, 0, stream>>>(
            xs, wE, ymlpP, HN, HN / 8, HN, HN, D_DIM,
            0L, 0L, (long)T_SEQ * D_DIM);
        // x = LN(x + LN(sum partials))
        k_resid8<<<T_SEQ, 64, 0, stream>>>(x, ymlpP);
        (void)ymlp;
    }

    // logits = x @ lm_head
    mfma_gemm<float, false, false><<<dim3(4, 16, 1), 256, 0, stream>>>(
        x, wL, out, D_DIM, 0, D_DIM, D_DIM, VOCABSZ, 0L, 0L, 0L);
}

// Round 3
// 582.844 us; speedup vs baseline: 1.1483x; 1.0398x over previous
//
#include <hip/hip_runtime.h>
#include <hip/hip_bf16.h>

using bf16 = __hip_bfloat16;

#define D_DIM   192
#define N_DIM   3072
#define NHEAD   4
#define T_SEQ   1024
#define HN      12288      // NHEAD * N_DIM
#define NP2     1536       // N_DIM/2
#define VOCABSZ 256
#define NLAYER  4
#define LN_EPS  1e-5f
#define TWO_PI  6.2831853071795864f

typedef __attribute__((ext_vector_type(8))) short          s16x8;
typedef __attribute__((ext_vector_type(8))) unsigned short u16x8;
typedef __attribute__((ext_vector_type(4))) float          f32x4;

__device__ __forceinline__ float b2f(bf16 v) { return __bfloat162float(v); }
__device__ __forceinline__ float us2f(unsigned short u) {
    unsigned int x = ((unsigned int)u) << 16;
    return __builtin_bit_cast(float, x);
}
__device__ __forceinline__ unsigned short f2us(float f) {
    bf16 b = __float2bfloat16(f);
    return __builtin_bit_cast(unsigned short, b);
}

// sentinel: encode ws_size into output (fires only if ws too small)
__global__ void fill_out(float* __restrict__ out, float val, int nelem) {
    int i = blockIdx.x * 256 + threadIdx.x;
    if (i < nelem) out[i] = val;
}

// ---------------------------------------------------------------------------
// Tiled transpose + fp32->bf16: in fp32 [R][C] -> out bf16 [C][R].
// ---------------------------------------------------------------------------
__global__ void t_cvt(const float* __restrict__ in, bf16* __restrict__ out,
                      int R, int C, long inZ, long outZ) {
    __shared__ float tile[64][65];
    in  += inZ  * blockIdx.z;
    out += outZ * blockIdx.z;
    const int tx = threadIdx.x & 63, ty = threadIdx.x >> 6;
    const int r0 = blockIdx.y * 64, c0 = blockIdx.x * 64;
    #pragma unroll
    for (int rr = 0; rr < 16; rr++) {
        int row = ty * 16 + rr;
        tile[row][tx] = in[(size_t)(r0 + row) * C + c0 + tx];
    }
    __syncthreads();
    #pragma unroll
    for (int rr = 0; rr < 16; rr++) {
        int row = ty * 16 + rr;
        out[(size_t)(c0 + row) * R + r0 + tx] = __float2bfloat16(tile[tx][row]);
    }
}

// ---------------------------------------------------------------------------
// Wave-per-row LN family (64 threads/block, 3 elems/lane, butterfly reduce)
// ---------------------------------------------------------------------------
__device__ __forceinline__ void wave_sum2(float& s, float& ss) {
    #pragma unroll
    for (int off = 1; off < 64; off <<= 1) {
        s  += __shfl_xor(s,  off, 64);
        ss += __shfl_xor(ss, off, 64);
    }
}

__global__ void k_embed(const int* __restrict__ idx, const float* __restrict__ emb,
                        const float* __restrict__ pos, float* __restrict__ x) {
    int t = blockIdx.x, l = threadIdx.x;
    int tok = idx[t];
    const float* e = emb + tok * D_DIM;
    const float* p = pos + t * D_DIM;
    float v0 = e[l] + p[l], v1 = e[l + 64] + p[l + 64], v2 = e[l + 128] + p[l + 128];
    float s = v0 + v1 + v2, ss = v0 * v0 + v1 * v1 + v2 * v2;
    wave_sum2(s, ss);
    float m = s / D_DIM, r = rsqrtf(ss / D_DIM - m * m + LN_EPS);
    float* xr = x + t * D_DIM;
    xr[l] = (v0 - m) * r; xr[l + 64] = (v1 - m) * r; xr[l + 128] = (v2 - m) * r;
}

__global__ void k_ln(float* __restrict__ buf) {
    int l = threadIdx.x;
    float* row = buf + (size_t)blockIdx.x * D_DIM;
    float v0 = row[l], v1 = row[l + 64], v2 = row[l + 128];
    float s = v0 + v1 + v2, ss = v0 * v0 + v1 * v1 + v2 * v2;
    wave_sum2(s, ss);
    float m = s / D_DIM, r = rsqrtf(ss / D_DIM - m * m + LN_EPS);
    row[l] = (v0 - m) * r; row[l + 64] = (v1 - m) * r; row[l + 128] = (v2 - m) * r;
}

// x = LN(x + LN(sum of 8 split-K partial slabs))
__global__ void k_resid8(float* __restrict__ x, const float* __restrict__ P) {
    int l = threadIdx.x, t = blockIdx.x;
    float y0 = 0.f, y1 = 0.f, y2 = 0.f;
    #pragma unroll
    for (int p = 0; p < 8; p++) {
        const float* r = P + (size_t)p * T_SEQ * D_DIM + (size_t)t * D_DIM;
        y0 += r[l]; y1 += r[l + 64]; y2 += r[l + 128];
    }
    float* xr = x + (size_t)t * D_DIM;
    float s = y0 + y1 + y2, ss = y0 * y0 + y1 * y1 + y2 * y2;
    wave_sum2(s, ss);
    float m1 = s / D_DIM, r1 = rsqrtf(ss / D_DIM - m1 * m1 + LN_EPS);
    float v0 = xr[l] + (y0 - m1) * r1;
    float v1 = xr[l + 64] + (y1 - m1) * r1;
    float v2 = xr[l + 128] + (y2 - m1) * r1;
    s = v0 + v1 + v2; ss = v0 * v0 + v1 * v1 + v2 * v2;
    wave_sum2(s, ss);
    float m2 = s / D_DIM, r2 = rsqrtf(ss / D_DIM - m2 * m2 + LN_EPS);
    xr[l] = (v0 - m2) * r2; xr[l + 64] = (v1 - m2) * r2; xr[l + 128] = (v2 - m2) * r2;
}

// RoPE cos/sin tables, interleaved bf16 pairs csT[t][p] = (cos, sin)
__global__ void k_tables(ushort2* __restrict__ csT) {
    int gid = blockIdx.x * 256 + threadIdx.x;
    int t = gid / NP2, p = gid % NP2;
    float qf = (float)(2 * p);
    float f = 1.0f / powf(65536.0f, qf / 3072.0f) / (float)TWO_PI;
    float ph = fmodf((float)t * f, 1.0f) * (float)TWO_PI;
    ushort2 cs;
    cs.x = f2us(cosf(ph));
    cs.y = f2us(sinf(ph));
    csT[gid] = cs;
}

// ---------------------------------------------------------------------------
// scores64: sc[h,t,s] = dot(qr[t,h], qr[s,h]) for s<t, else 0.
// Split-K=2 over grid.y (1088 blocks total): kh=0 computes K[0,1536) and
// writes the (i,j) lower tile; kh=1 computes K[1536,3072) with SWAPPED
// operands (dot is symmetric) and writes the unused mirror tile (j,i) for
// off-diag, or a small dbuf slab (on idle ykv memory) for diagonal tiles.
// k_comb adds the partials. 64x64 tile, 4 waves x (32x32), BK=64,
// double-buffered LDS + 2-DEEP register prefetch (deposit waits on loads
// issued a full iteration earlier -> counted vmcnt, latency hidden).
// Rows padded to 72 shorts. XCD-chunked L remap (136 = 8*17).
// ---------------------------------------------------------------------------
__launch_bounds__(256, 4)
__global__ void scores64(const bf16* __restrict__ qr, bf16* __restrict__ sc,
                         bf16* __restrict__ dbuf) {
    const int h  = blockIdx.z;
    const int kh = blockIdx.y;                     // K-half
    const int orig = blockIdx.x;
    const int L = (orig & 7) * 17 + (orig >> 3);   // bijective: 136 = 8*17
    int i = 0;
    while (((i + 1) * (i + 2)) >> 1 <= L) ++i;
    int j = L - ((i * (i + 1)) >> 1);
    const int t0 = i * 64, s0 = j * 64;
    const bool diag = (i == j);

    // operand roles: kh=1 off-diag computes the transposed tile directly
    int arow = t0, brow = s0;
    if (kh == 1 && !diag) { arow = s0; brow = t0; }

    __shared__ short As[2][64][72];
    __shared__ short Bs[2][64][72];

    const int tid = threadIdx.x;
    const int lane = tid & 63, w = tid >> 6, qd = lane >> 4, lc = lane & 15;
    const int wtm = (w >> 1) * 32, wtn = (w & 1) * 32;
    const int r0 = tid >> 2;                     // staging row 0..63
    const int kq = (tid & 3) * 16;               // staging k-offset (0,16,32,48)

    const int kBeg = kh * (N_DIM / 2);
    const bf16* gA = qr + (size_t)(arow + r0) * HN + h * N_DIM + kBeg + kq;
    const bf16* gB = qr + (size_t)(brow + r0) * HN + h * N_DIM + kBeg + kq;

    // two named register sets (static indexing only — no scratch)
    u16x8 pa0, pa1, pb0, pb1;   // set 0: even iters
    u16x8 qa0, qa1, qb0, qb1;   // set 1: odd iters
    auto load0 = [&](int k0) {
        pa0 = *(const u16x8*)(gA + k0);
        pa1 = *(const u16x8*)(gA + k0 + 8);
        pb0 = *(const u16x8*)(gB + k0);
        pb1 = *(const u16x8*)(gB + k0 + 8);
    };
    auto load1 = [&](int k0) {
        qa0 = *(const u16x8*)(gA + k0);
        qa1 = *(const u16x8*)(gA + k0 + 8);
        qb0 = *(const u16x8*)(gB + k0);
        qb1 = *(const u16x8*)(gB + k0 + 8);
    };
    auto dep0 = [&](int buf) {
        *(u16x8*)&As[buf][r0][kq]     = pa0;
        *(u16x8*)&As[buf][r0][kq + 8] = pa1;
        *(u16x8*)&Bs[buf][r0][kq]     = pb0;
        *(u16x8*)&Bs[buf][r0][kq + 8] = pb1;
    };
    auto dep1 = [&](int buf) {
        *(u16x8*)&As[buf][r0][kq]     = qa0;
        *(u16x8*)&As[buf][r0][kq + 8] = qa1;
        *(u16x8*)&Bs[buf][r0][kq]     = qb0;
        *(u16x8*)&Bs[buf][r0][kq + 8] = qb1;
    };

    f32x4 acc[2][2] = {};
    auto mfma_step = [&](int buf) {
        #pragma unroll
        for (int half = 0; half < 2; half++) {
            s16x8 a[2], b[2];
            #pragma unroll
            for (int m = 0; m < 2; m++)
                a[m] = *(const s16x8*)&As[buf][wtm + m * 16 + lc][qd * 8 + half * 32];
            #pragma unroll
            for (int n = 0; n < 2; n++)
                b[n] = *(const s16x8*)&Bs[buf][wtn + n * 16 + lc][qd * 8 + half * 32];
            #pragma unroll
            for (int m = 0; m < 2; m++)
                #pragma unroll
                for (int n = 0; n < 2; n++)
                    acc[m][n] = __builtin_amdgcn_mfma_f32_16x16x32_bf16(a[m], b[n], acc[m][n], 0, 0, 0);
        }
    };

    const int NIT = (N_DIM / 2) / 64;   // 24 (even)
    // prologue: set0 <- iter0, set1 <- iter1
    load0(0);
    load1(64);
    dep0(0);
    __syncthreads();

    for (int k = 0; k < NIT; k += 2) {
        // even iter k: compute buf0; deposit set1 -> buf1; refill set0 <- k+2
        if (k + 2 < NIT) load0((k + 2) * 64);
        mfma_step(0);
        if (k + 1 < NIT) dep1(1);
        __syncthreads();
        // odd iter k+1: compute buf1; deposit set0 -> buf0; refill set1 <- k+3
        if (k + 1 < NIT) {
            if (k + 3 < NIT) load1((k + 3) * 64);
            mfma_step(1);
            if (k + 2 < NIT) dep0(0);
            __syncthreads();
        }
    }

    if (kh == 1 && diag) {
        // diagonal second-half partial -> dbuf slab [64][64], masked
        bf16* P = dbuf + (size_t)(h * 16 + i) * 4096;
        #pragma unroll
        for (int m = 0; m < 2; m++) {
            #pragma unroll
            for (int r = 0; r < 4; r++) {
                int lt = wtm + m * 16 + qd * 4 + r;
                #pragma unroll
                for (int n = 0; n < 2; n++) {
                    int ls = wtn + n * 16 + lc;
                    P[lt * 64 + ls] = __float2bfloat16(ls >= lt ? 0.f : acc[m][n][r]);
                }
            }
        }
    } else {
        // kh0: tile (i,j) at rows t0, cols s0 (masked if diag).
        // kh1 off-diag: transposed tile at rows s0, cols t0 (mirror slot).
        bf16* C = sc + (size_t)h * T_SEQ * T_SEQ;
        const bool msk = (kh == 0) && diag;
        #pragma unroll
        for (int m = 0; m < 2; m++) {
            #pragma unroll
            for (int r = 0; r < 4; r++) {
                int t = arow + wtm + m * 16 + qd * 4 + r;
                #pragma unroll
                for (int n = 0; n < 2; n++) {
                    int s = brow + wtn + n * 16 + lc;
                    float v = (msk && s >= t) ? 0.f : acc[m][n][r];
                    C[(size_t)t * T_SEQ + s] = __float2bfloat16(v);
                }
            }
        }
    }
}

// ---------------------------------------------------------------------------
// k_comb: sc lower tile (i,j) += second-half partial (mirror tile (j,i),
// transposed via LDS; or dbuf slab for diagonal tiles).
// ---------------------------------------------------------------------------
__global__ void k_comb(bf16* __restrict__ sc, const bf16* __restrict__ dbuf) {
    __shared__ short tile[64][72];
    const int h = blockIdx.z;
    int L = blockIdx.x;
    int i = 0;
    while (((i + 1) * (i + 2)) >> 1 <= L) ++i;
    int j = L - ((i * (i + 1)) >> 1);
    bf16* C = sc + (size_t)h * T_SEQ * T_SEQ;
    const int r  = threadIdx.x >> 3;          // 0..31
    const int c8 = (threadIdx.x & 7) * 8;     // 0,8,...,56
    if (i != j) {
        // mirror tile P[s_local][t_local] lives at rows j*64.., cols i*64..
        #pragma unroll
        for (int p = 0; p < 2; p++) {
            int row = r + p * 32;
            u16x8 v = *(const u16x8*)(C + (size_t)(j * 64 + row) * T_SEQ + i * 64 + c8);
            *(u16x8*)&tile[row][c8] = v;
        }
        __syncthreads();
        #pragma unroll
        for (int p = 0; p < 2; p++) {
            int row = r + p * 32;             // t_local
            size_t off = (size_t)(i * 64 + row) * T_SEQ + j * 64 + c8;
            u16x8 a = *(const u16x8*)(C + off);
            u16x8 o;
            #pragma unroll
            for (int e = 0; e < 8; e++)
                o[e] = f2us(us2f(a[e]) + us2f((unsigned short)tile[c8 + e][row]));
            *(u16x8*)(C + off) = o;
        }
    } else {
        const bf16* P = dbuf + (size_t)(h * 16 + i) * 4096;
        #pragma unroll
        for (int p = 0; p < 2; p++) {
            int row = r + p * 32;
            size_t off = (size_t)(i * 64 + row) * T_SEQ + i * 64 + c8;
            u16x8 a = *(const u16x8*)(C + off);
            u16x8 b = *(const u16x8*)((const unsigned short*)P + row * 64 + c8);
            u16x8 o;
            #pragma unroll
            for (int e = 0; e < 8; e++)
                o[e] = f2us(us2f(a[e]) + us2f(b[e]));
            *(u16x8*)(C + off) = o;
        }
    }
}

// ---------------------------------------------------------------------------
// scores fallback (no qr buffer): 64x64, rope fused into staging.
// ---------------------------------------------------------------------------
__device__ __forceinline__ void stage_rope8(short* dst, const bf16* src,
                                            const ushort2* csP) {
    u16x8 v  = *(const u16x8*)src;
    u16x8 cs = *(const u16x8*)csP;
    u16x8 o;
    #pragma unroll
    for (int i = 0; i < 4; i++) {
        float e  = us2f(v[2 * i]), od = us2f(v[2 * i + 1]);
        float c  = us2f(cs[2 * i]), s = us2f(cs[2 * i + 1]);
        o[2 * i]     = f2us(e * c - od * s);
        o[2 * i + 1] = f2us(od * c + e * s);
    }
    *(u16x8*)dst = o;
}

__launch_bounds__(256)
__global__ void scores_fused(const bf16* __restrict__ xs,
                             const ushort2* __restrict__ csT,
                             bf16* __restrict__ sc) {
    const int h  = blockIdx.z;
    const int s0 = blockIdx.x * 64, t0 = blockIdx.y * 64;
    if (s0 > t0) return;
    __shared__ short As[64][40];
    __shared__ short Bs[64][40];
    const int tid  = threadIdx.x;
    const int srow = tid >> 2, kq = (tid & 3) * 8;
    const int lane = tid & 63, w = tid >> 6, qd = lane >> 4, lc = lane & 15;
    const int tA = t0 + srow, tB = s0 + srow;
    const bf16* gA = xs + (size_t)tA * HN + h * N_DIM + kq;
    const bf16* gB = xs + (size_t)tB * HN + h * N_DIM + kq;
    const ushort2* cA = csT + (size_t)tA * NP2 + (kq >> 1);
    const ushort2* cB = csT + (size_t)tB * NP2 + (kq >> 1);
    f32x4 acc[4] = {{0.f,0.f,0.f,0.f},{0.f,0.f,0.f,0.f},
                    {0.f,0.f,0.f,0.f},{0.f,0.f,0.f,0.f}};
    for (int k0 = 0; k0 < N_DIM; k0 += 32) {
        stage_rope8(&As[srow][kq], gA + k0, cA + (k0 >> 1));
        stage_rope8(&Bs[srow][kq], gB + k0, cB + (k0 >> 1));
        __syncthreads();
        s16x8 a = *(const s16x8*)&As[w * 16 + lc][qd * 8];
        #pragma unroll
        for (int j = 0; j < 4; j++) {
            s16x8 b = *(const s16x8*)&Bs[j * 16 + lc][qd * 8];
            acc[j] = __builtin_amdgcn_mfma_f32_16x16x32_bf16(a, b, acc[j], 0, 0, 0);
        }
        __syncthreads();
    }
    bf16* C = sc + (size_t)h * T_SEQ * T_SEQ;
    const bool diag = (s0 == t0);
    const int tbase = t0 + w * 16 + qd * 4;
    #pragma unroll
    for (int j = 0; j < 4; j++) {
        int s = s0 + j * 16 + lc;
        #pragma unroll
        for (int r = 0; r < 4; r++) {
            int t = tbase + r;
            C[(size_t)t * T_SEQ + s] =
                __float2bfloat16((!diag || s < t) ? acc[j][r] : 0.f);
        }
    }
}

// ---------------------------------------------------------------------------
// dgemm128: 128x128 tile, 4 waves x (64x64), K=192, double-buffered pipeline.
// EPI 1: xs = relu(acc); if WQR also qr = rope(relu(acc)) via shfl_xor pair.
// EPI 2: xs *= relu(acc) in place; A advanced to head slab of ykv.
// ---------------------------------------------------------------------------
template <int EPI, bool WQR>
__launch_bounds__(256)
__global__ void dgemm128(const float* __restrict__ A, const bf16* __restrict__ Bt,
                         bf16* __restrict__ xs, bf16* __restrict__ qr,
                         const ushort2* __restrict__ csT) {
    __shared__ short As[2][128][40];
    __shared__ short Bs[2][128][40];

    const int tid = threadIdx.x;
    const int lane = tid & 63, w = tid >> 6, qd = lane >> 4, lc = lane & 15;
    const int wtm = (w >> 1) * 64, wtn = (w & 1) * 64;
    const int n0 = blockIdx.x * 128, m0 = blockIdx.y * 128;
    if constexpr (EPI == 2) A += (size_t)(n0 / N_DIM) * T_SEQ * D_DIM;

    const int r0 = tid >> 2, r1 = r0 + 64;
    const int kq = (tid & 3) * 8;

    const float* gA = A  + kq;
    const bf16*  gB = Bt + kq;

    float4 fa0, fa1, fa2, fa3;
    u16x8 pb0, pb1;
    auto prefetch = [&](int k0) {
        const float* a0 = gA + (size_t)(m0 + r0) * D_DIM + k0;
        const float* a1 = gA + (size_t)(m0 + r1) * D_DIM + k0;
        fa0 = *(const float4*)a0; fa1 = *(const float4*)(a0 + 4);
        fa2 = *(const float4*)a1; fa3 = *(const float4*)(a1 + 4);
        pb0 = *(const u16x8*)(gB + (size_t)(n0 + r0) * D_DIM + k0);
        pb1 = *(const u16x8*)(gB + (size_t)(n0 + r1) * D_DIM + k0);
    };
    auto deposit = [&](int buf) {
        u16x8 o0, o1;
        o0[0] = f2us(fa0.x); o0[1] = f2us(fa0.y); o0[2] = f2us(fa0.z); o0[3] = f2us(fa0.w);
        o0[4] = f2us(fa1.x); o0[5] = f2us(fa1.y); o0[6] = f2us(fa1.z); o0[7] = f2us(fa1.w);
        o1[0] = f2us(fa2.x); o1[1] = f2us(fa2.y); o1[2] = f2us(fa2.z); o1[3] = f2us(fa2.w);
        o1[4] = f2us(fa3.x); o1[5] = f2us(fa3.y); o1[6] = f2us(fa3.z); o1[7] = f2us(fa3.w);
        *(u16x8*)&As[buf][r0][kq] = o0;
        *(u16x8*)&As[buf][r1][kq] = o1;
        *(u16x8*)&Bs[buf][r0][kq] = pb0;
        *(u16x8*)&Bs[buf][r1][kq] = pb1;
    };

    f32x4 acc[4][4] = {};

    prefetch(0);
    deposit(0);
    __syncthreads();

    const int NIT = D_DIM / 32;
    for (int k = 0; k < NIT; k++) {
        const int buf = k & 1;
        const bool more = (k + 1 < NIT);
        if (more) prefetch((k + 1) * 32);
        s16x8 a[4], b[4];
        #pragma unroll
        for (int m = 0; m < 4; m++) a[m] = *(const s16x8*)&As[buf][wtm + m * 16 + lc][qd * 8];
        #pragma unroll
        for (int n = 0; n < 4; n++) b[n] = *(const s16x8*)&Bs[buf][wtn + n * 16 + lc][qd * 8];
        #pragma unroll
        for (int m = 0; m < 4; m++)
            #pragma unroll
            for (int n = 0; n < 4; n++)
                acc[m][n] = __builtin_amdgcn_mfma_f32_16x16x32_bf16(a[m], b[n], acc[m][n], 0, 0, 0);
        if (more) {
            deposit(buf ^ 1);
            __syncthreads();
        }
    }

    #pragma unroll
    for (int m = 0; m < 4; m++) {
        #pragma unroll
        for (int r = 0; r < 4; r++) {
            int t = m0 + wtm + m * 16 + qd * 4 + r;
            #pragma unroll
            for (int n = 0; n < 4; n++) {
                int ng = n0 + wtn + n * 16 + lc;
                size_t ci = (size_t)t * HN + ng;
                float v = fmaxf(acc[m][n][r], 0.f);
                if constexpr (EPI == 1) {
                    xs[ci] = __float2bfloat16(v);
                    if constexpr (WQR) {
                        float pv = __shfl_xor(v, 1, 64);
                        int p = (ng % N_DIM) >> 1;
                        ushort2 cs = csT[(size_t)t * NP2 + p];
                        float c = us2f(cs.x), s = us2f(cs.y);
                        float o = (lc & 1) ? (v * c + pv * s) : (v * c - pv * s);
                        qr[ci] = __float2bfloat16(o);
                    }
                } else {
                    bf16* cp = xs + ci;
                    *cp = __float2bfloat16(b2f(*cp) * v);
                }
            }
        }
    }
}

// ---------------------------------------------------------------------------
// mfma_gemm (64x64, double-buffered): ykv (causal), ymlp slabs, logits.
// ---------------------------------------------------------------------------
template <typename TA, bool CAUSAL, bool SPLITK>
__launch_bounds__(256)
__global__ void mfma_gemm(const TA* __restrict__ A, const bf16* __restrict__ Bt,
                          float* __restrict__ C,
                          int K, int kSeg, int lda, int ldb, int ldc,
                          long aZ, long bZ, long cZ) {
    __shared__ short As[2][64][40];
    __shared__ short Bs[2][64][40];

    const int z = blockIdx.z;
    A += aZ * z;  Bt += bZ * z;  C += cZ * z;

    const int tid = threadIdx.x;
    const int n0 = blockIdx.x * 64, m0 = blockIdx.y * 64;
    const int srow = tid >> 2, sk = (tid & 3) * 8;
    const int lane = tid & 63, w = tid >> 6, qd = lane >> 4, lc = lane & 15;

    int kBeg, kEnd;
    if (SPLITK) { kBeg = z * kSeg; kEnd = kBeg + kSeg; }
    else        { kBeg = 0; kEnd = CAUSAL ? (m0 + 64 < K ? m0 + 64 : K) : K; }

    const TA*   ga = A  + (size_t)(m0 + srow) * lda + sk;
    const bf16* gb = Bt + (size_t)(n0 + srow) * ldb + sk;

    float4 f0, f1;
    u16x8 paw, pbw;
    auto prefetch = [&](int k0) {
        if constexpr (__is_same(TA, float)) {
            f0 = *(const float4*)(ga + k0);
            f1 = *(const float4*)(ga + k0 + 4);
        } else {
            paw = *(const u16x8*)(ga + k0);
        }
        pbw = *(const u16x8*)(gb + k0);
    };
    auto deposit = [&](int buf) {
        if constexpr (__is_same(TA, float)) {
            u16x8 o;
            o[0] = f2us(f0.x); o[1] = f2us(f0.y); o[2] = f2us(f0.z); o[3] = f2us(f0.w);
            o[4] = f2us(f1.x); o[5] = f2us(f1.y); o[6] = f2us(f1.z); o[7] = f2us(f1.w);
            *(u16x8*)&As[buf][srow][sk] = o;
        } else {
            *(u16x8*)&As[buf][srow][sk] = paw;
        }
        *(u16x8*)&Bs[buf][srow][sk] = pbw;
    };

    f32x4 acc[4] = {{0.f,0.f,0.f,0.f},{0.f,0.f,0.f,0.f},
                    {0.f,0.f,0.f,0.f},{0.f,0.f,0.f,0.f}};

    const int NIT = (kEnd - kBeg) / 32;
    prefetch(kBeg);
    deposit(0);
    __syncthreads();

    for (int k = 0; k < NIT; k++) {
        const int buf = k & 1;
        const bool more = (k + 1 < NIT);
        if (more) prefetch(kBeg + (k + 1) * 32);
        s16x8 a = *(const s16x8*)&As[buf][w * 16 + lc][qd * 8];
        s16x8 b[4];
        #pragma unroll
        for (int j = 0; j < 4; j++) b[j] = *(const s16x8*)&Bs[buf][j * 16 + lc][qd * 8];
        #pragma unroll
        for (int j = 0; j < 4; j++)
            acc[j] = __builtin_amdgcn_mfma_f32_16x16x32_bf16(a, b[j], acc[j], 0, 0, 0);
        if (more) {
            deposit(buf ^ 1);
            __syncthreads();
        }
    }

    #pragma unroll
    for (int j = 0; j < 4; j++) {
        int n = n0 + j * 16 + lc;
        #pragma unroll
        for (int r = 0; r < 4; r++) {
            int m = m0 + w * 16 + qd * 4 + r;
            C[(size_t)m * ldc + n] = acc[j][r];
        }
    }
}

extern "C" void kernel_launch(void* const* d_in, const int* in_sizes, int n_in,
                              void* d_out, int out_size, void* d_ws, size_t ws_size,
                              hipStream_t stream) {
    const int*   idx   = (const int*)  d_in[0];
    const float* dec_x = (const float*)d_in[1];   // (NH, D, N)
    const float* dec_y = (const float*)d_in[2];   // (NH, D, N)
    const float* enc   = (const float*)d_in[3];   // (NH*N, D)
    const float* emb   = (const float*)d_in[4];   // (VOCAB, D)
    const float* pose  = (const float*)d_in[5];   // (BLOCK, D)
    const float* lmh   = (const float*)d_in[6];   // (D, VOCAB)
    float* out = (float*)d_out;                   // (T, VOCAB) fp32

    // workspace layout — identical to passing r11 (ws >= 84,377,600 proven)
    char* wp = (char*)d_ws;
    float*   x    = (float*)wp;              wp += (size_t)T_SEQ * D_DIM * 4;
    bf16*    xs   = (bf16*)wp;               wp += (size_t)T_SEQ * HN * 2;
    ushort2* csT  = (ushort2*)wp;            wp += (size_t)T_SEQ * NP2 * 4;
    bf16*    sc   = (bf16*)wp;               wp += (size_t)NHEAD * T_SEQ * T_SEQ * 2;
    float*   ykv  = (float*)wp;              wp += (size_t)NHEAD * T_SEQ * D_DIM * 4;
    float*   ymlp = (float*)wp;              wp += (size_t)T_SEQ * D_DIM * 4;   // layout keeper
    bf16*    xT   = (bf16*)wp;               wp += (size_t)D_DIM * T_SEQ * 2;
    bf16*    wX   = (bf16*)wp;               wp += (size_t)NHEAD * N_DIM * D_DIM * 2;
    bf16*    wY   = (bf16*)wp;               wp += (size_t)NHEAD * N_DIM * D_DIM * 2;
    bf16*    wE   = (bf16*)wp;               wp += (size_t)D_DIM * HN * 2;
    bf16*    wL   = (bf16*)wp;               wp += (size_t)VOCABSZ * D_DIM * 2;
    const size_t BASE_NEED = (size_t)(wp - (char*)d_ws);
    bf16*    qr   = (bf16*)wp;
    const size_t FULL_NEED = BASE_NEED + (size_t)T_SEQ * HN * 2;
    float* ymlpP = (float*)sc;     // 8 slabs x T*D x 4B overlay on dead sc region
    bf16*  dbuf  = (bf16*)ykv;     // 512 KB diag partials overlay on idle ykv region

    if (ws_size < BASE_NEED) {
        fill_out<<<(out_size + 255) / 256, 256, 0, stream>>>(out, (float)ws_size, out_size);
        return;
    }
    const bool USE_QR = (ws_size >= FULL_NEED);

    // weight mirrors (bf16, [n][k])
    t_cvt<<<dim3(48, 3, 4), 256, 0, stream>>>(dec_x, wX, D_DIM, N_DIM,
                                              (long)D_DIM * N_DIM, (long)N_DIM * D_DIM);
    t_cvt<<<dim3(48, 3, 4), 256, 0, stream>>>(dec_y, wY, D_DIM, N_DIM,
                                              (long)D_DIM * N_DIM, (long)N_DIM * D_DIM);
    t_cvt<<<dim3(3, 192, 1), 256, 0, stream>>>(enc, wE, HN, D_DIM, 0L, 0L);
    t_cvt<<<dim3(4, 3, 1), 256, 0, stream>>>(lmh, wL, D_DIM, VOCABSZ, 0L, 0L);

    k_tables<<<(T_SEQ * NP2) / 256, 256, 0, stream>>>(csT);
    k_embed<<<T_SEQ, 64, 0, stream>>>(idx, emb, pose, x);

    for (int l = 0; l < NLAYER; ++l) {
        // xT = x^T (bf16) for ykv's B operand
        t_cvt<<<dim3(3, 16, 1), 256, 0, stream>>>(x, xT, T_SEQ, D_DIM, 0L, 0L);
        // xs = relu(x @ dec_x)  (+ fused qr when available)
        if (USE_QR) {
            dgemm128<1, true><<<dim3(96, 8), 256, 0, stream>>>(x, wX, xs, qr, csT);
            scores64<<<dim3(136, 2, NHEAD), 256, 0, stream>>>(qr, sc, dbuf);
            k_comb<<<dim3(136, 1, NHEAD), 256, 0, stream>>>(sc, dbuf);
        } else {
            dgemm128<1, false><<<dim3(96, 8), 256, 0, stream>>>(x, wX, xs, qr, csT);
            scores_fused<<<dim3(16, 16, NHEAD), 256, 0, stream>>>(xs, csT, sc);
        }
        // ykv = sc @ x   (causal)
        mfma_gemm<bf16, true, false><<<dim3(3, 16, NHEAD), 256, 0, stream>>>(
            sc, xT, ykv, T_SEQ, 0, T_SEQ, T_SEQ, D_DIM,
            (long)T_SEQ * T_SEQ, 0L, (long)T_SEQ * D_DIM);
        // ykv = LN(ykv)
        k_ln<<<NHEAD * T_SEQ, 64, 0, stream>>>(ykv);
        // xs *= relu(ykv @ dec_y)   (gate; head slab picked inside kernel)
        dgemm128<2, false><<<dim3(96, 8), 256, 0, stream>>>(
            (const float*)ykv, wY, xs, nullptr, nullptr);
        // ymlp partials = xy @ enc   (split-K=8 -> slabs in sc region)
        mfma_gemm<bf16, false, true><<<dim3(3, 16, 8), 256, 0, stream>>>(
            xs, wE, ymlpP, HN, HN / 8, HN, HN, D_DIM,
            0L, 0L, (long)T_SEQ * D_DIM);
        // x = LN(x + LN(sum partials))
        k_resid8<<<T_SEQ, 64, 0, stream>>>(x, ymlpP);
        (void)ymlp;
    }

    // logits = x @ lm_head
    mfma_gemm<float, false, false><<<dim3(4, 16, 1), 256, 0, stream>>>(
        x, wL, out, D_DIM, 0, D_DIM, D_DIM, VOCABSZ, 0L, 0L, 0L);
}

// Round 4
// 570.320 us; speedup vs baseline: 1.1735x; 1.0220x over previous
//
#include <hip/hip_runtime.h>
#include <hip/hip_bf16.h>

using bf16 = __hip_bfloat16;

#define D_DIM   192
#define N_DIM   3072
#define NHEAD   4
#define T_SEQ   1024
#define HN      12288      // NHEAD * N_DIM
#define NP2     1536       // N_DIM/2
#define VOCABSZ 256
#define NLAYER  4
#define LN_EPS  1e-5f
#define TWO_PI  6.2831853071795864f

typedef __attribute__((ext_vector_type(8))) short          s16x8;
typedef __attribute__((ext_vector_type(8))) unsigned short u16x8;
typedef __attribute__((ext_vector_type(4))) float          f32x4;

__device__ __forceinline__ float b2f(bf16 v) { return __bfloat162float(v); }
__device__ __forceinline__ float us2f(unsigned short u) {
    unsigned int x = ((unsigned int)u) << 16;
    return __builtin_bit_cast(float, x);
}
__device__ __forceinline__ unsigned short f2us(float f) {
    bf16 b = __float2bfloat16(f);
    return __builtin_bit_cast(unsigned short, b);
}

// sentinel: encode ws_size into output (fires only if ws too small)
__global__ void fill_out(float* __restrict__ out, float val, int nelem) {
    int i = blockIdx.x * 256 + threadIdx.x;
    if (i < nelem) out[i] = val;
}

// ---------------------------------------------------------------------------
// Tiled transpose + fp32->bf16: in fp32 [R][C] -> out bf16 [C][R].
// ---------------------------------------------------------------------------
__global__ void t_cvt(const float* __restrict__ in, bf16* __restrict__ out,
                      int R, int C, long inZ, long outZ) {
    __shared__ float tile[64][65];
    in  += inZ  * blockIdx.z;
    out += outZ * blockIdx.z;
    const int tx = threadIdx.x & 63, ty = threadIdx.x >> 6;
    const int r0 = blockIdx.y * 64, c0 = blockIdx.x * 64;
    #pragma unroll
    for (int rr = 0; rr < 16; rr++) {
        int row = ty * 16 + rr;
        tile[row][tx] = in[(size_t)(r0 + row) * C + c0 + tx];
    }
    __syncthreads();
    #pragma unroll
    for (int rr = 0; rr < 16; rr++) {
        int row = ty * 16 + rr;
        out[(size_t)(c0 + row) * R + r0 + tx] = __float2bfloat16(tile[tx][row]);
    }
}

// ---------------------------------------------------------------------------
// Wave-per-row LN family (64 threads/block, 3 elems/lane, butterfly reduce)
// ---------------------------------------------------------------------------
__device__ __forceinline__ void wave_sum2(float& s, float& ss) {
    #pragma unroll
    for (int off = 1; off < 64; off <<= 1) {
        s  += __shfl_xor(s,  off, 64);
        ss += __shfl_xor(ss, off, 64);
    }
}

__global__ void k_embed(const int* __restrict__ idx, const float* __restrict__ emb,
                        const float* __restrict__ pos, float* __restrict__ x) {
    int t = blockIdx.x, l = threadIdx.x;
    int tok = idx[t];
    const float* e = emb + tok * D_DIM;
    const float* p = pos + t * D_DIM;
    float v0 = e[l] + p[l], v1 = e[l + 64] + p[l + 64], v2 = e[l + 128] + p[l + 128];
    float s = v0 + v1 + v2, ss = v0 * v0 + v1 * v1 + v2 * v2;
    wave_sum2(s, ss);
    float m = s / D_DIM, r = rsqrtf(ss / D_DIM - m * m + LN_EPS);
    float* xr = x + t * D_DIM;
    xr[l] = (v0 - m) * r; xr[l + 64] = (v1 - m) * r; xr[l + 128] = (v2 - m) * r;
}

__global__ void k_ln(float* __restrict__ buf) {
    int l = threadIdx.x;
    float* row = buf + (size_t)blockIdx.x * D_DIM;
    float v0 = row[l], v1 = row[l + 64], v2 = row[l + 128];
    float s = v0 + v1 + v2, ss = v0 * v0 + v1 * v1 + v2 * v2;
    wave_sum2(s, ss);
    float m = s / D_DIM, r = rsqrtf(ss / D_DIM - m * m + LN_EPS);
    row[l] = (v0 - m) * r; row[l + 64] = (v1 - m) * r; row[l + 128] = (v2 - m) * r;
}

// x = LN(x + LN(sum of 8 split-K partial slabs))
__global__ void k_resid8(float* __restrict__ x, const float* __restrict__ P) {
    int l = threadIdx.x, t = blockIdx.x;
    float y0 = 0.f, y1 = 0.f, y2 = 0.f;
    #pragma unroll
    for (int p = 0; p < 8; p++) {
        const float* r = P + (size_t)p * T_SEQ * D_DIM + (size_t)t * D_DIM;
        y0 += r[l]; y1 += r[l + 64]; y2 += r[l + 128];
    }
    float* xr = x + (size_t)t * D_DIM;
    float s = y0 + y1 + y2, ss = y0 * y0 + y1 * y1 + y2 * y2;
    wave_sum2(s, ss);
    float m1 = s / D_DIM, r1 = rsqrtf(ss / D_DIM - m1 * m1 + LN_EPS);
    float v0 = xr[l] + (y0 - m1) * r1;
    float v1 = xr[l + 64] + (y1 - m1) * r1;
    float v2 = xr[l + 128] + (y2 - m1) * r1;
    s = v0 + v1 + v2; ss = v0 * v0 + v1 * v1 + v2 * v2;
    wave_sum2(s, ss);
    float m2 = s / D_DIM, r2 = rsqrtf(ss / D_DIM - m2 * m2 + LN_EPS);
    xr[l] = (v0 - m2) * r2; xr[l + 64] = (v1 - m2) * r2; xr[l + 128] = (v2 - m2) * r2;
}

// RoPE cos/sin tables, interleaved bf16 pairs csT[t][p] = (cos, sin)
__global__ void k_tables(ushort2* __restrict__ csT) {
    int gid = blockIdx.x * 256 + threadIdx.x;
    int t = gid / NP2, p = gid % NP2;
    float qf = (float)(2 * p);
    float f = 1.0f / powf(65536.0f, qf / 3072.0f) / (float)TWO_PI;
    float ph = fmodf((float)t * f, 1.0f) * (float)TWO_PI;
    ushort2 cs;
    cs.x = f2us(cosf(ph));
    cs.y = f2us(sinf(ph));
    csT[gid] = cs;
}

// ---------------------------------------------------------------------------
// scores64: sc[h,t,s] = dot(qr[t,h], qr[s,h]) for s<t, else 0.
// Split-K=2 over grid.y (1088 blocks): kh=0 -> lower tile (i,j); kh=1 with
// swapped operands -> mirror tile (j,i) (or dbuf slab for diagonal).
// k_comb adds the partials. 64x64 tile, 4 waves x (32x32), BK=64,
// double-buffered LDS + 2-deep register prefetch. Rows padded to 72 shorts.
// XCD-chunked L remap (136 = 8*17).
// ---------------------------------------------------------------------------
__launch_bounds__(256, 4)
__global__ void scores64(const bf16* __restrict__ qr, bf16* __restrict__ sc,
                         bf16* __restrict__ dbuf) {
    const int h  = blockIdx.z;
    const int kh = blockIdx.y;                     // K-half
    const int orig = blockIdx.x;
    const int L = (orig & 7) * 17 + (orig >> 3);   // bijective: 136 = 8*17
    int i = 0;
    while (((i + 1) * (i + 2)) >> 1 <= L) ++i;
    int j = L - ((i * (i + 1)) >> 1);
    const int t0 = i * 64, s0 = j * 64;
    const bool diag = (i == j);

    // operand roles: kh=1 off-diag computes the transposed tile directly
    int arow = t0, brow = s0;
    if (kh == 1 && !diag) { arow = s0; brow = t0; }

    __shared__ short As[2][64][72];
    __shared__ short Bs[2][64][72];

    const int tid = threadIdx.x;
    const int lane = tid & 63, w = tid >> 6, qd = lane >> 4, lc = lane & 15;
    const int wtm = (w >> 1) * 32, wtn = (w & 1) * 32;
    const int r0 = tid >> 2;                     // staging row 0..63
    const int kq = (tid & 3) * 16;               // staging k-offset (0,16,32,48)

    const int kBeg = kh * (N_DIM / 2);
    const bf16* gA = qr + (size_t)(arow + r0) * HN + h * N_DIM + kBeg + kq;
    const bf16* gB = qr + (size_t)(brow + r0) * HN + h * N_DIM + kBeg + kq;

    // two named register sets (static indexing only — no scratch)
    u16x8 pa0, pa1, pb0, pb1;   // set 0: even iters
    u16x8 qa0, qa1, qb0, qb1;   // set 1: odd iters
    auto load0 = [&](int k0) {
        pa0 = *(const u16x8*)(gA + k0);
        pa1 = *(const u16x8*)(gA + k0 + 8);
        pb0 = *(const u16x8*)(gB + k0);
        pb1 = *(const u16x8*)(gB + k0 + 8);
    };
    auto load1 = [&](int k0) {
        qa0 = *(const u16x8*)(gA + k0);
        qa1 = *(const u16x8*)(gA + k0 + 8);
        qb0 = *(const u16x8*)(gB + k0);
        qb1 = *(const u16x8*)(gB + k0 + 8);
    };
    auto dep0 = [&](int buf) {
        *(u16x8*)&As[buf][r0][kq]     = pa0;
        *(u16x8*)&As[buf][r0][kq + 8] = pa1;
        *(u16x8*)&Bs[buf][r0][kq]     = pb0;
        *(u16x8*)&Bs[buf][r0][kq + 8] = pb1;
    };
    auto dep1 = [&](int buf) {
        *(u16x8*)&As[buf][r0][kq]     = qa0;
        *(u16x8*)&As[buf][r0][kq + 8] = qa1;
        *(u16x8*)&Bs[buf][r0][kq]     = qb0;
        *(u16x8*)&Bs[buf][r0][kq + 8] = qb1;
    };

    f32x4 acc[2][2] = {};
    auto mfma_step = [&](int buf) {
        #pragma unroll
        for (int half = 0; half < 2; half++) {
            s16x8 a[2], b[2];
            #pragma unroll
            for (int m = 0; m < 2; m++)
                a[m] = *(const s16x8*)&As[buf][wtm + m * 16 + lc][qd * 8 + half * 32];
            #pragma unroll
            for (int n = 0; n < 2; n++)
                b[n] = *(const s16x8*)&Bs[buf][wtn + n * 16 + lc][qd * 8 + half * 32];
            #pragma unroll
            for (int m = 0; m < 2; m++)
                #pragma unroll
                for (int n = 0; n < 2; n++)
                    acc[m][n] = __builtin_amdgcn_mfma_f32_16x16x32_bf16(a[m], b[n], acc[m][n], 0, 0, 0);
        }
    };

    const int NIT = (N_DIM / 2) / 64;   // 24 (even)
    // prologue: set0 <- iter0, set1 <- iter1
    load0(0);
    load1(64);
    dep0(0);
    __syncthreads();

    for (int k = 0; k < NIT; k += 2) {
        // even iter k: compute buf0; deposit set1 -> buf1; refill set0 <- k+2
        if (k + 2 < NIT) load0((k + 2) * 64);
        mfma_step(0);
        if (k + 1 < NIT) dep1(1);
        __syncthreads();
        // odd iter k+1: compute buf1; deposit set0 -> buf0; refill set1 <- k+3
        if (k + 1 < NIT) {
            if (k + 3 < NIT) load1((k + 3) * 64);
            mfma_step(1);
            if (k + 2 < NIT) dep0(0);
            __syncthreads();
        }
    }

    if (kh == 1 && diag) {
        // diagonal second-half partial -> dbuf slab [64][64], masked
        bf16* P = dbuf + (size_t)(h * 16 + i) * 4096;
        #pragma unroll
        for (int m = 0; m < 2; m++) {
            #pragma unroll
            for (int r = 0; r < 4; r++) {
                int lt = wtm + m * 16 + qd * 4 + r;
                #pragma unroll
                for (int n = 0; n < 2; n++) {
                    int ls = wtn + n * 16 + lc;
                    P[lt * 64 + ls] = __float2bfloat16(ls >= lt ? 0.f : acc[m][n][r]);
                }
            }
        }
    } else {
        // kh0: tile (i,j) at rows t0, cols s0 (masked if diag).
        // kh1 off-diag: transposed tile at rows s0, cols t0 (mirror slot).
        bf16* C = sc + (size_t)h * T_SEQ * T_SEQ;
        const bool msk = (kh == 0) && diag;
        #pragma unroll
        for (int m = 0; m < 2; m++) {
            #pragma unroll
            for (int r = 0; r < 4; r++) {
                int t = arow + wtm + m * 16 + qd * 4 + r;
                #pragma unroll
                for (int n = 0; n < 2; n++) {
                    int s = brow + wtn + n * 16 + lc;
                    float v = (msk && s >= t) ? 0.f : acc[m][n][r];
                    C[(size_t)t * T_SEQ + s] = __float2bfloat16(v);
                }
            }
        }
    }
}

// ---------------------------------------------------------------------------
// k_comb: sc lower tile (i,j) += second-half partial (mirror tile (j,i),
// transposed via LDS; or dbuf slab for diagonal tiles).
// ---------------------------------------------------------------------------
__global__ void k_comb(bf16* __restrict__ sc, const bf16* __restrict__ dbuf) {
    __shared__ short tile[64][72];
    const int h = blockIdx.z;
    int L = blockIdx.x;
    int i = 0;
    while (((i + 1) * (i + 2)) >> 1 <= L) ++i;
    int j = L - ((i * (i + 1)) >> 1);
    bf16* C = sc + (size_t)h * T_SEQ * T_SEQ;
    const int r  = threadIdx.x >> 3;          // 0..31
    const int c8 = (threadIdx.x & 7) * 8;     // 0,8,...,56
    if (i != j) {
        // mirror tile P[s_local][t_local] lives at rows j*64.., cols i*64..
        #pragma unroll
        for (int p = 0; p < 2; p++) {
            int row = r + p * 32;
            u16x8 v = *(const u16x8*)(C + (size_t)(j * 64 + row) * T_SEQ + i * 64 + c8);
            *(u16x8*)&tile[row][c8] = v;
        }
        __syncthreads();
        #pragma unroll
        for (int p = 0; p < 2; p++) {
            int row = r + p * 32;             // t_local
            size_t off = (size_t)(i * 64 + row) * T_SEQ + j * 64 + c8;
            u16x8 a = *(const u16x8*)(C + off);
            u16x8 o;
            #pragma unroll
            for (int e = 0; e < 8; e++)
                o[e] = f2us(us2f(a[e]) + us2f((unsigned short)tile[c8 + e][row]));
            *(u16x8*)(C + off) = o;
        }
    } else {
        const bf16* P = dbuf + (size_t)(h * 16 + i) * 4096;
        #pragma unroll
        for (int p = 0; p < 2; p++) {
            int row = r + p * 32;
            size_t off = (size_t)(i * 64 + row) * T_SEQ + i * 64 + c8;
            u16x8 a = *(const u16x8*)(C + off);
            u16x8 b = *(const u16x8*)((const unsigned short*)P + row * 64 + c8);
            u16x8 o;
            #pragma unroll
            for (int e = 0; e < 8; e++)
                o[e] = f2us(us2f(a[e]) + us2f(b[e]));
            *(u16x8*)(C + off) = o;
        }
    }
}

// ---------------------------------------------------------------------------
// scores fallback (no qr buffer): 64x64, rope fused into staging.
// ---------------------------------------------------------------------------
__device__ __forceinline__ void stage_rope8(short* dst, const bf16* src,
                                            const ushort2* csP) {
    u16x8 v  = *(const u16x8*)src;
    u16x8 cs = *(const u16x8*)csP;
    u16x8 o;
    #pragma unroll
    for (int i = 0; i < 4; i++) {
        float e  = us2f(v[2 * i]), od = us2f(v[2 * i + 1]);
        float c  = us2f(cs[2 * i]), s = us2f(cs[2 * i + 1]);
        o[2 * i]     = f2us(e * c - od * s);
        o[2 * i + 1] = f2us(od * c + e * s);
    }
    *(u16x8*)dst = o;
}

__launch_bounds__(256)
__global__ void scores_fused(const bf16* __restrict__ xs,
                             const ushort2* __restrict__ csT,
                             bf16* __restrict__ sc) {
    const int h  = blockIdx.z;
    const int s0 = blockIdx.x * 64, t0 = blockIdx.y * 64;
    if (s0 > t0) return;
    __shared__ short As[64][40];
    __shared__ short Bs[64][40];
    const int tid  = threadIdx.x;
    const int srow = tid >> 2, kq = (tid & 3) * 8;
    const int lane = tid & 63, w = tid >> 6, qd = lane >> 4, lc = lane & 15;
    const int tA = t0 + srow, tB = s0 + srow;
    const bf16* gA = xs + (size_t)tA * HN + h * N_DIM + kq;
    const bf16* gB = xs + (size_t)tB * HN + h * N_DIM + kq;
    const ushort2* cA = csT + (size_t)tA * NP2 + (kq >> 1);
    const ushort2* cB = csT + (size_t)tB * NP2 + (kq >> 1);
    f32x4 acc[4] = {{0.f,0.f,0.f,0.f},{0.f,0.f,0.f,0.f},
                    {0.f,0.f,0.f,0.f},{0.f,0.f,0.f,0.f}};
    for (int k0 = 0; k0 < N_DIM; k0 += 32) {
        stage_rope8(&As[srow][kq], gA + k0, cA + (k0 >> 1));
        stage_rope8(&Bs[srow][kq], gB + k0, cB + (k0 >> 1));
        __syncthreads();
        s16x8 a = *(const s16x8*)&As[w * 16 + lc][qd * 8];
        #pragma unroll
        for (int j = 0; j < 4; j++) {
            s16x8 b = *(const s16x8*)&Bs[j * 16 + lc][qd * 8];
            acc[j] = __builtin_amdgcn_mfma_f32_16x16x32_bf16(a, b, acc[j], 0, 0, 0);
        }
        __syncthreads();
    }
    bf16* C = sc + (size_t)h * T_SEQ * T_SEQ;
    const bool diag = (s0 == t0);
    const int tbase = t0 + w * 16 + qd * 4;
    #pragma unroll
    for (int j = 0; j < 4; j++) {
        int s = s0 + j * 16 + lc;
        #pragma unroll
        for (int r = 0; r < 4; r++) {
            int t = tbase + r;
            C[(size_t)t * T_SEQ + s] =
                __float2bfloat16((!diag || s < t) ? acc[j][r] : 0.f);
        }
    }
}

// ---------------------------------------------------------------------------
// dgemm128: 128x128 tile, 4 waves x (64x64), K=192, double-buffered pipeline.
// EPI 1: xs = relu(acc); if WQR also qr = rope(relu(acc)).
// EPI 2: xs *= relu(acc) in place; A advanced to head slab of ykv.
// Epilogue is LDS-staged: acc -> bf16 tile S[128][136] in the (dead) staging
// pool, then each thread emits 8x coalesced u16x8 stores. Rope pairs become
// in-lane (no shfl), cos/sin table reads become one u16x8 per 8 outputs.
// Replaces 128 scalar 2B stores + 64 shfl + 64 scattered 4B loads / thread.
// ---------------------------------------------------------------------------
template <int EPI, bool WQR>
__launch_bounds__(256)
__global__ void dgemm128(const float* __restrict__ A, const bf16* __restrict__ Bt,
                         bf16* __restrict__ xs, bf16* __restrict__ qr,
                         const ushort2* __restrict__ csT) {
    __shared__ __align__(16) short pool[2 * 2 * 128 * 40];   // 40 KB
    short (*As)[128][40] = (short(*)[128][40])pool;
    short (*Bs)[128][40] = (short(*)[128][40])(pool + 2 * 128 * 40);

    const int tid = threadIdx.x;
    const int lane = tid & 63, w = tid >> 6, qd = lane >> 4, lc = lane & 15;
    const int wtm = (w >> 1) * 64, wtn = (w & 1) * 64;
    const int n0 = blockIdx.x * 128, m0 = blockIdx.y * 128;
    if constexpr (EPI == 2) A += (size_t)(n0 / N_DIM) * T_SEQ * D_DIM;

    const int r0 = tid >> 2, r1 = r0 + 64;
    const int kq = (tid & 3) * 8;

    const float* gA = A  + kq;
    const bf16*  gB = Bt + kq;

    float4 fa0, fa1, fa2, fa3;
    u16x8 pb0, pb1;
    auto prefetch = [&](int k0) {
        const float* a0 = gA + (size_t)(m0 + r0) * D_DIM + k0;
        const float* a1 = gA + (size_t)(m0 + r1) * D_DIM + k0;
        fa0 = *(const float4*)a0; fa1 = *(const float4*)(a0 + 4);
        fa2 = *(const float4*)a1; fa3 = *(const float4*)(a1 + 4);
        pb0 = *(const u16x8*)(gB + (size_t)(n0 + r0) * D_DIM + k0);
        pb1 = *(const u16x8*)(gB + (size_t)(n0 + r1) * D_DIM + k0);
    };
    auto deposit = [&](int buf) {
        u16x8 o0, o1;
        o0[0] = f2us(fa0.x); o0[1] = f2us(fa0.y); o0[2] = f2us(fa0.z); o0[3] = f2us(fa0.w);
        o0[4] = f2us(fa1.x); o0[5] = f2us(fa1.y); o0[6] = f2us(fa1.z); o0[7] = f2us(fa1.w);
        o1[0] = f2us(fa2.x); o1[1] = f2us(fa2.y); o1[2] = f2us(fa2.z); o1[3] = f2us(fa2.w);
        o1[4] = f2us(fa3.x); o1[5] = f2us(fa3.y); o1[6] = f2us(fa3.z); o1[7] = f2us(fa3.w);
        *(u16x8*)&As[buf][r0][kq] = o0;
        *(u16x8*)&As[buf][r1][kq] = o1;
        *(u16x8*)&Bs[buf][r0][kq] = pb0;
        *(u16x8*)&Bs[buf][r1][kq] = pb1;
    };

    f32x4 acc[4][4] = {};

    prefetch(0);
    deposit(0);
    __syncthreads();

    const int NIT = D_DIM / 32;
    for (int k = 0; k < NIT; k++) {
        const int buf = k & 1;
        const bool more = (k + 1 < NIT);
        if (more) prefetch((k + 1) * 32);
        s16x8 a[4], b[4];
        #pragma unroll
        for (int m = 0; m < 4; m++) a[m] = *(const s16x8*)&As[buf][wtm + m * 16 + lc][qd * 8];
        #pragma unroll
        for (int n = 0; n < 4; n++) b[n] = *(const s16x8*)&Bs[buf][wtn + n * 16 + lc][qd * 8];
        #pragma unroll
        for (int m = 0; m < 4; m++)
            #pragma unroll
            for (int n = 0; n < 4; n++)
                acc[m][n] = __builtin_amdgcn_mfma_f32_16x16x32_bf16(a[m], b[n], acc[m][n], 0, 0, 0);
        if (more) {
            deposit(buf ^ 1);
            __syncthreads();
        }
    }

    // -------- LDS-staged epilogue --------
    __syncthreads();                       // all waves done reading As/Bs
    short (*S)[136] = (short(*)[136])pool; // 128 x 136 shorts = 34.8 KB <= 40 KB
    #pragma unroll
    for (int m = 0; m < 4; m++) {
        #pragma unroll
        for (int r = 0; r < 4; r++) {
            int tl = wtm + m * 16 + qd * 4 + r;
            #pragma unroll
            for (int n = 0; n < 4; n++) {
                int cl = wtn + n * 16 + lc;
                S[tl][cl] = (short)f2us(fmaxf(acc[m][n][r], 0.f));
            }
        }
    }
    __syncthreads();
    #pragma unroll
    for (int e = 0; e < 8; e++) {
        int idxe = tid + e * 256;
        int row = idxe >> 4, cg = idxe & 15;
        u16x8 v = *(const u16x8*)&S[row][cg * 8];
        int t = m0 + row, ngg = n0 + cg * 8;
        size_t ci = (size_t)t * HN + ngg;
        if constexpr (EPI == 1) {
            *(u16x8*)(xs + ci) = v;
            if constexpr (WQR) {
                int p0 = (ngg % N_DIM) >> 1;
                u16x8 cs8 = *(const u16x8*)&csT[(size_t)t * NP2 + p0];
                u16x8 o;
                #pragma unroll
                for (int q = 0; q < 4; q++) {
                    float ev = us2f(v[2 * q]), ov = us2f(v[2 * q + 1]);
                    float c = us2f(cs8[2 * q]), s = us2f(cs8[2 * q + 1]);
                    o[2 * q]     = f2us(ev * c - ov * s);
                    o[2 * q + 1] = f2us(ov * c + ev * s);
                }
                *(u16x8*)(qr + ci) = o;
            }
        } else {
            u16x8 g = *(const u16x8*)(xs + ci);
            u16x8 o;
            #pragma unroll
            for (int q = 0; q < 8; q++) o[q] = f2us(us2f(g[q]) * us2f(v[q]));
            *(u16x8*)(xs + ci) = o;
        }
    }
}

// ---------------------------------------------------------------------------
// mfma_gemm (64x64, double-buffered): ykv (causal), ymlp slabs, logits.
// ---------------------------------------------------------------------------
template <typename TA, bool CAUSAL, bool SPLITK>
__launch_bounds__(256)
__global__ void mfma_gemm(const TA* __restrict__ A, const bf16* __restrict__ Bt,
                          float* __restrict__ C,
                          int K, int kSeg, int lda, int ldb, int ldc,
                          long aZ, long bZ, long cZ) {
    __shared__ short As[2][64][40];
    __shared__ short Bs[2][64][40];

    const int z = blockIdx.z;
    A += aZ * z;  Bt += bZ * z;  C += cZ * z;

    const int tid = threadIdx.x;
    const int n0 = blockIdx.x * 64, m0 = blockIdx.y * 64;
    const int srow = tid >> 2, sk = (tid & 3) * 8;
    const int lane = tid & 63, w = tid >> 6, qd = lane >> 4, lc = lane & 15;

    int kBeg, kEnd;
    if (SPLITK) { kBeg = z * kSeg; kEnd = kBeg + kSeg; }
    else        { kBeg = 0; kEnd = CAUSAL ? (m0 + 64 < K ? m0 + 64 : K) : K; }

    const TA*   ga = A  + (size_t)(m0 + srow) * lda + sk;
    const bf16* gb = Bt + (size_t)(n0 + srow) * ldb + sk;

    float4 f0, f1;
    u16x8 paw, pbw;
    auto prefetch = [&](int k0) {
        if constexpr (__is_same(TA, float)) {
            f0 = *(const float4*)(ga + k0);
            f1 = *(const float4*)(ga + k0 + 4);
        } else {
            paw = *(const u16x8*)(ga + k0);
        }
        pbw = *(const u16x8*)(gb + k0);
    };
    auto deposit = [&](int buf) {
        if constexpr (__is_same(TA, float)) {
            u16x8 o;
            o[0] = f2us(f0.x); o[1] = f2us(f0.y); o[2] = f2us(f0.z); o[3] = f2us(f0.w);
            o[4] = f2us(f1.x); o[5] = f2us(f1.y); o[6] = f2us(f1.z); o[7] = f2us(f1.w);
            *(u16x8*)&As[buf][srow][sk] = o;
        } else {
            *(u16x8*)&As[buf][srow][sk] = paw;
        }
        *(u16x8*)&Bs[buf][srow][sk] = pbw;
    };

    f32x4 acc[4] = {{0.f,0.f,0.f,0.f},{0.f,0.f,0.f,0.f},
                    {0.f,0.f,0.f,0.f},{0.f,0.f,0.f,0.f}};

    const int NIT = (kEnd - kBeg) / 32;
    prefetch(kBeg);
    deposit(0);
    __syncthreads();

    for (int k = 0; k < NIT; k++) {
        const int buf = k & 1;
        const bool more = (k + 1 < NIT);
        if (more) prefetch(kBeg + (k + 1) * 32);
        s16x8 a = *(const s16x8*)&As[buf][w * 16 + lc][qd * 8];
        s16x8 b[4];
        #pragma unroll
        for (int j = 0; j < 4; j++) b[j] = *(const s16x8*)&Bs[buf][j * 16 + lc][qd * 8];
        #pragma unroll
        for (int j = 0; j < 4; j++)
            acc[j] = __builtin_amdgcn_mfma_f32_16x16x32_bf16(a, b[j], acc[j], 0, 0, 0);
        if (more) {
            deposit(buf ^ 1);
            __syncthreads();
        }
    }

    #pragma unroll
    for (int j = 0; j < 4; j++) {
        int n = n0 + j * 16 + lc;
        #pragma unroll
        for (int r = 0; r < 4; r++) {
            int m = m0 + w * 16 + qd * 4 + r;
            C[(size_t)m * ldc + n] = acc[j][r];
        }
    }
}

extern "C" void kernel_launch(void* const* d_in, const int* in_sizes, int n_in,
                              void* d_out, int out_size, void* d_ws, size_t ws_size,
                              hipStream_t stream) {
    const int*   idx   = (const int*)  d_in[0];
    const float* dec_x = (const float*)d_in[1];   // (NH, D, N)
    const float* dec_y = (const float*)d_in[2];   // (NH, D, N)
    const float* enc   = (const float*)d_in[3];   // (NH*N, D)
    const float* emb   = (const float*)d_in[4];   // (VOCAB, D)
    const float* pose  = (const float*)d_in[5];   // (BLOCK, D)
    const float* lmh   = (const float*)d_in[6];   // (D, VOCAB)
    float* out = (float*)d_out;                   // (T, VOCAB) fp32

    // workspace layout — identical to passing r11 (ws >= 84,377,600 proven)
    char* wp = (char*)d_ws;
    float*   x    = (float*)wp;              wp += (size_t)T_SEQ * D_DIM * 4;
    bf16*    xs   = (bf16*)wp;               wp += (size_t)T_SEQ * HN * 2;
    ushort2* csT  = (ushort2*)wp;            wp += (size_t)T_SEQ * NP2 * 4;
    bf16*    sc   = (bf16*)wp;               wp += (size_t)NHEAD * T_SEQ * T_SEQ * 2;
    float*   ykv  = (float*)wp;              wp += (size_t)NHEAD * T_SEQ * D_DIM * 4;
    float*   ymlp = (float*)wp;              wp += (size_t)T_SEQ * D_DIM * 4;   // layout keeper
    bf16*    xT   = (bf16*)wp;               wp += (size_t)D_DIM * T_SEQ * 2;
    bf16*    wX   = (bf16*)wp;               wp += (size_t)NHEAD * N_DIM * D_DIM * 2;
    bf16*    wY   = (bf16*)wp;               wp += (size_t)NHEAD * N_DIM * D_DIM * 2;
    bf16*    wE   = (bf16*)wp;               wp += (size_t)D_DIM * HN * 2;
    bf16*    wL   = (bf16*)wp;               wp += (size_t)VOCABSZ * D_DIM * 2;
    const size_t BASE_NEED = (size_t)(wp - (char*)d_ws);
    bf16*    qr   = (bf16*)wp;
    const size_t FULL_NEED = BASE_NEED + (size_t)T_SEQ * HN * 2;
    float* ymlpP = (float*)sc;     // 8 slabs x T*D x 4B overlay on dead sc region
    bf16*  dbuf  = (bf16*)ykv;     // 512 KB diag partials overlay on idle ykv region

    if (ws_size < BASE_NEED) {
        fill_out<<<(out_size + 255) / 256, 256, 0, stream>>>(out, (float)ws_size, out_size);
        return;
    }
    const bool USE_QR = (ws_size >= FULL_NEED);

    // weight mirrors (bf16, [n][k])
    t_cvt<<<dim3(48, 3, 4), 256, 0, stream>>>(dec_x, wX, D_DIM, N_DIM,
                                              (long)D_DIM * N_DIM, (long)N_DIM * D_DIM);
    t_cvt<<<dim3(48, 3, 4), 256, 0, stream>>>(dec_y, wY, D_DIM, N_DIM,
                                              (long)D_DIM * N_DIM, (long)N_DIM * D_DIM);
    t_cvt<<<dim3(3, 192, 1), 256, 0, stream>>>(enc, wE, HN, D_DIM, 0L, 0L);
    t_cvt<<<dim3(4, 3, 1), 256, 0, stream>>>(lmh, wL, D_DIM, VOCABSZ, 0L, 0L);

    k_tables<<<(T_SEQ * NP2) / 256, 256, 0, stream>>>(csT);
    k_embed<<<T_SEQ, 64, 0, stream>>>(idx, emb, pose, x);

    for (int l = 0; l < NLAYER; ++l) {
        // xT = x^T (bf16) for ykv's B operand
        t_cvt<<<dim3(3, 16, 1), 256, 0, stream>>>(x, xT, T_SEQ, D_DIM, 0L, 0L);
        // xs = relu(x @ dec_x)  (+ fused qr when available)
        if (USE_QR) {
            dgemm128<1, true><<<dim3(96, 8), 256, 0, stream>>>(x, wX, xs, qr, csT);
            scores64<<<dim3(136, 2, NHEAD), 256, 0, stream>>>(qr, sc, dbuf);
            k_comb<<<dim3(136, 1, NHEAD), 256, 0, stream>>>(sc, dbuf);
        } else {
            dgemm128<1, false><<<dim3(96, 8), 256, 0, stream>>>(x, wX, xs, qr, csT);
            scores_fused<<<dim3(16, 16, NHEAD), 256, 0, stream>>>(xs, csT, sc);
        }
        // ykv = sc @ x   (causal)
        mfma_gemm<bf16, true, false><<<dim3(3, 16, NHEAD), 256, 0, stream>>>(
            sc, xT, ykv, T_SEQ, 0, T_SEQ, T_SEQ, D_DIM,
            (long)T_SEQ * T_SEQ, 0L, (long)T_SEQ * D_DIM);
        // ykv = LN(ykv)
        k_ln<<<NHEAD * T_SEQ, 64, 0, stream>>>(ykv);
        // xs *= relu(ykv @ dec_y)   (gate; head slab picked inside kernel)
        dgemm128<2, false><<<dim3(96, 8), 256, 0, stream>>>(
            (const float*)ykv, wY, xs, nullptr, nullptr);
        // ymlp partials = xy @ enc   (split-K=8 -> slabs in sc region)
        mfma_gemm<bf16, false, true><<<dim3(3, 16, 8), 256, 0, stream>>>(
            xs, wE, ymlpP, HN, HN / 8, HN, HN, D_DIM,
            0L, 0L, (long)T_SEQ * D_DIM);
        // x = LN(x + LN(sum partials))
        k_resid8<<<T_SEQ, 64, 0, stream>>>(x, ymlpP);
        (void)ymlp;
    }

    // logits = x @ lm_head
    mfma_gemm<float, false, false><<<dim3(4, 16, 1), 256, 0, stream>>>(
        x, wL, out, D_DIM, 0, D_DIM, D_DIM, VOCABSZ, 0L, 0L, 0L);
}

// Round 5
// 562.471 us; speedup vs baseline: 1.1899x; 1.0140x over previous
//
#include <hip/hip_runtime.h>
#include <hip/hip_bf16.h>

using bf16 = __hip_bfloat16;

#define D_DIM   192
#define N_DIM   3072
#define NHEAD   4
#define T_SEQ   1024
#define HN      12288      // NHEAD * N_DIM
#define NP2     1536       // N_DIM/2
#define VOCABSZ 256
#define NLAYER  4
#define LN_EPS  1e-5f
#define TWO_PI  6.2831853071795864f

typedef __attribute__((ext_vector_type(8))) short          s16x8;
typedef __attribute__((ext_vector_type(8))) unsigned short u16x8;
typedef __attribute__((ext_vector_type(4))) float          f32x4;

__device__ __forceinline__ float b2f(bf16 v) { return __bfloat162float(v); }
__device__ __forceinline__ float us2f(unsigned short u) {
    unsigned int x = ((unsigned int)u) << 16;
    return __builtin_bit_cast(float, x);
}
__device__ __forceinline__ unsigned short f2us(float f) {
    bf16 b = __float2bfloat16(f);
    return __builtin_bit_cast(unsigned short, b);
}

// sentinel: encode ws_size into output (fires only if ws too small)
__global__ void fill_out(float* __restrict__ out, float val, int nelem) {
    int i = blockIdx.x * 256 + threadIdx.x;
    if (i < nelem) out[i] = val;
}

// ---------------------------------------------------------------------------
// Tiled transpose + fp32->bf16: in fp32 [R][C] -> out bf16 [C][R].
// ---------------------------------------------------------------------------
__global__ void t_cvt(const float* __restrict__ in, bf16* __restrict__ out,
                      int R, int C, long inZ, long outZ) {
    __shared__ float tile[64][65];
    in  += inZ  * blockIdx.z;
    out += outZ * blockIdx.z;
    const int tx = threadIdx.x & 63, ty = threadIdx.x >> 6;
    const int r0 = blockIdx.y * 64, c0 = blockIdx.x * 64;
    #pragma unroll
    for (int rr = 0; rr < 16; rr++) {
        int row = ty * 16 + rr;
        tile[row][tx] = in[(size_t)(r0 + row) * C + c0 + tx];
    }
    __syncthreads();
    #pragma unroll
    for (int rr = 0; rr < 16; rr++) {
        int row = ty * 16 + rr;
        out[(size_t)(c0 + row) * R + r0 + tx] = __float2bfloat16(tile[tx][row]);
    }
}

// ---------------------------------------------------------------------------
// Wave-per-row LN family (64 threads/block, 3 elems/lane, butterfly reduce)
// ---------------------------------------------------------------------------
__device__ __forceinline__ void wave_sum2(float& s, float& ss) {
    #pragma unroll
    for (int off = 1; off < 64; off <<= 1) {
        s  += __shfl_xor(s,  off, 64);
        ss += __shfl_xor(ss, off, 64);
    }
}

__global__ void k_embed(const int* __restrict__ idx, const float* __restrict__ emb,
                        const float* __restrict__ pos, float* __restrict__ x) {
    int t = blockIdx.x, l = threadIdx.x;
    int tok = idx[t];
    const float* e = emb + tok * D_DIM;
    const float* p = pos + t * D_DIM;
    float v0 = e[l] + p[l], v1 = e[l + 64] + p[l + 64], v2 = e[l + 128] + p[l + 128];
    float s = v0 + v1 + v2, ss = v0 * v0 + v1 * v1 + v2 * v2;
    wave_sum2(s, ss);
    float m = s / D_DIM, r = rsqrtf(ss / D_DIM - m * m + LN_EPS);
    float* xr = x + t * D_DIM;
    xr[l] = (v0 - m) * r; xr[l + 64] = (v1 - m) * r; xr[l + 128] = (v2 - m) * r;
}

__global__ void k_ln(float* __restrict__ buf) {
    int l = threadIdx.x;
    float* row = buf + (size_t)blockIdx.x * D_DIM;
    float v0 = row[l], v1 = row[l + 64], v2 = row[l + 128];
    float s = v0 + v1 + v2, ss = v0 * v0 + v1 * v1 + v2 * v2;
    wave_sum2(s, ss);
    float m = s / D_DIM, r = rsqrtf(ss / D_DIM - m * m + LN_EPS);
    row[l] = (v0 - m) * r; row[l + 64] = (v1 - m) * r; row[l + 128] = (v2 - m) * r;
}

// row = LN(row + P1row)  — fuses ykv split-K=2 slab sum into the LN pass
__global__ void k_ln2(float* __restrict__ buf, const float* __restrict__ P1) {
    int l = threadIdx.x;
    size_t off = (size_t)blockIdx.x * D_DIM;
    float* row = buf + off;
    const float* r1 = P1 + off;
    float v0 = row[l] + r1[l];
    float v1 = row[l + 64] + r1[l + 64];
    float v2 = row[l + 128] + r1[l + 128];
    float s = v0 + v1 + v2, ss = v0 * v0 + v1 * v1 + v2 * v2;
    wave_sum2(s, ss);
    float m = s / D_DIM, r = rsqrtf(ss / D_DIM - m * m + LN_EPS);
    row[l] = (v0 - m) * r; row[l + 64] = (v1 - m) * r; row[l + 128] = (v2 - m) * r;
}

// x = LN(x + LN(sum of 8 split-K partial slabs))
__global__ void k_resid8(float* __restrict__ x, const float* __restrict__ P) {
    int l = threadIdx.x, t = blockIdx.x;
    float y0 = 0.f, y1 = 0.f, y2 = 0.f;
    #pragma unroll
    for (int p = 0; p < 8; p++) {
        const float* r = P + (size_t)p * T_SEQ * D_DIM + (size_t)t * D_DIM;
        y0 += r[l]; y1 += r[l + 64]; y2 += r[l + 128];
    }
    float* xr = x + (size_t)t * D_DIM;
    float s = y0 + y1 + y2, ss = y0 * y0 + y1 * y1 + y2 * y2;
    wave_sum2(s, ss);
    float m1 = s / D_DIM, r1 = rsqrtf(ss / D_DIM - m1 * m1 + LN_EPS);
    float v0 = xr[l] + (y0 - m1) * r1;
    float v1 = xr[l + 64] + (y1 - m1) * r1;
    float v2 = xr[l + 128] + (y2 - m1) * r1;
    s = v0 + v1 + v2; ss = v0 * v0 + v1 * v1 + v2 * v2;
    wave_sum2(s, ss);
    float m2 = s / D_DIM, r2 = rsqrtf(ss / D_DIM - m2 * m2 + LN_EPS);
    xr[l] = (v0 - m2) * r2; xr[l + 64] = (v1 - m2) * r2; xr[l + 128] = (v2 - m2) * r2;
}

// RoPE cos/sin tables, interleaved bf16 pairs csT[t][p] = (cos, sin)
__global__ void k_tables(ushort2* __restrict__ csT) {
    int gid = blockIdx.x * 256 + threadIdx.x;
    int t = gid / NP2, p = gid % NP2;
    float qf = (float)(2 * p);
    float f = 1.0f / powf(65536.0f, qf / 3072.0f) / (float)TWO_PI;
    float ph = fmodf((float)t * f, 1.0f) * (float)TWO_PI;
    ushort2 cs;
    cs.x = f2us(cosf(ph));
    cs.y = f2us(sinf(ph));
    csT[gid] = cs;
}

// ---------------------------------------------------------------------------
// scores64: sc[h,t,s] = dot(qr[t,h], qr[s,h]) for s<t, else 0.
// Split-K=2 over grid.y (1088 blocks): kh=0 -> lower tile (i,j); kh=1 with
// swapped operands -> mirror tile (j,i) (or dbuf slab for diagonal).
// k_comb adds the partials. 64x64 tile, 4 waves x (32x32), BK=64,
// double-buffered LDS + 2-deep register prefetch. Rows padded to 72 shorts.
// XCD-chunked L remap (136 = 8*17).
// ---------------------------------------------------------------------------
__launch_bounds__(256, 4)
__global__ void scores64(const bf16* __restrict__ qr, bf16* __restrict__ sc,
                         bf16* __restrict__ dbuf) {
    const int h  = blockIdx.z;
    const int kh = blockIdx.y;                     // K-half
    const int orig = blockIdx.x;
    const int L = (orig & 7) * 17 + (orig >> 3);   // bijective: 136 = 8*17
    int i = 0;
    while (((i + 1) * (i + 2)) >> 1 <= L) ++i;
    int j = L - ((i * (i + 1)) >> 1);
    const int t0 = i * 64, s0 = j * 64;
    const bool diag = (i == j);

    // operand roles: kh=1 off-diag computes the transposed tile directly
    int arow = t0, brow = s0;
    if (kh == 1 && !diag) { arow = s0; brow = t0; }

    __shared__ short As[2][64][72];
    __shared__ short Bs[2][64][72];

    const int tid = threadIdx.x;
    const int lane = tid & 63, w = tid >> 6, qd = lane >> 4, lc = lane & 15;
    const int wtm = (w >> 1) * 32, wtn = (w & 1) * 32;
    const int r0 = tid >> 2;                     // staging row 0..63
    const int kq = (tid & 3) * 16;               // staging k-offset (0,16,32,48)

    const int kBeg = kh * (N_DIM / 2);
    const bf16* gA = qr + (size_t)(arow + r0) * HN + h * N_DIM + kBeg + kq;
    const bf16* gB = qr + (size_t)(brow + r0) * HN + h * N_DIM + kBeg + kq;

    // two named register sets (static indexing only — no scratch)
    u16x8 pa0, pa1, pb0, pb1;   // set 0: even iters
    u16x8 qa0, qa1, qb0, qb1;   // set 1: odd iters
    auto load0 = [&](int k0) {
        pa0 = *(const u16x8*)(gA + k0);
        pa1 = *(const u16x8*)(gA + k0 + 8);
        pb0 = *(const u16x8*)(gB + k0);
        pb1 = *(const u16x8*)(gB + k0 + 8);
    };
    auto load1 = [&](int k0) {
        qa0 = *(const u16x8*)(gA + k0);
        qa1 = *(const u16x8*)(gA + k0 + 8);
        qb0 = *(const u16x8*)(gB + k0);
        qb1 = *(const u16x8*)(gB + k0 + 8);
    };
    auto dep0 = [&](int buf) {
        *(u16x8*)&As[buf][r0][kq]     = pa0;
        *(u16x8*)&As[buf][r0][kq + 8] = pa1;
        *(u16x8*)&Bs[buf][r0][kq]     = pb0;
        *(u16x8*)&Bs[buf][r0][kq + 8] = pb1;
    };
    auto dep1 = [&](int buf) {
        *(u16x8*)&As[buf][r0][kq]     = qa0;
        *(u16x8*)&As[buf][r0][kq + 8] = qa1;
        *(u16x8*)&Bs[buf][r0][kq]     = qb0;
        *(u16x8*)&Bs[buf][r0][kq + 8] = qb1;
    };

    f32x4 acc[2][2] = {};
    auto mfma_step = [&](int buf) {
        #pragma unroll
        for (int half = 0; half < 2; half++) {
            s16x8 a[2], b[2];
            #pragma unroll
            for (int m = 0; m < 2; m++)
                a[m] = *(const s16x8*)&As[buf][wtm + m * 16 + lc][qd * 8 + half * 32];
            #pragma unroll
            for (int n = 0; n < 2; n++)
                b[n] = *(const s16x8*)&Bs[buf][wtn + n * 16 + lc][qd * 8 + half * 32];
            #pragma unroll
            for (int m = 0; m < 2; m++)
                #pragma unroll
                for (int n = 0; n < 2; n++)
                    acc[m][n] = __builtin_amdgcn_mfma_f32_16x16x32_bf16(a[m], b[n], acc[m][n], 0, 0, 0);
        }
    };

    const int NIT = (N_DIM / 2) / 64;   // 24 (even)
    // prologue: set0 <- iter0, set1 <- iter1
    load0(0);
    load1(64);
    dep0(0);
    __syncthreads();

    for (int k = 0; k < NIT; k += 2) {
        // even iter k: compute buf0; deposit set1 -> buf1; refill set0 <- k+2
        if (k + 2 < NIT) load0((k + 2) * 64);
        mfma_step(0);
        if (k + 1 < NIT) dep1(1);
        __syncthreads();
        // odd iter k+1: compute buf1; deposit set0 -> buf0; refill set1 <- k+3
        if (k + 1 < NIT) {
            if (k + 3 < NIT) load1((k + 3) * 64);
            mfma_step(1);
            if (k + 2 < NIT) dep0(0);
            __syncthreads();
        }
    }

    if (kh == 1 && diag) {
        // diagonal second-half partial -> dbuf slab [64][64], masked
        bf16* P = dbuf + (size_t)(h * 16 + i) * 4096;
        #pragma unroll
        for (int m = 0; m < 2; m++) {
            #pragma unroll
            for (int r = 0; r < 4; r++) {
                int lt = wtm + m * 16 + qd * 4 + r;
                #pragma unroll
                for (int n = 0; n < 2; n++) {
                    int ls = wtn + n * 16 + lc;
                    P[lt * 64 + ls] = __float2bfloat16(ls >= lt ? 0.f : acc[m][n][r]);
                }
            }
        }
    } else {
        // kh0: tile (i,j) at rows t0, cols s0 (masked if diag).
        // kh1 off-diag: transposed tile at rows s0, cols t0 (mirror slot).
        bf16* C = sc + (size_t)h * T_SEQ * T_SEQ;
        const bool msk = (kh == 0) && diag;
        #pragma unroll
        for (int m = 0; m < 2; m++) {
            #pragma unroll
            for (int r = 0; r < 4; r++) {
                int t = arow + wtm + m * 16 + qd * 4 + r;
                #pragma unroll
                for (int n = 0; n < 2; n++) {
                    int s = brow + wtn + n * 16 + lc;
                    float v = (msk && s >= t) ? 0.f : acc[m][n][r];
                    C[(size_t)t * T_SEQ + s] = __float2bfloat16(v);
                }
            }
        }
    }
}

// ---------------------------------------------------------------------------
// k_comb: sc lower tile (i,j) += second-half partial (mirror tile (j,i),
// transposed via LDS; or dbuf slab for diagonal tiles).
// ---------------------------------------------------------------------------
__global__ void k_comb(bf16* __restrict__ sc, const bf16* __restrict__ dbuf) {
    __shared__ short tile[64][72];
    const int h = blockIdx.z;
    int L = blockIdx.x;
    int i = 0;
    while (((i + 1) * (i + 2)) >> 1 <= L) ++i;
    int j = L - ((i * (i + 1)) >> 1);
    bf16* C = sc + (size_t)h * T_SEQ * T_SEQ;
    const int r  = threadIdx.x >> 3;          // 0..31
    const int c8 = (threadIdx.x & 7) * 8;     // 0,8,...,56
    if (i != j) {
        // mirror tile P[s_local][t_local] lives at rows j*64.., cols i*64..
        #pragma unroll
        for (int p = 0; p < 2; p++) {
            int row = r + p * 32;
            u16x8 v = *(const u16x8*)(C + (size_t)(j * 64 + row) * T_SEQ + i * 64 + c8);
            *(u16x8*)&tile[row][c8] = v;
        }
        __syncthreads();
        #pragma unroll
        for (int p = 0; p < 2; p++) {
            int row = r + p * 32;             // t_local
            size_t off = (size_t)(i * 64 + row) * T_SEQ + j * 64 + c8;
            u16x8 a = *(const u16x8*)(C + off);
            u16x8 o;
            #pragma unroll
            for (int e = 0; e < 8; e++)
                o[e] = f2us(us2f(a[e]) + us2f((unsigned short)tile[c8 + e][row]));
            *(u16x8*)(C + off) = o;
        }
    } else {
        const bf16* P = dbuf + (size_t)(h * 16 + i) * 4096;
        #pragma unroll
        for (int p = 0; p < 2; p++) {
            int row = r + p * 32;
            size_t off = (size_t)(i * 64 + row) * T_SEQ + i * 64 + c8;
            u16x8 a = *(const u16x8*)(C + off);
            u16x8 b = *(const u16x8*)((const unsigned short*)P + row * 64 + c8);
            u16x8 o;
            #pragma unroll
            for (int e = 0; e < 8; e++)
                o[e] = f2us(us2f(a[e]) + us2f(b[e]));
            *(u16x8*)(C + off) = o;
        }
    }
}

// ---------------------------------------------------------------------------
// scores fallback (no qr buffer): 64x64, rope fused into staging.
// ---------------------------------------------------------------------------
__device__ __forceinline__ void stage_rope8(short* dst, const bf16* src,
                                            const ushort2* csP) {
    u16x8 v  = *(const u16x8*)src;
    u16x8 cs = *(const u16x8*)csP;
    u16x8 o;
    #pragma unroll
    for (int i = 0; i < 4; i++) {
        float e  = us2f(v[2 * i]), od = us2f(v[2 * i + 1]);
        float c  = us2f(cs[2 * i]), s = us2f(cs[2 * i + 1]);
        o[2 * i]     = f2us(e * c - od * s);
        o[2 * i + 1] = f2us(od * c + e * s);
    }
    *(u16x8*)dst = o;
}

__launch_bounds__(256)
__global__ void scores_fused(const bf16* __restrict__ xs,
                             const ushort2* __restrict__ csT,
                             bf16* __restrict__ sc) {
    const int h  = blockIdx.z;
    const int s0 = blockIdx.x * 64, t0 = blockIdx.y * 64;
    if (s0 > t0) return;
    __shared__ short As[64][40];
    __shared__ short Bs[64][40];
    const int tid  = threadIdx.x;
    const int srow = tid >> 2, kq = (tid & 3) * 8;
    const int lane = tid & 63, w = tid >> 6, qd = lane >> 4, lc = lane & 15;
    const int tA = t0 + srow, tB = s0 + srow;
    const bf16* gA = xs + (size_t)tA * HN + h * N_DIM + kq;
    const bf16* gB = xs + (size_t)tB * HN + h * N_DIM + kq;
    const ushort2* cA = csT + (size_t)tA * NP2 + (kq >> 1);
    const ushort2* cB = csT + (size_t)tB * NP2 + (kq >> 1);
    f32x4 acc[4] = {{0.f,0.f,0.f,0.f},{0.f,0.f,0.f,0.f},
                    {0.f,0.f,0.f,0.f},{0.f,0.f,0.f,0.f}};
    for (int k0 = 0; k0 < N_DIM; k0 += 32) {
        stage_rope8(&As[srow][kq], gA + k0, cA + (k0 >> 1));
        stage_rope8(&Bs[srow][kq], gB + k0, cB + (k0 >> 1));
        __syncthreads();
        s16x8 a = *(const s16x8*)&As[w * 16 + lc][qd * 8];
        #pragma unroll
        for (int j = 0; j < 4; j++) {
            s16x8 b = *(const s16x8*)&Bs[j * 16 + lc][qd * 8];
            acc[j] = __builtin_amdgcn_mfma_f32_16x16x32_bf16(a, b, acc[j], 0, 0, 0);
        }
        __syncthreads();
    }
    bf16* C = sc + (size_t)h * T_SEQ * T_SEQ;
    const bool diag = (s0 == t0);
    const int tbase = t0 + w * 16 + qd * 4;
    #pragma unroll
    for (int j = 0; j < 4; j++) {
        int s = s0 + j * 16 + lc;
        #pragma unroll
        for (int r = 0; r < 4; r++) {
            int t = tbase + r;
            C[(size_t)t * T_SEQ + s] =
                __float2bfloat16((!diag || s < t) ? acc[j][r] : 0.f);
        }
    }
}

// ---------------------------------------------------------------------------
// dgemm128: 128x128 tile, 4 waves x (64x64), K=192, double-buffered LDS +
// 2-DEEP register prefetch (deposit waits on loads issued a full iteration
// earlier). LDS-staged coalesced epilogue (relu / rope / gate).
// ---------------------------------------------------------------------------
template <int EPI, bool WQR>
__launch_bounds__(256)
__global__ void dgemm128(const float* __restrict__ A, const bf16* __restrict__ Bt,
                         bf16* __restrict__ xs, bf16* __restrict__ qr,
                         const ushort2* __restrict__ csT) {
    __shared__ __align__(16) short pool[2 * 2 * 128 * 40];   // 40 KB
    short (*As)[128][40] = (short(*)[128][40])pool;
    short (*Bs)[128][40] = (short(*)[128][40])(pool + 2 * 128 * 40);

    const int tid = threadIdx.x;
    const int lane = tid & 63, w = tid >> 6, qd = lane >> 4, lc = lane & 15;
    const int wtm = (w >> 1) * 64, wtn = (w & 1) * 64;
    const int n0 = blockIdx.x * 128, m0 = blockIdx.y * 128;
    if constexpr (EPI == 2) A += (size_t)(n0 / N_DIM) * T_SEQ * D_DIM;

    const int r0 = tid >> 2, r1 = r0 + 64;
    const int kq = (tid & 3) * 8;

    const float* gA = A  + kq;
    const bf16*  gB = Bt + kq;

    // two register sets for 2-deep prefetch
    float4 fa00, fa01, fa02, fa03, fa10, fa11, fa12, fa13;
    u16x8 pb00, pb01, pb10, pb11;
    auto load0 = [&](int k0) {
        const float* a0 = gA + (size_t)(m0 + r0) * D_DIM + k0;
        const float* a1 = gA + (size_t)(m0 + r1) * D_DIM + k0;
        fa00 = *(const float4*)a0; fa01 = *(const float4*)(a0 + 4);
        fa02 = *(const float4*)a1; fa03 = *(const float4*)(a1 + 4);
        pb00 = *(const u16x8*)(gB + (size_t)(n0 + r0) * D_DIM + k0);
        pb01 = *(const u16x8*)(gB + (size_t)(n0 + r1) * D_DIM + k0);
    };
    auto load1 = [&](int k0) {
        const float* a0 = gA + (size_t)(m0 + r0) * D_DIM + k0;
        const float* a1 = gA + (size_t)(m0 + r1) * D_DIM + k0;
        fa10 = *(const float4*)a0; fa11 = *(const float4*)(a0 + 4);
        fa12 = *(const float4*)a1; fa13 = *(const float4*)(a1 + 4);
        pb10 = *(const u16x8*)(gB + (size_t)(n0 + r0) * D_DIM + k0);
        pb11 = *(const u16x8*)(gB + (size_t)(n0 + r1) * D_DIM + k0);
    };
    auto dep0 = [&](int buf) {
        u16x8 o0, o1;
        o0[0] = f2us(fa00.x); o0[1] = f2us(fa00.y); o0[2] = f2us(fa00.z); o0[3] = f2us(fa00.w);
        o0[4] = f2us(fa01.x); o0[5] = f2us(fa01.y); o0[6] = f2us(fa01.z); o0[7] = f2us(fa01.w);
        o1[0] = f2us(fa02.x); o1[1] = f2us(fa02.y); o1[2] = f2us(fa02.z); o1[3] = f2us(fa02.w);
        o1[4] = f2us(fa03.x); o1[5] = f2us(fa03.y); o1[6] = f2us(fa03.z); o1[7] = f2us(fa03.w);
        *(u16x8*)&As[buf][r0][kq] = o0;
        *(u16x8*)&As[buf][r1][kq] = o1;
        *(u16x8*)&Bs[buf][r0][kq] = pb00;
        *(u16x8*)&Bs[buf][r1][kq] = pb01;
    };
    auto dep1 = [&](int buf) {
        u16x8 o0, o1;
        o0[0] = f2us(fa10.x); o0[1] = f2us(fa10.y); o0[2] = f2us(fa10.z); o0[3] = f2us(fa10.w);
        o0[4] = f2us(fa11.x); o0[5] = f2us(fa11.y); o0[6] = f2us(fa11.z); o0[7] = f2us(fa11.w);
        o1[0] = f2us(fa12.x); o1[1] = f2us(fa12.y); o1[2] = f2us(fa12.z); o1[3] = f2us(fa12.w);
        o1[4] = f2us(fa13.x); o1[5] = f2us(fa13.y); o1[6] = f2us(fa13.z); o1[7] = f2us(fa13.w);
        *(u16x8*)&As[buf][r0][kq] = o0;
        *(u16x8*)&As[buf][r1][kq] = o1;
        *(u16x8*)&Bs[buf][r0][kq] = pb10;
        *(u16x8*)&Bs[buf][r1][kq] = pb11;
    };

    f32x4 acc[4][4] = {};
    auto mfma_step = [&](int buf) {
        s16x8 a[4], b[4];
        #pragma unroll
        for (int m = 0; m < 4; m++) a[m] = *(const s16x8*)&As[buf][wtm + m * 16 + lc][qd * 8];
        #pragma unroll
        for (int n = 0; n < 4; n++) b[n] = *(const s16x8*)&Bs[buf][wtn + n * 16 + lc][qd * 8];
        #pragma unroll
        for (int m = 0; m < 4; m++)
            #pragma unroll
            for (int n = 0; n < 4; n++)
                acc[m][n] = __builtin_amdgcn_mfma_f32_16x16x32_bf16(a[m], b[n], acc[m][n], 0, 0, 0);
    };

    const int NIT = D_DIM / 32;   // 6 (even)
    load0(0);
    load1(32);
    dep0(0);
    __syncthreads();
    for (int k = 0; k < NIT; k += 2) {
        if (k + 2 < NIT) load0((k + 2) * 32);
        mfma_step(0);
        if (k + 1 < NIT) dep1(1);
        __syncthreads();
        if (k + 1 < NIT) {
            if (k + 3 < NIT) load1((k + 3) * 32);
            mfma_step(1);
            if (k + 2 < NIT) dep0(0);
            __syncthreads();
        }
    }

    // -------- LDS-staged epilogue --------
    short (*S)[136] = (short(*)[136])pool; // 128 x 136 shorts = 34.8 KB <= 40 KB
    #pragma unroll
    for (int m = 0; m < 4; m++) {
        #pragma unroll
        for (int r = 0; r < 4; r++) {
            int tl = wtm + m * 16 + qd * 4 + r;
            #pragma unroll
            for (int n = 0; n < 4; n++) {
                int cl = wtn + n * 16 + lc;
                S[tl][cl] = (short)f2us(fmaxf(acc[m][n][r], 0.f));
            }
        }
    }
    __syncthreads();
    #pragma unroll
    for (int e = 0; e < 8; e++) {
        int idxe = tid + e * 256;
        int row = idxe >> 4, cg = idxe & 15;
        u16x8 v = *(const u16x8*)&S[row][cg * 8];
        int t = m0 + row, ngg = n0 + cg * 8;
        size_t ci = (size_t)t * HN + ngg;
        if constexpr (EPI == 1) {
            *(u16x8*)(xs + ci) = v;
            if constexpr (WQR) {
                int p0 = (ngg % N_DIM) >> 1;
                u16x8 cs8 = *(const u16x8*)&csT[(size_t)t * NP2 + p0];
                u16x8 o;
                #pragma unroll
                for (int q = 0; q < 4; q++) {
                    float ev = us2f(v[2 * q]), ov = us2f(v[2 * q + 1]);
                    float c = us2f(cs8[2 * q]), s = us2f(cs8[2 * q + 1]);
                    o[2 * q]     = f2us(ev * c - ov * s);
                    o[2 * q + 1] = f2us(ov * c + ev * s);
                }
                *(u16x8*)(qr + ci) = o;
            }
        } else {
            u16x8 g = *(const u16x8*)(xs + ci);
            u16x8 o;
            #pragma unroll
            for (int q = 0; q < 8; q++) o[q] = f2us(us2f(g[q]) * us2f(v[q]));
            *(u16x8*)(xs + ci) = o;
        }
    }
}

// ---------------------------------------------------------------------------
// mfma_gemm (64x64): MODE 0 = plain, 1 = causal split-K=2 (z = head*2+seg,
// slab1 at C + bZ), 2 = split-K slabs over z, 3 = causal full (fallback).
// Double-buffered LDS + 2-deep register prefetch (scores64 recipe).
// ---------------------------------------------------------------------------
template <typename TA, int MODE>
__launch_bounds__(256)
__global__ void mfma_gemm(const TA* __restrict__ A, const bf16* __restrict__ Bt,
                          float* __restrict__ C,
                          int K, int kSeg, int lda, int ldb, int ldc,
                          long aZ, long bZ, long cZ) {
    __shared__ short As[2][64][40];
    __shared__ short Bs[2][64][40];

    const int z = blockIdx.z;
    const int tid = threadIdx.x;
    const int n0 = blockIdx.x * 64, m0 = blockIdx.y * 64;
    const int srow = tid >> 2, sk = (tid & 3) * 8;
    const int lane = tid & 63, w = tid >> 6, qd = lane >> 4, lc = lane & 15;

    int kBeg, kEnd;
    if constexpr (MODE == 1) {
        const int h = z >> 1, seg = z & 1;
        A += aZ * h;
        C += cZ * h + bZ * seg;
        const int kc = (m0 + 64 < K) ? m0 + 64 : K;
        const int half = kc >> 1;            // multiple of 32
        kBeg = seg * half; kEnd = kBeg + half;
    } else if constexpr (MODE == 2) {
        A += aZ * z; Bt += bZ * z; C += cZ * z;
        kBeg = z * kSeg; kEnd = kBeg + kSeg;
    } else if constexpr (MODE == 3) {
        A += aZ * z; Bt += bZ * z; C += cZ * z;
        kBeg = 0; kEnd = (m0 + 64 < K) ? m0 + 64 : K;
    } else {
        A += aZ * z; Bt += bZ * z; C += cZ * z;
        kBeg = 0; kEnd = K;
    }

    const TA*   ga = A  + (size_t)(m0 + srow) * lda + sk;
    const bf16* gb = Bt + (size_t)(n0 + srow) * ldb + sk;

    // two register sets for 2-deep prefetch
    float4 f00, f01, f10, f11;
    u16x8 pa0, pa1, pb0, pb1;
    auto load0 = [&](int k0) {
        if constexpr (__is_same(TA, float)) {
            f00 = *(const float4*)(ga + k0);
            f01 = *(const float4*)(ga + k0 + 4);
        } else {
            pa0 = *(const u16x8*)(ga + k0);
        }
        pb0 = *(const u16x8*)(gb + k0);
    };
    auto load1 = [&](int k0) {
        if constexpr (__is_same(TA, float)) {
            f10 = *(const float4*)(ga + k0);
            f11 = *(const float4*)(ga + k0 + 4);
        } else {
            pa1 = *(const u16x8*)(ga + k0);
        }
        pb1 = *(const u16x8*)(gb + k0);
    };
    auto dep0 = [&](int buf) {
        if constexpr (__is_same(TA, float)) {
            u16x8 o;
            o[0] = f2us(f00.x); o[1] = f2us(f00.y); o[2] = f2us(f00.z); o[3] = f2us(f00.w);
            o[4] = f2us(f01.x); o[5] = f2us(f01.y); o[6] = f2us(f01.z); o[7] = f2us(f01.w);
            *(u16x8*)&As[buf][srow][sk] = o;
        } else {
            *(u16x8*)&As[buf][srow][sk] = pa0;
        }
        *(u16x8*)&Bs[buf][srow][sk] = pb0;
    };
    auto dep1 = [&](int buf) {
        if constexpr (__is_same(TA, float)) {
            u16x8 o;
            o[0] = f2us(f10.x); o[1] = f2us(f10.y); o[2] = f2us(f10.z); o[3] = f2us(f10.w);
            o[4] = f2us(f11.x); o[5] = f2us(f11.y); o[6] = f2us(f11.z); o[7] = f2us(f11.w);
            *(u16x8*)&As[buf][srow][sk] = o;
        } else {
            *(u16x8*)&As[buf][srow][sk] = pa1;
        }
        *(u16x8*)&Bs[buf][srow][sk] = pb1;
    };

    f32x4 acc[4] = {{0.f,0.f,0.f,0.f},{0.f,0.f,0.f,0.f},
                    {0.f,0.f,0.f,0.f},{0.f,0.f,0.f,0.f}};
    auto mfma_step = [&](int buf) {
        s16x8 a = *(const s16x8*)&As[buf][w * 16 + lc][qd * 8];
        s16x8 b[4];
        #pragma unroll
        for (int j = 0; j < 4; j++) b[j] = *(const s16x8*)&Bs[buf][j * 16 + lc][qd * 8];
        #pragma unroll
        for (int j = 0; j < 4; j++)
            acc[j] = __builtin_amdgcn_mfma_f32_16x16x32_bf16(a, b[j], acc[j], 0, 0, 0);
    };

    const int NIT = (kEnd - kBeg) / 32;
    // prologue over-read at kBeg+32 is in-bounds for all call sites (rows are
    // >= kBeg+64 elements long in every instantiation).
    load0(kBeg);
    load1(kBeg + 32);
    dep0(0);
    __syncthreads();

    for (int k = 0; k < NIT; k += 2) {
        if (k + 2 < NIT) load0(kBeg + (k + 2) * 32);
        mfma_step(0);
        if (k + 1 < NIT) dep1(1);
        __syncthreads();
        if (k + 1 < NIT) {
            if (k + 3 < NIT) load1(kBeg + (k + 3) * 32);
            mfma_step(1);
            if (k + 2 < NIT) dep0(0);
            __syncthreads();
        }
    }

    #pragma unroll
    for (int j = 0; j < 4; j++) {
        int n = n0 + j * 16 + lc;
        #pragma unroll
        for (int r = 0; r < 4; r++) {
            int m = m0 + w * 16 + qd * 4 + r;
            C[(size_t)m * ldc + n] = acc[j][r];
        }
    }
}

extern "C" void kernel_launch(void* const* d_in, const int* in_sizes, int n_in,
                              void* d_out, int out_size, void* d_ws, size_t ws_size,
                              hipStream_t stream) {
    const int*   idx   = (const int*)  d_in[0];
    const float* dec_x = (const float*)d_in[1];   // (NH, D, N)
    const float* dec_y = (const float*)d_in[2];   // (NH, D, N)
    const float* enc   = (const float*)d_in[3];   // (NH*N, D)
    const float* emb   = (const float*)d_in[4];   // (VOCAB, D)
    const float* pose  = (const float*)d_in[5];   // (BLOCK, D)
    const float* lmh   = (const float*)d_in[6];   // (D, VOCAB)
    float* out = (float*)d_out;                   // (T, VOCAB) fp32

    // workspace layout — identical to passing r11 (ws >= 84,377,600 proven)
    char* wp = (char*)d_ws;
    float*   x    = (float*)wp;              wp += (size_t)T_SEQ * D_DIM * 4;
    bf16*    xs   = (bf16*)wp;               wp += (size_t)T_SEQ * HN * 2;
    ushort2* csT  = (ushort2*)wp;            wp += (size_t)T_SEQ * NP2 * 4;
    bf16*    sc   = (bf16*)wp;               wp += (size_t)NHEAD * T_SEQ * T_SEQ * 2;
    float*   ykv  = (float*)wp;              wp += (size_t)NHEAD * T_SEQ * D_DIM * 4;
    float*   ymlp = (float*)wp;              wp += (size_t)T_SEQ * D_DIM * 4;   // layout keeper
    bf16*    xT   = (bf16*)wp;               wp += (size_t)D_DIM * T_SEQ * 2;
    bf16*    wX   = (bf16*)wp;               wp += (size_t)NHEAD * N_DIM * D_DIM * 2;
    bf16*    wY   = (bf16*)wp;               wp += (size_t)NHEAD * N_DIM * D_DIM * 2;
    bf16*    wE   = (bf16*)wp;               wp += (size_t)D_DIM * HN * 2;
    bf16*    wL   = (bf16*)wp;               wp += (size_t)VOCABSZ * D_DIM * 2;
    const size_t BASE_NEED = (size_t)(wp - (char*)d_ws);
    bf16*    qr   = (bf16*)wp;
    const size_t FULL_NEED = BASE_NEED + (size_t)T_SEQ * HN * 2;
    float* ymlpP = (float*)sc;     // 8 slabs x T*D x 4B overlay on dead sc region
    bf16*  dbuf  = (bf16*)ykv;     // 512 KB diag partials overlay on idle ykv region

    if (ws_size < BASE_NEED) {
        fill_out<<<(out_size + 255) / 256, 256, 0, stream>>>(out, (float)ws_size, out_size);
        return;
    }
    const bool USE_QR = (ws_size >= FULL_NEED);

    // weight mirrors (bf16, [n][k])
    t_cvt<<<dim3(48, 3, 4), 256, 0, stream>>>(dec_x, wX, D_DIM, N_DIM,
                                              (long)D_DIM * N_DIM, (long)N_DIM * D_DIM);
    t_cvt<<<dim3(48, 3, 4), 256, 0, stream>>>(dec_y, wY, D_DIM, N_DIM,
                                              (long)D_DIM * N_DIM, (long)N_DIM * D_DIM);
    t_cvt<<<dim3(3, 192, 1), 256, 0, stream>>>(enc, wE, HN, D_DIM, 0L, 0L);
    t_cvt<<<dim3(4, 3, 1), 256, 0, stream>>>(lmh, wL, D_DIM, VOCABSZ, 0L, 0L);

    k_tables<<<(T_SEQ * NP2) / 256, 256, 0, stream>>>(csT);
    k_embed<<<T_SEQ, 64, 0, stream>>>(idx, emb, pose, x);

    for (int l = 0; l < NLAYER; ++l) {
        // xT = x^T (bf16) for ykv's B operand
        t_cvt<<<dim3(3, 16, 1), 256, 0, stream>>>(x, xT, T_SEQ, D_DIM, 0L, 0L);
        // xs = relu(x @ dec_x)  (+ fused qr when available)
        if (USE_QR) {
            dgemm128<1, true><<<dim3(96, 8), 256, 0, stream>>>(x, wX, xs, qr, csT);
            scores64<<<dim3(136, 2, NHEAD), 256, 0, stream>>>(qr, sc, dbuf);
            k_comb<<<dim3(136, 1, NHEAD), 256, 0, stream>>>(sc, dbuf);
            // ykv = sc @ x  (causal, split-K=2; slab1 on dead qr region)
            long segZ = (long)((float*)qr - ykv);
            mfma_gemm<bf16, 1><<<dim3(3, 16, NHEAD * 2), 256, 0, stream>>>(
                sc, xT, ykv, T_SEQ, 0, T_SEQ, T_SEQ, D_DIM,
                (long)T_SEQ * T_SEQ, segZ, (long)T_SEQ * D_DIM);
            // ykv = LN(slab0 + slab1)
            k_ln2<<<NHEAD * T_SEQ, 64, 0, stream>>>(ykv, (const float*)qr);
        } else {
            dgemm128<1, false><<<dim3(96, 8), 256, 0, stream>>>(x, wX, xs, qr, csT);
            scores_fused<<<dim3(16, 16, NHEAD), 256, 0, stream>>>(xs, csT, sc);
            mfma_gemm<bf16, 3><<<dim3(3, 16, NHEAD), 256, 0, stream>>>(
                sc, xT, ykv, T_SEQ, 0, T_SEQ, T_SEQ, D_DIM,
                (long)T_SEQ * T_SEQ, 0L, (long)T_SEQ * D_DIM);
            k_ln<<<NHEAD * T_SEQ, 64, 0, stream>>>(ykv);
        }
        // xs *= relu(ykv @ dec_y)   (gate; head slab picked inside kernel)
        dgemm128<2, false><<<dim3(96, 8), 256, 0, stream>>>(
            (const float*)ykv, wY, xs, nullptr, nullptr);
        // ymlp partials = xy @ enc   (split-K=8 -> slabs in sc region)
        mfma_gemm<bf16, 2><<<dim3(3, 16, 8), 256, 0, stream>>>(
            xs, wE, ymlpP, HN, HN / 8, HN, HN, D_DIM,
            0L, 0L, (long)T_SEQ * D_DIM);
        // x = LN(x + LN(sum partials))
        k_resid8<<<T_SEQ, 64, 0, stream>>>(x, ymlpP);
        (void)ymlp;
    }

    // logits = x @ lm_head
    mfma_gemm<float, 0><<<dim3(4, 16, 1), 256, 0, stream>>>(
        x, wL, out, D_DIM, 0, D_DIM, D_DIM, VOCABSZ, 0L, 0L, 0L);
}

// Round 6
// 522.651 us; speedup vs baseline: 1.2806x; 1.0762x over previous
//
#include <hip/hip_runtime.h>
#include <hip/hip_bf16.h>

using bf16 = __hip_bfloat16;

#define D_DIM   192
#define N_DIM   3072
#define NHEAD   4
#define T_SEQ   1024
#define HN      12288      // NHEAD * N_DIM
#define NP2     1536       // N_DIM/2
#define VOCABSZ 256
#define NLAYER  4
#define LN_EPS  1e-5f
#define TWO_PI  6.2831853071795864f

typedef __attribute__((ext_vector_type(8)))  short          s16x8;
typedef __attribute__((ext_vector_type(8)))  unsigned short u16x8;
typedef __attribute__((ext_vector_type(4)))  float          f32x4;
typedef __attribute__((ext_vector_type(16))) float          f32x16;

__device__ __forceinline__ float b2f(bf16 v) { return __bfloat162float(v); }
__device__ __forceinline__ float us2f(unsigned short u) {
    unsigned int x = ((unsigned int)u) << 16;
    return __builtin_bit_cast(float, x);
}
__device__ __forceinline__ unsigned short f2us(float f) {
    bf16 b = __float2bfloat16(f);
    return __builtin_bit_cast(unsigned short, b);
}

// sentinel: encode ws_size into output (fires only if ws too small)
__global__ void fill_out(float* __restrict__ out, float val, int nelem) {
    int i = blockIdx.x * 256 + threadIdx.x;
    if (i < nelem) out[i] = val;
}

// ---------------------------------------------------------------------------
// Tiled transpose + fp32->bf16: in fp32 [R][C] -> out bf16 [C][R].
// ---------------------------------------------------------------------------
__global__ void t_cvt(const float* __restrict__ in, bf16* __restrict__ out,
                      int R, int C, long inZ, long outZ) {
    __shared__ float tile[64][65];
    in  += inZ  * blockIdx.z;
    out += outZ * blockIdx.z;
    const int tx = threadIdx.x & 63, ty = threadIdx.x >> 6;
    const int r0 = blockIdx.y * 64, c0 = blockIdx.x * 64;
    #pragma unroll
    for (int rr = 0; rr < 16; rr++) {
        int row = ty * 16 + rr;
        tile[row][tx] = in[(size_t)(r0 + row) * C + c0 + tx];
    }
    __syncthreads();
    #pragma unroll
    for (int rr = 0; rr < 16; rr++) {
        int row = ty * 16 + rr;
        out[(size_t)(c0 + row) * R + r0 + tx] = __float2bfloat16(tile[tx][row]);
    }
}

// ---------------------------------------------------------------------------
// Wave-per-row LN family (64 threads/block, 3 elems/lane, butterfly reduce)
// ---------------------------------------------------------------------------
__device__ __forceinline__ void wave_sum2(float& s, float& ss) {
    #pragma unroll
    for (int off = 1; off < 64; off <<= 1) {
        s  += __shfl_xor(s,  off, 64);
        ss += __shfl_xor(ss, off, 64);
    }
}

__global__ void k_embed(const int* __restrict__ idx, const float* __restrict__ emb,
                        const float* __restrict__ pos, float* __restrict__ x) {
    int t = blockIdx.x, l = threadIdx.x;
    int tok = idx[t];
    const float* e = emb + tok * D_DIM;
    const float* p = pos + t * D_DIM;
    float v0 = e[l] + p[l], v1 = e[l + 64] + p[l + 64], v2 = e[l + 128] + p[l + 128];
    float s = v0 + v1 + v2, ss = v0 * v0 + v1 * v1 + v2 * v2;
    wave_sum2(s, ss);
    float m = s / D_DIM, r = rsqrtf(ss / D_DIM - m * m + LN_EPS);
    float* xr = x + t * D_DIM;
    xr[l] = (v0 - m) * r; xr[l + 64] = (v1 - m) * r; xr[l + 128] = (v2 - m) * r;
}

__global__ void k_ln(float* __restrict__ buf) {
    int l = threadIdx.x;
    float* row = buf + (size_t)blockIdx.x * D_DIM;
    float v0 = row[l], v1 = row[l + 64], v2 = row[l + 128];
    float s = v0 + v1 + v2, ss = v0 * v0 + v1 * v1 + v2 * v2;
    wave_sum2(s, ss);
    float m = s / D_DIM, r = rsqrtf(ss / D_DIM - m * m + LN_EPS);
    row[l] = (v0 - m) * r; row[l + 64] = (v1 - m) * r; row[l + 128] = (v2 - m) * r;
}

// row = LN(row + P1row)  — fuses ykv split-K=2 slab sum into the LN pass
__global__ void k_ln2(float* __restrict__ buf, const float* __restrict__ P1) {
    int l = threadIdx.x;
    size_t off = (size_t)blockIdx.x * D_DIM;
    float* row = buf + off;
    const float* r1 = P1 + off;
    float v0 = row[l] + r1[l];
    float v1 = row[l + 64] + r1[l + 64];
    float v2 = row[l + 128] + r1[l + 128];
    float s = v0 + v1 + v2, ss = v0 * v0 + v1 * v1 + v2 * v2;
    wave_sum2(s, ss);
    float m = s / D_DIM, r = rsqrtf(ss / D_DIM - m * m + LN_EPS);
    row[l] = (v0 - m) * r; row[l + 64] = (v1 - m) * r; row[l + 128] = (v2 - m) * r;
}

// x = LN(x + LN(sum of 8 split-K partial slabs))
__global__ void k_resid8(float* __restrict__ x, const float* __restrict__ P) {
    int l = threadIdx.x, t = blockIdx.x;
    float y0 = 0.f, y1 = 0.f, y2 = 0.f;
    #pragma unroll
    for (int p = 0; p < 8; p++) {
        const float* r = P + (size_t)p * T_SEQ * D_DIM + (size_t)t * D_DIM;
        y0 += r[l]; y1 += r[l + 64]; y2 += r[l + 128];
    }
    float* xr = x + (size_t)t * D_DIM;
    float s = y0 + y1 + y2, ss = y0 * y0 + y1 * y1 + y2 * y2;
    wave_sum2(s, ss);
    float m1 = s / D_DIM, r1 = rsqrtf(ss / D_DIM - m1 * m1 + LN_EPS);
    float v0 = xr[l] + (y0 - m1) * r1;
    float v1 = xr[l + 64] + (y1 - m1) * r1;
    float v2 = xr[l + 128] + (y2 - m1) * r1;
    s = v0 + v1 + v2; ss = v0 * v0 + v1 * v1 + v2 * v2;
    wave_sum2(s, ss);
    float m2 = s / D_DIM, r2 = rsqrtf(ss / D_DIM - m2 * m2 + LN_EPS);
    xr[l] = (v0 - m2) * r2; xr[l + 64] = (v1 - m2) * r2; xr[l + 128] = (v2 - m2) * r2;
}

// RoPE cos/sin tables, interleaved bf16 pairs csT[t][p] = (cos, sin)
// powf(65536,x) replaced with exp2f(16x): 1.5M threads of setup VALU.
__global__ void k_tables(ushort2* __restrict__ csT) {
    int gid = blockIdx.x * 256 + threadIdx.x;
    int t = gid / NP2, p = gid % NP2;
    float qf = (float)(2 * p);
    float f = exp2f(qf * (-16.0f / 3072.0f)) * (1.0f / (float)TWO_PI);
    float ph = fmodf((float)t * f, 1.0f) * (float)TWO_PI;
    ushort2 cs;
    cs.x = f2us(cosf(ph));
    cs.y = f2us(sinf(ph));
    csT[gid] = cs;
}

// ---------------------------------------------------------------------------
// scores64: sc[h,t,s] = dot(qr[t,h], qr[s,h]) for s<t, else 0.
// Split-K=2 over grid.y (1088 blocks): kh=0 -> lower tile (i,j); kh=1 with
// swapped operands -> mirror tile (j,i) (or dbuf slab for diagonal).
// 64x64 tile, 4 waves x one 32x32x16 MFMA acc each (halves MFMA instr count
// vs 2x2 16x16 frags at equal FLOP), BK=64, double-buffered LDS + 2-deep
// register prefetch. LDS-staged coalesced epilogue. Rows padded to 72 shorts
// (stride 144 B, 144/16 odd -> conflict-free b128 for 32-lane row groups).
// XCD-chunked L remap (136 = 8*17).
// ---------------------------------------------------------------------------
__launch_bounds__(256, 4)
__global__ void scores64(const bf16* __restrict__ qr, bf16* __restrict__ sc,
                         bf16* __restrict__ dbuf) {
    const int h  = blockIdx.z;
    const int kh = blockIdx.y;                     // K-half
    const int orig = blockIdx.x;
    const int L = (orig & 7) * 17 + (orig >> 3);   // bijective: 136 = 8*17
    int i = 0;
    while (((i + 1) * (i + 2)) >> 1 <= L) ++i;
    int j = L - ((i * (i + 1)) >> 1);
    const int t0 = i * 64, s0 = j * 64;
    const bool diag = (i == j);

    // operand roles: kh=1 off-diag computes the transposed tile directly
    int arow = t0, brow = s0;
    if (kh == 1 && !diag) { arow = s0; brow = t0; }

    __shared__ short As[2][64][72];
    __shared__ short Bs[2][64][72];

    const int tid = threadIdx.x;
    const int lane = tid & 63, w = tid >> 6;
    const int wtm = (w >> 1) * 32, wtn = (w & 1) * 32;
    const int l31 = lane & 31, lhi = lane >> 5;    // 32x32 frag addressing
    const int r0 = tid >> 2;                       // staging row 0..63
    const int kq = (tid & 3) * 16;                 // staging k-offset

    const int kBeg = kh * (N_DIM / 2);
    const bf16* gA = qr + (size_t)(arow + r0) * HN + h * N_DIM + kBeg + kq;
    const bf16* gB = qr + (size_t)(brow + r0) * HN + h * N_DIM + kBeg + kq;

    // two named register sets (static indexing only — no scratch)
    u16x8 pa0, pa1, pb0, pb1;   // set 0: even iters
    u16x8 qa0, qa1, qb0, qb1;   // set 1: odd iters
    auto load0 = [&](int k0) {
        pa0 = *(const u16x8*)(gA + k0);
        pa1 = *(const u16x8*)(gA + k0 + 8);
        pb0 = *(const u16x8*)(gB + k0);
        pb1 = *(const u16x8*)(gB + k0 + 8);
    };
    auto load1 = [&](int k0) {
        qa0 = *(const u16x8*)(gA + k0);
        qa1 = *(const u16x8*)(gA + k0 + 8);
        qb0 = *(const u16x8*)(gB + k0);
        qb1 = *(const u16x8*)(gB + k0 + 8);
    };
    auto dep0 = [&](int buf) {
        *(u16x8*)&As[buf][r0][kq]     = pa0;
        *(u16x8*)&As[buf][r0][kq + 8] = pa1;
        *(u16x8*)&Bs[buf][r0][kq]     = pb0;
        *(u16x8*)&Bs[buf][r0][kq + 8] = pb1;
    };
    auto dep1 = [&](int buf) {
        *(u16x8*)&As[buf][r0][kq]     = qa0;
        *(u16x8*)&As[buf][r0][kq + 8] = qa1;
        *(u16x8*)&Bs[buf][r0][kq]     = qb0;
        *(u16x8*)&Bs[buf][r0][kq + 8] = qb1;
    };

    f32x16 acc;
    #pragma unroll
    for (int r = 0; r < 16; r++) acc[r] = 0.f;

    auto mfma_step = [&](int buf) {
        #pragma unroll
        for (int ks = 0; ks < 4; ks++) {
            s16x8 a = *(const s16x8*)&As[buf][wtm + l31][ks * 16 + lhi * 8];
            s16x8 b = *(const s16x8*)&Bs[buf][wtn + l31][ks * 16 + lhi * 8];
            acc = __builtin_amdgcn_mfma_f32_32x32x16_bf16(a, b, acc, 0, 0, 0);
        }
    };

    const int NIT = (N_DIM / 2) / 64;   // 24 (even)
    load0(0);
    load1(64);
    dep0(0);
    __syncthreads();

    for (int k = 0; k < NIT; k += 2) {
        if (k + 2 < NIT) load0((k + 2) * 64);
        mfma_step(0);
        if (k + 1 < NIT) dep1(1);
        __syncthreads();
        if (k + 1 < NIT) {
            if (k + 3 < NIT) load1((k + 3) * 64);
            mfma_step(1);
            if (k + 2 < NIT) dep0(0);
            __syncthreads();
        }
    }

    // -------- LDS-staged coalesced epilogue --------
    __syncthreads();                               // all waves done with As
    short (*S)[72] = (short(*)[72])&As[0][0][0];   // 64x72 tile reuse
    #pragma unroll
    for (int r = 0; r < 16; r++) {
        // 32x32x16 C/D layout: col = lane&31, row = (r&3)+8*(r>>2)+4*(lane>>5)
        int row = wtm + (r & 3) + 8 * (r >> 2) + 4 * lhi;
        int col = wtn + l31;
        float v = acc[r];
        if (diag && col >= row) v = 0.f;           // same local mask both kh
        S[row][col] = (short)f2us(v);
    }
    __syncthreads();
    if (kh == 1 && diag) {
        bf16* P = dbuf + (size_t)(h * 16 + i) * 4096;
        #pragma unroll
        for (int e = 0; e < 2; e++) {
            int idxe = tid + e * 256;
            int row = idxe >> 3, cg = (idxe & 7) * 8;
            u16x8 v = *(const u16x8*)&S[row][cg];
            *(u16x8*)(P + row * 64 + cg) = v;
        }
    } else {
        bf16* C = sc + (size_t)h * T_SEQ * T_SEQ;
        #pragma unroll
        for (int e = 0; e < 2; e++) {
            int idxe = tid + e * 256;
            int row = idxe >> 3, cg = (idxe & 7) * 8;
            u16x8 v = *(const u16x8*)&S[row][cg];
            *(u16x8*)(C + (size_t)(arow + row) * T_SEQ + brow + cg) = v;
        }
    }
}

// ---------------------------------------------------------------------------
// k_comb: sc lower tile (i,j) += second-half partial (mirror tile (j,i),
// transposed via LDS; or dbuf slab for diagonal tiles).
// ---------------------------------------------------------------------------
__global__ void k_comb(bf16* __restrict__ sc, const bf16* __restrict__ dbuf) {
    __shared__ short tile[64][72];
    const int h = blockIdx.z;
    int L = blockIdx.x;
    int i = 0;
    while (((i + 1) * (i + 2)) >> 1 <= L) ++i;
    int j = L - ((i * (i + 1)) >> 1);
    bf16* C = sc + (size_t)h * T_SEQ * T_SEQ;
    const int r  = threadIdx.x >> 3;          // 0..31
    const int c8 = (threadIdx.x & 7) * 8;     // 0,8,...,56
    if (i != j) {
        // mirror tile P[s_local][t_local] lives at rows j*64.., cols i*64..
        #pragma unroll
        for (int p = 0; p < 2; p++) {
            int row = r + p * 32;
            u16x8 v = *(const u16x8*)(C + (size_t)(j * 64 + row) * T_SEQ + i * 64 + c8);
            *(u16x8*)&tile[row][c8] = v;
        }
        __syncthreads();
        #pragma unroll
        for (int p = 0; p < 2; p++) {
            int row = r + p * 32;             // t_local
            size_t off = (size_t)(i * 64 + row) * T_SEQ + j * 64 + c8;
            u16x8 a = *(const u16x8*)(C + off);
            u16x8 o;
            #pragma unroll
            for (int e = 0; e < 8; e++)
                o[e] = f2us(us2f(a[e]) + us2f((unsigned short)tile[c8 + e][row]));
            *(u16x8*)(C + off) = o;
        }
    } else {
        const bf16* P = dbuf + (size_t)(h * 16 + i) * 4096;
        #pragma unroll
        for (int p = 0; p < 2; p++) {
            int row = r + p * 32;
            size_t off = (size_t)(i * 64 + row) * T_SEQ + i * 64 + c8;
            u16x8 a = *(const u16x8*)(C + off);
            u16x8 b = *(const u16x8*)((const unsigned short*)P + row * 64 + c8);
            u16x8 o;
            #pragma unroll
            for (int e = 0; e < 8; e++)
                o[e] = f2us(us2f(a[e]) + us2f(b[e]));
            *(u16x8*)(C + off) = o;
        }
    }
}

// ---------------------------------------------------------------------------
// scores fallback (no qr buffer): 64x64, rope fused into staging.
// ---------------------------------------------------------------------------
__device__ __forceinline__ void stage_rope8(short* dst, const bf16* src,
                                            const ushort2* csP) {
    u16x8 v  = *(const u16x8*)src;
    u16x8 cs = *(const u16x8*)csP;
    u16x8 o;
    #pragma unroll
    for (int i = 0; i < 4; i++) {
        float e  = us2f(v[2 * i]), od = us2f(v[2 * i + 1]);
        float c  = us2f(cs[2 * i]), s = us2f(cs[2 * i + 1]);
        o[2 * i]     = f2us(e * c - od * s);
        o[2 * i + 1] = f2us(od * c + e * s);
    }
    *(u16x8*)dst = o;
}

__launch_bounds__(256)
__global__ void scores_fused(const bf16* __restrict__ xs,
                             const ushort2* __restrict__ csT,
                             bf16* __restrict__ sc) {
    const int h  = blockIdx.z;
    const int s0 = blockIdx.x * 64, t0 = blockIdx.y * 64;
    if (s0 > t0) return;
    __shared__ short As[64][40];
    __shared__ short Bs[64][40];
    const int tid  = threadIdx.x;
    const int srow = tid >> 2, kq = (tid & 3) * 8;
    const int lane = tid & 63, w = tid >> 6, qd = lane >> 4, lc = lane & 15;
    const int tA = t0 + srow, tB = s0 + srow;
    const bf16* gA = xs + (size_t)tA * HN + h * N_DIM + kq;
    const bf16* gB = xs + (size_t)tB * HN + h * N_DIM + kq;
    const ushort2* cA = csT + (size_t)tA * NP2 + (kq >> 1);
    const ushort2* cB = csT + (size_t)tB * NP2 + (kq >> 1);
    f32x4 acc[4] = {{0.f,0.f,0.f,0.f},{0.f,0.f,0.f,0.f},
                    {0.f,0.f,0.f,0.f},{0.f,0.f,0.f,0.f}};
    for (int k0 = 0; k0 < N_DIM; k0 += 32) {
        stage_rope8(&As[srow][kq], gA + k0, cA + (k0 >> 1));
        stage_rope8(&Bs[srow][kq], gB + k0, cB + (k0 >> 1));
        __syncthreads();
        s16x8 a = *(const s16x8*)&As[w * 16 + lc][qd * 8];
        #pragma unroll
        for (int j = 0; j < 4; j++) {
            s16x8 b = *(const s16x8*)&Bs[j * 16 + lc][qd * 8];
            acc[j] = __builtin_amdgcn_mfma_f32_16x16x32_bf16(a, b, acc[j], 0, 0, 0);
        }
        __syncthreads();
    }
    bf16* C = sc + (size_t)h * T_SEQ * T_SEQ;
    const bool diag = (s0 == t0);
    const int tbase = t0 + w * 16 + qd * 4;
    #pragma unroll
    for (int j = 0; j < 4; j++) {
        int s = s0 + j * 16 + lc;
        #pragma unroll
        for (int r = 0; r < 4; r++) {
            int t = tbase + r;
            C[(size_t)t * T_SEQ + s] =
                __float2bfloat16((!diag || s < t) ? acc[j][r] : 0.f);
        }
    }
}

// ---------------------------------------------------------------------------
// dgemm128: 128x128 tile, 4 waves x (64x64), K=192, double-buffered LDS +
// 2-DEEP register prefetch. LDS-staged coalesced epilogue (relu/rope/gate).
// ---------------------------------------------------------------------------
template <int EPI, bool WQR>
__launch_bounds__(256)
__global__ void dgemm128(const float* __restrict__ A, const bf16* __restrict__ Bt,
                         bf16* __restrict__ xs, bf16* __restrict__ qr,
                         const ushort2* __restrict__ csT) {
    __shared__ __align__(16) short pool[2 * 2 * 128 * 40];   // 40 KB
    short (*As)[128][40] = (short(*)[128][40])pool;
    short (*Bs)[128][40] = (short(*)[128][40])(pool + 2 * 128 * 40);

    const int tid = threadIdx.x;
    const int lane = tid & 63, w = tid >> 6, qd = lane >> 4, lc = lane & 15;
    const int wtm = (w >> 1) * 64, wtn = (w & 1) * 64;
    const int n0 = blockIdx.x * 128, m0 = blockIdx.y * 128;
    if constexpr (EPI == 2) A += (size_t)(n0 / N_DIM) * T_SEQ * D_DIM;

    const int r0 = tid >> 2, r1 = r0 + 64;
    const int kq = (tid & 3) * 8;

    const float* gA = A  + kq;
    const bf16*  gB = Bt + kq;

    // two register sets for 2-deep prefetch
    float4 fa00, fa01, fa02, fa03, fa10, fa11, fa12, fa13;
    u16x8 pb00, pb01, pb10, pb11;
    auto load0 = [&](int k0) {
        const float* a0 = gA + (size_t)(m0 + r0) * D_DIM + k0;
        const float* a1 = gA + (size_t)(m0 + r1) * D_DIM + k0;
        fa00 = *(const float4*)a0; fa01 = *(const float4*)(a0 + 4);
        fa02 = *(const float4*)a1; fa03 = *(const float4*)(a1 + 4);
        pb00 = *(const u16x8*)(gB + (size_t)(n0 + r0) * D_DIM + k0);
        pb01 = *(const u16x8*)(gB + (size_t)(n0 + r1) * D_DIM + k0);
    };
    auto load1 = [&](int k0) {
        const float* a0 = gA + (size_t)(m0 + r0) * D_DIM + k0;
        const float* a1 = gA + (size_t)(m0 + r1) * D_DIM + k0;
        fa10 = *(const float4*)a0; fa11 = *(const float4*)(a0 + 4);
        fa12 = *(const float4*)a1; fa13 = *(const float4*)(a1 + 4);
        pb10 = *(const u16x8*)(gB + (size_t)(n0 + r0) * D_DIM + k0);
        pb11 = *(const u16x8*)(gB + (size_t)(n0 + r1) * D_DIM + k0);
    };
    auto dep0 = [&](int buf) {
        u16x8 o0, o1;
        o0[0] = f2us(fa00.x); o0[1] = f2us(fa00.y); o0[2] = f2us(fa00.z); o0[3] = f2us(fa00.w);
        o0[4] = f2us(fa01.x); o0[5] = f2us(fa01.y); o0[6] = f2us(fa01.z); o0[7] = f2us(fa01.w);
        o1[0] = f2us(fa02.x); o1[1] = f2us(fa02.y); o1[2] = f2us(fa02.z); o1[3] = f2us(fa02.w);
        o1[4] = f2us(fa03.x); o1[5] = f2us(fa03.y); o1[6] = f2us(fa03.z); o1[7] = f2us(fa03.w);
        *(u16x8*)&As[buf][r0][kq] = o0;
        *(u16x8*)&As[buf][r1][kq] = o1;
        *(u16x8*)&Bs[buf][r0][kq] = pb00;
        *(u16x8*)&Bs[buf][r1][kq] = pb01;
    };
    auto dep1 = [&](int buf) {
        u16x8 o0, o1;
        o0[0] = f2us(fa10.x); o0[1] = f2us(fa10.y); o0[2] = f2us(fa10.z); o0[3] = f2us(fa10.w);
        o0[4] = f2us(fa11.x); o0[5] = f2us(fa11.y); o0[6] = f2us(fa11.z); o0[7] = f2us(fa11.w);
        o1[0] = f2us(fa12.x); o1[1] = f2us(fa12.y); o1[2] = f2us(fa12.z); o1[3] = f2us(fa12.w);
        o1[4] = f2us(fa13.x); o1[5] = f2us(fa13.y); o1[6] = f2us(fa13.z); o1[7] = f2us(fa13.w);
        *(u16x8*)&As[buf][r0][kq] = o0;
        *(u16x8*)&As[buf][r1][kq] = o1;
        *(u16x8*)&Bs[buf][r0][kq] = pb10;
        *(u16x8*)&Bs[buf][r1][kq] = pb11;
    };

    f32x4 acc[4][4] = {};
    auto mfma_step = [&](int buf) {
        s16x8 a[4], b[4];
        #pragma unroll
        for (int m = 0; m < 4; m++) a[m] = *(const s16x8*)&As[buf][wtm + m * 16 + lc][qd * 8];
        #pragma unroll
        for (int n = 0; n < 4; n++) b[n] = *(const s16x8*)&Bs[buf][wtn + n * 16 + lc][qd * 8];
        #pragma unroll
        for (int m = 0; m < 4; m++)
            #pragma unroll
            for (int n = 0; n < 4; n++)
                acc[m][n] = __builtin_amdgcn_mfma_f32_16x16x32_bf16(a[m], b[n], acc[m][n], 0, 0, 0);
    };

    const int NIT = D_DIM / 32;   // 6 (even)
    load0(0);
    load1(32);
    dep0(0);
    __syncthreads();
    for (int k = 0; k < NIT; k += 2) {
        if (k + 2 < NIT) load0((k + 2) * 32);
        mfma_step(0);
        if (k + 1 < NIT) dep1(1);
        __syncthreads();
        if (k + 1 < NIT) {
            if (k + 3 < NIT) load1((k + 3) * 32);
            mfma_step(1);
            if (k + 2 < NIT) dep0(0);
            __syncthreads();
        }
    }

    // -------- LDS-staged epilogue --------
    short (*S)[136] = (short(*)[136])pool; // 128 x 136 shorts = 34.8 KB <= 40 KB
    #pragma unroll
    for (int m = 0; m < 4; m++) {
        #pragma unroll
        for (int r = 0; r < 4; r++) {
            int tl = wtm + m * 16 + qd * 4 + r;
            #pragma unroll
            for (int n = 0; n < 4; n++) {
                int cl = wtn + n * 16 + lc;
                S[tl][cl] = (short)f2us(fmaxf(acc[m][n][r], 0.f));
            }
        }
    }
    __syncthreads();
    #pragma unroll
    for (int e = 0; e < 8; e++) {
        int idxe = tid + e * 256;
        int row = idxe >> 4, cg = idxe & 15;
        u16x8 v = *(const u16x8*)&S[row][cg * 8];
        int t = m0 + row, ngg = n0 + cg * 8;
        size_t ci = (size_t)t * HN + ngg;
        if constexpr (EPI == 1) {
            *(u16x8*)(xs + ci) = v;
            if constexpr (WQR) {
                int p0 = (ngg % N_DIM) >> 1;
                u16x8 cs8 = *(const u16x8*)&csT[(size_t)t * NP2 + p0];
                u16x8 o;
                #pragma unroll
                for (int q = 0; q < 4; q++) {
                    float ev = us2f(v[2 * q]), ov = us2f(v[2 * q + 1]);
                    float c = us2f(cs8[2 * q]), s = us2f(cs8[2 * q + 1]);
                    o[2 * q]     = f2us(ev * c - ov * s);
                    o[2 * q + 1] = f2us(ov * c + ev * s);
                }
                *(u16x8*)(qr + ci) = o;
            }
        } else {
            u16x8 g = *(const u16x8*)(xs + ci);
            u16x8 o;
            #pragma unroll
            for (int q = 0; q < 8; q++) o[q] = f2us(us2f(g[q]) * us2f(v[q]));
            *(u16x8*)(xs + ci) = o;
        }
    }
}

// ---------------------------------------------------------------------------
// mfma_gemm (64x64): MODE 0 = plain, 1 = causal split-K=2 (z = head*2+seg,
// slab1 at C + bZ; 64-granular split), 2 = split-K slabs over z, 3 = causal
// full (fallback). BK=64 (halved barriers), double-buffered LDS + 2-deep
// register prefetch. Rows padded to 72 shorts.
// ---------------------------------------------------------------------------
template <typename TA, int MODE>
__launch_bounds__(256)
__global__ void mfma_gemm(const TA* __restrict__ A, const bf16* __restrict__ Bt,
                          float* __restrict__ C,
                          int K, int kSeg, int lda, int ldb, int ldc,
                          long aZ, long bZ, long cZ) {
    __shared__ short As[2][64][72];
    __shared__ short Bs[2][64][72];

    const int z = blockIdx.z;
    const int tid = threadIdx.x;
    const int n0 = blockIdx.x * 64, m0 = blockIdx.y * 64;
    const int srow = tid >> 2, sk = (tid & 3) * 16;
    const int lane = tid & 63, w = tid >> 6, qd = lane >> 4, lc = lane & 15;

    int kBeg, kEnd;
    if constexpr (MODE == 1) {
        const int h = z >> 1, seg = z & 1;
        A += aZ * h;
        C += cZ * h + bZ * seg;
        const int kc = (m0 + 64 < K) ? m0 + 64 : K;
        const int half0 = ((kc + 127) >> 7) << 6;   // ceil(kc/128)*64
        kBeg = seg ? half0 : 0;
        kEnd = seg ? kc : half0;
    } else if constexpr (MODE == 2) {
        A += aZ * z; Bt += bZ * z; C += cZ * z;
        kBeg = z * kSeg; kEnd = kBeg + kSeg;
    } else if constexpr (MODE == 3) {
        A += aZ * z; Bt += bZ * z; C += cZ * z;
        kBeg = 0; kEnd = (m0 + 64 < K) ? m0 + 64 : K;
    } else {
        A += aZ * z; Bt += bZ * z; C += cZ * z;
        kBeg = 0; kEnd = K;
    }

    const TA*   ga = A  + (size_t)(m0 + srow) * lda + sk;
    const bf16* gb = Bt + (size_t)(n0 + srow) * ldb + sk;

    // two register sets for 2-deep prefetch (16 k-elems per operand each)
    float4 f00, f01, f02, f03, f10, f11, f12, f13;
    u16x8 pa00, pa01, pa10, pa11, pb00, pb01, pb10, pb11;
    auto load0 = [&](int k0) {
        if constexpr (__is_same(TA, float)) {
            f00 = *(const float4*)(ga + k0);
            f01 = *(const float4*)(ga + k0 + 4);
            f02 = *(const float4*)(ga + k0 + 8);
            f03 = *(const float4*)(ga + k0 + 12);
        } else {
            pa00 = *(const u16x8*)(ga + k0);
            pa01 = *(const u16x8*)(ga + k0 + 8);
        }
        pb00 = *(const u16x8*)(gb + k0);
        pb01 = *(const u16x8*)(gb + k0 + 8);
    };
    auto load1 = [&](int k0) {
        if constexpr (__is_same(TA, float)) {
            f10 = *(const float4*)(ga + k0);
            f11 = *(const float4*)(ga + k0 + 4);
            f12 = *(const float4*)(ga + k0 + 8);
            f13 = *(const float4*)(ga + k0 + 12);
        } else {
            pa10 = *(const u16x8*)(ga + k0);
            pa11 = *(const u16x8*)(ga + k0 + 8);
        }
        pb10 = *(const u16x8*)(gb + k0);
        pb11 = *(const u16x8*)(gb + k0 + 8);
    };
    auto dep0 = [&](int buf) {
        if constexpr (__is_same(TA, float)) {
            u16x8 o0, o1;
            o0[0] = f2us(f00.x); o0[1] = f2us(f00.y); o0[2] = f2us(f00.z); o0[3] = f2us(f00.w);
            o0[4] = f2us(f01.x); o0[5] = f2us(f01.y); o0[6] = f2us(f01.z); o0[7] = f2us(f01.w);
            o1[0] = f2us(f02.x); o1[1] = f2us(f02.y); o1[2] = f2us(f02.z); o1[3] = f2us(f02.w);
            o1[4] = f2us(f03.x); o1[5] = f2us(f03.y); o1[6] = f2us(f03.z); o1[7] = f2us(f03.w);
            *(u16x8*)&As[buf][srow][sk]     = o0;
            *(u16x8*)&As[buf][srow][sk + 8] = o1;
        } else {
            *(u16x8*)&As[buf][srow][sk]     = pa00;
            *(u16x8*)&As[buf][srow][sk + 8] = pa01;
        }
        *(u16x8*)&Bs[buf][srow][sk]     = pb00;
        *(u16x8*)&Bs[buf][srow][sk + 8] = pb01;
    };
    auto dep1 = [&](int buf) {
        if constexpr (__is_same(TA, float)) {
            u16x8 o0, o1;
            o0[0] = f2us(f10.x); o0[1] = f2us(f10.y); o0[2] = f2us(f10.z); o0[3] = f2us(f10.w);
            o0[4] = f2us(f11.x); o0[5] = f2us(f11.y); o0[6] = f2us(f11.z); o0[7] = f2us(f11.w);
            o1[0] = f2us(f12.x); o1[1] = f2us(f12.y); o1[2] = f2us(f12.z); o1[3] = f2us(f12.w);
            o1[4] = f2us(f13.x); o1[5] = f2us(f13.y); o1[6] = f2us(f13.z); o1[7] = f2us(f13.w);
            *(u16x8*)&As[buf][srow][sk]     = o0;
            *(u16x8*)&As[buf][srow][sk + 8] = o1;
        } else {
            *(u16x8*)&As[buf][srow][sk]     = pa10;
            *(u16x8*)&As[buf][srow][sk + 8] = pa11;
        }
        *(u16x8*)&Bs[buf][srow][sk]     = pb10;
        *(u16x8*)&Bs[buf][srow][sk + 8] = pb11;
    };

    f32x4 acc[4] = {{0.f,0.f,0.f,0.f},{0.f,0.f,0.f,0.f},
                    {0.f,0.f,0.f,0.f},{0.f,0.f,0.f,0.f}};
    auto mfma_step = [&](int buf) {
        #pragma unroll
        for (int half = 0; half < 2; half++) {
            s16x8 a = *(const s16x8*)&As[buf][w * 16 + lc][qd * 8 + half * 32];
            s16x8 b[4];
            #pragma unroll
            for (int j = 0; j < 4; j++)
                b[j] = *(const s16x8*)&Bs[buf][j * 16 + lc][qd * 8 + half * 32];
            #pragma unroll
            for (int j = 0; j < 4; j++)
                acc[j] = __builtin_amdgcn_mfma_f32_16x16x32_bf16(a, b[j], acc[j], 0, 0, 0);
        }
    };

    const int NIT = (kEnd - kBeg) >> 6;
    // prologue over-reads stay inside the workspace (rows are long enough or
    // followed by live ws regions; unconsumed when NIT small).
    load0(kBeg);
    load1(kBeg + 64);
    dep0(0);
    __syncthreads();

    for (int k = 0; k < NIT; k += 2) {
        if (k + 2 < NIT) load0(kBeg + (k + 2) * 64);
        mfma_step(0);
        if (k + 1 < NIT) dep1(1);
        __syncthreads();
        if (k + 1 < NIT) {
            if (k + 3 < NIT) load1(kBeg + (k + 3) * 64);
            mfma_step(1);
            if (k + 2 < NIT) dep0(0);
            __syncthreads();
        }
    }

    #pragma unroll
    for (int j = 0; j < 4; j++) {
        int n = n0 + j * 16 + lc;
        #pragma unroll
        for (int r = 0; r < 4; r++) {
            int m = m0 + w * 16 + qd * 4 + r;
            C[(size_t)m * ldc + n] = acc[j][r];
        }
    }
}

extern "C" void kernel_launch(void* const* d_in, const int* in_sizes, int n_in,
                              void* d_out, int out_size, void* d_ws, size_t ws_size,
                              hipStream_t stream) {
    const int*   idx   = (const int*)  d_in[0];
    const float* dec_x = (const float*)d_in[1];   // (NH, D, N)
    const float* dec_y = (const float*)d_in[2];   // (NH, D, N)
    const float* enc   = (const float*)d_in[3];   // (NH*N, D)
    const float* emb   = (const float*)d_in[4];   // (VOCAB, D)
    const float* pose  = (const float*)d_in[5];   // (BLOCK, D)
    const float* lmh   = (const float*)d_in[6];   // (D, VOCAB)
    float* out = (float*)d_out;                   // (T, VOCAB) fp32

    // workspace layout — identical to passing r11 (ws >= 84,377,600 proven)
    char* wp = (char*)d_ws;
    float*   x    = (float*)wp;              wp += (size_t)T_SEQ * D_DIM * 4;
    bf16*    xs   = (bf16*)wp;               wp += (size_t)T_SEQ * HN * 2;
    ushort2* csT  = (ushort2*)wp;            wp += (size_t)T_SEQ * NP2 * 4;
    bf16*    sc   = (bf16*)wp;               wp += (size_t)NHEAD * T_SEQ * T_SEQ * 2;
    float*   ykv  = (float*)wp;              wp += (size_t)NHEAD * T_SEQ * D_DIM * 4;
    float*   ymlp = (float*)wp;              wp += (size_t)T_SEQ * D_DIM * 4;   // layout keeper
    bf16*    xT   = (bf16*)wp;               wp += (size_t)D_DIM * T_SEQ * 2;
    bf16*    wX   = (bf16*)wp;               wp += (size_t)NHEAD * N_DIM * D_DIM * 2;
    bf16*    wY   = (bf16*)wp;               wp += (size_t)NHEAD * N_DIM * D_DIM * 2;
    bf16*    wE   = (bf16*)wp;               wp += (size_t)D_DIM * HN * 2;
    bf16*    wL   = (bf16*)wp;               wp += (size_t)VOCABSZ * D_DIM * 2;
    const size_t BASE_NEED = (size_t)(wp - (char*)d_ws);
    bf16*    qr   = (bf16*)wp;
    const size_t FULL_NEED = BASE_NEED + (size_t)T_SEQ * HN * 2;
    float* ymlpP = (float*)sc;     // 8 slabs x T*D x 4B overlay on dead sc region
    bf16*  dbuf  = (bf16*)ykv;     // 512 KB diag partials overlay on idle ykv region

    if (ws_size < BASE_NEED) {
        fill_out<<<(out_size + 255) / 256, 256, 0, stream>>>(out, (float)ws_size, out_size);
        return;
    }
    const bool USE_QR = (ws_size >= FULL_NEED);

    // weight mirrors (bf16, [n][k])
    t_cvt<<<dim3(48, 3, 4), 256, 0, stream>>>(dec_x, wX, D_DIM, N_DIM,
                                              (long)D_DIM * N_DIM, (long)N_DIM * D_DIM);
    t_cvt<<<dim3(48, 3, 4), 256, 0, stream>>>(dec_y, wY, D_DIM, N_DIM,
                                              (long)D_DIM * N_DIM, (long)N_DIM * D_DIM);
    t_cvt<<<dim3(3, 192, 1), 256, 0, stream>>>(enc, wE, HN, D_DIM, 0L, 0L);
    t_cvt<<<dim3(4, 3, 1), 256, 0, stream>>>(lmh, wL, D_DIM, VOCABSZ, 0L, 0L);

    k_tables<<<(T_SEQ * NP2) / 256, 256, 0, stream>>>(csT);
    k_embed<<<T_SEQ, 64, 0, stream>>>(idx, emb, pose, x);

    for (int l = 0; l < NLAYER; ++l) {
        // xT = x^T (bf16) for ykv's B operand
        t_cvt<<<dim3(3, 16, 1), 256, 0, stream>>>(x, xT, T_SEQ, D_DIM, 0L, 0L);
        // xs = relu(x @ dec_x)  (+ fused qr when available)
        if (USE_QR) {
            dgemm128<1, true><<<dim3(96, 8), 256, 0, stream>>>(x, wX, xs, qr, csT);
            scores64<<<dim3(136, 2, NHEAD), 256, 0, stream>>>(qr, sc, dbuf);
            k_comb<<<dim3(136, 1, NHEAD), 256, 0, stream>>>(sc, dbuf);
            // ykv = sc @ x  (causal, split-K=2; slab1 on dead qr region)
            long segZ = (long)((float*)qr - ykv);
            mfma_gemm<bf16, 1><<<dim3(3, 16, NHEAD * 2), 256, 0, stream>>>(
                sc, xT, ykv, T_SEQ, 0, T_SEQ, T_SEQ, D_DIM,
                (long)T_SEQ * T_SEQ, segZ, (long)T_SEQ * D_DIM);
            // ykv = LN(slab0 + slab1)
            k_ln2<<<NHEAD * T_SEQ, 64, 0, stream>>>(ykv, (const float*)qr);
        } else {
            dgemm128<1, false><<<dim3(96, 8), 256, 0, stream>>>(x, wX, xs, qr, csT);
            scores_fused<<<dim3(16, 16, NHEAD), 256, 0, stream>>>(xs, csT, sc);
            mfma_gemm<bf16, 3><<<dim3(3, 16, NHEAD), 256, 0, stream>>>(
                sc, xT, ykv, T_SEQ, 0, T_SEQ, T_SEQ, D_DIM,
                (long)T_SEQ * T_SEQ, 0L, (long)T_SEQ * D_DIM);
            k_ln<<<NHEAD * T_SEQ, 64, 0, stream>>>(ykv);
        }
        // xs *= relu(ykv @ dec_y)   (gate; head slab picked inside kernel)
        dgemm128<2, false><<<dim3(96, 8), 256, 0, stream>>>(
            (const float*)ykv, wY, xs, nullptr, nullptr);
        // ymlp partials = xy @ enc   (split-K=8 -> slabs in sc region)
        mfma_gemm<bf16, 2><<<dim3(3, 16, 8), 256, 0, stream>>>(
            xs, wE, ymlpP, HN, HN / 8, HN, HN, D_DIM,
            0L, 0L, (long)T_SEQ * D_DIM);
        // x = LN(x + LN(sum partials))
        k_resid8<<<T_SEQ, 64, 0, stream>>>(x, ymlpP);
        (void)ymlp;
    }

    // logits = x @ lm_head
    mfma_gemm<float, 0><<<dim3(4, 16, 1), 256, 0, stream>>>(
        x, wL, out, D_DIM, 0, D_DIM, D_DIM, VOCABSZ, 0L, 0L, 0L);
}

// Round 7
// 516.557 us; speedup vs baseline: 1.2957x; 1.0118x over previous
//
#include <hip/hip_runtime.h>
#include <hip/hip_bf16.h>

using bf16 = __hip_bfloat16;

#define D_DIM   192
#define N_DIM   3072
#define NHEAD   4
#define T_SEQ   1024
#define HN      12288      // NHEAD * N_DIM
#define NP2     1536       // N_DIM/2
#define VOCABSZ 256
#define NLAYER  4
#define LN_EPS  1e-5f
#define TWO_PI  6.2831853071795864f

typedef __attribute__((ext_vector_type(8)))  short          s16x8;
typedef __attribute__((ext_vector_type(8)))  unsigned short u16x8;
typedef __attribute__((ext_vector_type(4)))  float          f32x4;
typedef __attribute__((ext_vector_type(16))) float          f32x16;

__device__ __forceinline__ float b2f(bf16 v) { return __bfloat162float(v); }
__device__ __forceinline__ float us2f(unsigned short u) {
    unsigned int x = ((unsigned int)u) << 16;
    return __builtin_bit_cast(float, x);
}
__device__ __forceinline__ unsigned short f2us(float f) {
    bf16 b = __float2bfloat16(f);
    return __builtin_bit_cast(unsigned short, b);
}

// sentinel: encode ws_size into output (fires only if ws too small)
__global__ void fill_out(float* __restrict__ out, float val, int nelem) {
    int i = blockIdx.x * 256 + threadIdx.x;
    if (i < nelem) out[i] = val;
}

// ---------------------------------------------------------------------------
// Tiled transpose + fp32->bf16: in fp32 [R][C] -> out bf16 [C][R].
// ---------------------------------------------------------------------------
__global__ void t_cvt(const float* __restrict__ in, bf16* __restrict__ out,
                      int R, int C, long inZ, long outZ) {
    __shared__ float tile[64][65];
    in  += inZ  * blockIdx.z;
    out += outZ * blockIdx.z;
    const int tx = threadIdx.x & 63, ty = threadIdx.x >> 6;
    const int r0 = blockIdx.y * 64, c0 = blockIdx.x * 64;
    #pragma unroll
    for (int rr = 0; rr < 16; rr++) {
        int row = ty * 16 + rr;
        tile[row][tx] = in[(size_t)(r0 + row) * C + c0 + tx];
    }
    __syncthreads();
    #pragma unroll
    for (int rr = 0; rr < 16; rr++) {
        int row = ty * 16 + rr;
        out[(size_t)(c0 + row) * R + r0 + tx] = __float2bfloat16(tile[tx][row]);
    }
}

// ---------------------------------------------------------------------------
// Wave-per-row LN family (64 threads/block, 3 elems/lane, butterfly reduce)
// ---------------------------------------------------------------------------
__device__ __forceinline__ void wave_sum2(float& s, float& ss) {
    #pragma unroll
    for (int off = 1; off < 64; off <<= 1) {
        s  += __shfl_xor(s,  off, 64);
        ss += __shfl_xor(ss, off, 64);
    }
}

__global__ void k_embed(const int* __restrict__ idx, const float* __restrict__ emb,
                        const float* __restrict__ pos, float* __restrict__ x) {
    int t = blockIdx.x, l = threadIdx.x;
    int tok = idx[t];
    const float* e = emb + tok * D_DIM;
    const float* p = pos + t * D_DIM;
    float v0 = e[l] + p[l], v1 = e[l + 64] + p[l + 64], v2 = e[l + 128] + p[l + 128];
    float s = v0 + v1 + v2, ss = v0 * v0 + v1 * v1 + v2 * v2;
    wave_sum2(s, ss);
    float m = s / D_DIM, r = rsqrtf(ss / D_DIM - m * m + LN_EPS);
    float* xr = x + t * D_DIM;
    xr[l] = (v0 - m) * r; xr[l + 64] = (v1 - m) * r; xr[l + 128] = (v2 - m) * r;
}

__global__ void k_ln(float* __restrict__ buf) {
    int l = threadIdx.x;
    float* row = buf + (size_t)blockIdx.x * D_DIM;
    float v0 = row[l], v1 = row[l + 64], v2 = row[l + 128];
    float s = v0 + v1 + v2, ss = v0 * v0 + v1 * v1 + v2 * v2;
    wave_sum2(s, ss);
    float m = s / D_DIM, r = rsqrtf(ss / D_DIM - m * m + LN_EPS);
    row[l] = (v0 - m) * r; row[l + 64] = (v1 - m) * r; row[l + 128] = (v2 - m) * r;
}

// row = LN(row + P1row)  — fuses ykv split-K=2 slab sum into the LN pass
__global__ void k_ln2(float* __restrict__ buf, const float* __restrict__ P1) {
    int l = threadIdx.x;
    size_t off = (size_t)blockIdx.x * D_DIM;
    float* row = buf + off;
    const float* r1 = P1 + off;
    float v0 = row[l] + r1[l];
    float v1 = row[l + 64] + r1[l + 64];
    float v2 = row[l + 128] + r1[l + 128];
    float s = v0 + v1 + v2, ss = v0 * v0 + v1 * v1 + v2 * v2;
    wave_sum2(s, ss);
    float m = s / D_DIM, r = rsqrtf(ss / D_DIM - m * m + LN_EPS);
    row[l] = (v0 - m) * r; row[l + 64] = (v1 - m) * r; row[l + 128] = (v2 - m) * r;
}

// x = LN(x + LN(sum of 8 split-K partial slabs))
__global__ void k_resid8(float* __restrict__ x, const float* __restrict__ P) {
    int l = threadIdx.x, t = blockIdx.x;
    float y0 = 0.f, y1 = 0.f, y2 = 0.f;
    #pragma unroll
    for (int p = 0; p < 8; p++) {
        const float* r = P + (size_t)p * T_SEQ * D_DIM + (size_t)t * D_DIM;
        y0 += r[l]; y1 += r[l + 64]; y2 += r[l + 128];
    }
    float* xr = x + (size_t)t * D_DIM;
    float s = y0 + y1 + y2, ss = y0 * y0 + y1 * y1 + y2 * y2;
    wave_sum2(s, ss);
    float m1 = s / D_DIM, r1 = rsqrtf(ss / D_DIM - m1 * m1 + LN_EPS);
    float v0 = xr[l] + (y0 - m1) * r1;
    float v1 = xr[l + 64] + (y1 - m1) * r1;
    float v2 = xr[l + 128] + (y2 - m1) * r1;
    s = v0 + v1 + v2; ss = v0 * v0 + v1 * v1 + v2 * v2;
    wave_sum2(s, ss);
    float m2 = s / D_DIM, r2 = rsqrtf(ss / D_DIM - m2 * m2 + LN_EPS);
    xr[l] = (v0 - m2) * r2; xr[l + 64] = (v1 - m2) * r2; xr[l + 128] = (v2 - m2) * r2;
}

// RoPE cos/sin tables, interleaved bf16 pairs csT[t][p] = (cos, sin)
__global__ void k_tables(ushort2* __restrict__ csT) {
    int gid = blockIdx.x * 256 + threadIdx.x;
    int t = gid / NP2, p = gid % NP2;
    float qf = (float)(2 * p);
    float f = exp2f(qf * (-16.0f / 3072.0f)) * (1.0f / (float)TWO_PI);
    float ph = fmodf((float)t * f, 1.0f) * (float)TWO_PI;
    ushort2 cs;
    cs.x = f2us(cosf(ph));
    cs.y = f2us(sinf(ph));
    csT[gid] = cs;
}

// ---------------------------------------------------------------------------
// scores64: partial scores, split-K=2 over grid.y (1088 blocks).
//   kh=0: lower-K half -> lower tile (i,j), masked if diag.
//   kh=1 off-diag: upper-K half with swapped operands -> stored in the DEAD
//     strictly-upper slot (j,i) but in (t,s) ORIENTATION (transposed scatter
//     into LDS), so the ykv GEMM can consume it with coalesced row reads.
//   kh=1 diag: masked partial -> dbuf slab (on idle ymlp-keeper region).
// NO k_comb: ykv dual-A MFMA combines partials in fp32.
// 64x64 tile, 4 waves x one 32x32x16 MFMA acc, BK=64, double-buffered LDS +
// 2-deep register prefetch. Rows padded to 72 shorts. XCD remap (136=8*17).
// ---------------------------------------------------------------------------
__launch_bounds__(256, 4)
__global__ void scores64(const bf16* __restrict__ qr, bf16* __restrict__ sc,
                         bf16* __restrict__ dbuf) {
    const int h  = blockIdx.z;
    const int kh = blockIdx.y;                     // K-half
    const int orig = blockIdx.x;
    const int L = (orig & 7) * 17 + (orig >> 3);   // bijective: 136 = 8*17
    int i = 0;
    while (((i + 1) * (i + 2)) >> 1 <= L) ++i;
    int j = L - ((i * (i + 1)) >> 1);
    const int t0 = i * 64, s0 = j * 64;
    const bool diag = (i == j);

    // operand roles: kh=1 off-diag computes the transposed tile directly
    int arow = t0, brow = s0;
    if (kh == 1 && !diag) { arow = s0; brow = t0; }

    __shared__ short As[2][64][72];
    __shared__ short Bs[2][64][72];

    const int tid = threadIdx.x;
    const int lane = tid & 63, w = tid >> 6;
    const int wtm = (w >> 1) * 32, wtn = (w & 1) * 32;
    const int l31 = lane & 31, lhi = lane >> 5;    // 32x32 frag addressing
    const int r0 = tid >> 2;                       // staging row 0..63
    const int kq = (tid & 3) * 16;                 // staging k-offset

    const int kBeg = kh * (N_DIM / 2);
    const bf16* gA = qr + (size_t)(arow + r0) * HN + h * N_DIM + kBeg + kq;
    const bf16* gB = qr + (size_t)(brow + r0) * HN + h * N_DIM + kBeg + kq;

    // two named register sets (static indexing only — no scratch)
    u16x8 pa0, pa1, pb0, pb1;   // set 0: even iters
    u16x8 qa0, qa1, qb0, qb1;   // set 1: odd iters
    auto load0 = [&](int k0) {
        pa0 = *(const u16x8*)(gA + k0);
        pa1 = *(const u16x8*)(gA + k0 + 8);
        pb0 = *(const u16x8*)(gB + k0);
        pb1 = *(const u16x8*)(gB + k0 + 8);
    };
    auto load1 = [&](int k0) {
        qa0 = *(const u16x8*)(gA + k0);
        qa1 = *(const u16x8*)(gA + k0 + 8);
        qb0 = *(const u16x8*)(gB + k0);
        qb1 = *(const u16x8*)(gB + k0 + 8);
    };
    auto dep0 = [&](int buf) {
        *(u16x8*)&As[buf][r0][kq]     = pa0;
        *(u16x8*)&As[buf][r0][kq + 8] = pa1;
        *(u16x8*)&Bs[buf][r0][kq]     = pb0;
        *(u16x8*)&Bs[buf][r0][kq + 8] = pb1;
    };
    auto dep1 = [&](int buf) {
        *(u16x8*)&As[buf][r0][kq]     = qa0;
        *(u16x8*)&As[buf][r0][kq + 8] = qa1;
        *(u16x8*)&Bs[buf][r0][kq]     = qb0;
        *(u16x8*)&Bs[buf][r0][kq + 8] = qb1;
    };

    f32x16 acc;
    #pragma unroll
    for (int r = 0; r < 16; r++) acc[r] = 0.f;

    auto mfma_step = [&](int buf) {
        #pragma unroll
        for (int ks = 0; ks < 4; ks++) {
            s16x8 a = *(const s16x8*)&As[buf][wtm + l31][ks * 16 + lhi * 8];
            s16x8 b = *(const s16x8*)&Bs[buf][wtn + l31][ks * 16 + lhi * 8];
            acc = __builtin_amdgcn_mfma_f32_32x32x16_bf16(a, b, acc, 0, 0, 0);
        }
    };

    const int NIT = (N_DIM / 2) / 64;   // 24 (even)
    load0(0);
    load1(64);
    dep0(0);
    __syncthreads();

    for (int k = 0; k < NIT; k += 2) {
        if (k + 2 < NIT) load0((k + 2) * 64);
        mfma_step(0);
        if (k + 1 < NIT) dep1(1);
        __syncthreads();
        if (k + 1 < NIT) {
            if (k + 3 < NIT) load1((k + 3) * 64);
            mfma_step(1);
            if (k + 2 < NIT) dep0(0);
            __syncthreads();
        }
    }

    // -------- LDS-staged coalesced epilogue --------
    __syncthreads();                               // all waves done with As
    short (*S)[72] = (short(*)[72])&As[0][0][0];   // 64x72 tile reuse
    const bool trS = (kh == 1) && !diag;           // store transposed (t,s)
    #pragma unroll
    for (int r = 0; r < 16; r++) {
        // 32x32x16 C/D layout: col = lane&31, row = (r&3)+8*(r>>2)+4*(lane>>5)
        int rr = wtm + (r & 3) + 8 * (r >> 2) + 4 * lhi;
        int cc = wtn + l31;
        float v = acc[r];
        if (diag && cc >= rr) v = 0.f;
        if (trS) S[cc][rr] = (short)f2us(v);       // M[t_local][s_local]
        else     S[rr][cc] = (short)f2us(v);
    }
    __syncthreads();
    if (kh == 1 && diag) {
        bf16* P = dbuf + (size_t)(h * 16 + i) * 4096;
        #pragma unroll
        for (int e = 0; e < 2; e++) {
            int idxe = tid + e * 256;
            int row = idxe >> 3, cg = (idxe & 7) * 8;
            u16x8 v = *(const u16x8*)&S[row][cg];
            *(u16x8*)(P + row * 64 + cg) = v;
        }
    } else {
        // kh0: lower slot (t-rows t0, s-cols s0).
        // kh1 off-diag: upper slot (rows s0=j*64 hold t_local, cols t0=i*64
        //   hold s_local) — (t,s)-oriented content, read by ykv mirror path.
        bf16* C = sc + (size_t)h * T_SEQ * T_SEQ;
        #pragma unroll
        for (int e = 0; e < 2; e++) {
            int idxe = tid + e * 256;
            int row = idxe >> 3, cg = (idxe & 7) * 8;
            u16x8 v = *(const u16x8*)&S[row][cg];
            *(u16x8*)(C + (size_t)(arow + row) * T_SEQ + brow + cg) = v;
        }
    }
}

// ---------------------------------------------------------------------------
// scores fallback (no qr buffer): 64x64, rope fused into staging.
// ---------------------------------------------------------------------------
__device__ __forceinline__ void stage_rope8(short* dst, const bf16* src,
                                            const ushort2* csP) {
    u16x8 v  = *(const u16x8*)src;
    u16x8 cs = *(const u16x8*)csP;
    u16x8 o;
    #pragma unroll
    for (int i = 0; i < 4; i++) {
        float e  = us2f(v[2 * i]), od = us2f(v[2 * i + 1]);
        float c  = us2f(cs[2 * i]), s = us2f(cs[2 * i + 1]);
        o[2 * i]     = f2us(e * c - od * s);
        o[2 * i + 1] = f2us(od * c + e * s);
    }
    *(u16x8*)dst = o;
}

__launch_bounds__(256)
__global__ void scores_fused(const bf16* __restrict__ xs,
                             const ushort2* __restrict__ csT,
                             bf16* __restrict__ sc) {
    const int h  = blockIdx.z;
    const int s0 = blockIdx.x * 64, t0 = blockIdx.y * 64;
    if (s0 > t0) return;
    __shared__ short As[64][40];
    __shared__ short Bs[64][40];
    const int tid  = threadIdx.x;
    const int srow = tid >> 2, kq = (tid & 3) * 8;
    const int lane = tid & 63, w = tid >> 6, qd = lane >> 4, lc = lane & 15;
    const int tA = t0 + srow, tB = s0 + srow;
    const bf16* gA = xs + (size_t)tA * HN + h * N_DIM + kq;
    const bf16* gB = xs + (size_t)tB * HN + h * N_DIM + kq;
    const ushort2* cA = csT + (size_t)tA * NP2 + (kq >> 1);
    const ushort2* cB = csT + (size_t)tB * NP2 + (kq >> 1);
    f32x4 acc[4] = {{0.f,0.f,0.f,0.f},{0.f,0.f,0.f,0.f},
                    {0.f,0.f,0.f,0.f},{0.f,0.f,0.f,0.f}};
    for (int k0 = 0; k0 < N_DIM; k0 += 32) {
        stage_rope8(&As[srow][kq], gA + k0, cA + (k0 >> 1));
        stage_rope8(&Bs[srow][kq], gB + k0, cB + (k0 >> 1));
        __syncthreads();
        s16x8 a = *(const s16x8*)&As[w * 16 + lc][qd * 8];
        #pragma unroll
        for (int j = 0; j < 4; j++) {
            s16x8 b = *(const s16x8*)&Bs[j * 16 + lc][qd * 8];
            acc[j] = __builtin_amdgcn_mfma_f32_16x16x32_bf16(a, b, acc[j], 0, 0, 0);
        }
        __syncthreads();
    }
    bf16* C = sc + (size_t)h * T_SEQ * T_SEQ;
    const bool diag = (s0 == t0);
    const int tbase = t0 + w * 16 + qd * 4;
    #pragma unroll
    for (int j = 0; j < 4; j++) {
        int s = s0 + j * 16 + lc;
        #pragma unroll
        for (int r = 0; r < 4; r++) {
            int t = tbase + r;
            C[(size_t)t * T_SEQ + s] =
                __float2bfloat16((!diag || s < t) ? acc[j][r] : 0.f);
        }
    }
}

// ---------------------------------------------------------------------------
// dgemm128: 128x128 tile, 4 waves x (64x64), K=192, double-buffered LDS +
// 2-DEEP register prefetch. LDS-staged coalesced epilogue (relu/rope/gate).
// (unchanged this round — control)
// ---------------------------------------------------------------------------
template <int EPI, bool WQR>
__launch_bounds__(256)
__global__ void dgemm128(const float* __restrict__ A, const bf16* __restrict__ Bt,
                         bf16* __restrict__ xs, bf16* __restrict__ qr,
                         const ushort2* __restrict__ csT) {
    __shared__ __align__(16) short pool[2 * 2 * 128 * 40];   // 40 KB
    short (*As)[128][40] = (short(*)[128][40])pool;
    short (*Bs)[128][40] = (short(*)[128][40])(pool + 2 * 128 * 40);

    const int tid = threadIdx.x;
    const int lane = tid & 63, w = tid >> 6, qd = lane >> 4, lc = lane & 15;
    const int wtm = (w >> 1) * 64, wtn = (w & 1) * 64;
    const int n0 = blockIdx.x * 128, m0 = blockIdx.y * 128;
    if constexpr (EPI == 2) A += (size_t)(n0 / N_DIM) * T_SEQ * D_DIM;

    const int r0 = tid >> 2, r1 = r0 + 64;
    const int kq = (tid & 3) * 8;

    const float* gA = A  + kq;
    const bf16*  gB = Bt + kq;

    float4 fa00, fa01, fa02, fa03, fa10, fa11, fa12, fa13;
    u16x8 pb00, pb01, pb10, pb11;
    auto load0 = [&](int k0) {
        const float* a0 = gA + (size_t)(m0 + r0) * D_DIM + k0;
        const float* a1 = gA + (size_t)(m0 + r1) * D_DIM + k0;
        fa00 = *(const float4*)a0; fa01 = *(const float4*)(a0 + 4);
        fa02 = *(const float4*)a1; fa03 = *(const float4*)(a1 + 4);
        pb00 = *(const u16x8*)(gB + (size_t)(n0 + r0) * D_DIM + k0);
        pb01 = *(const u16x8*)(gB + (size_t)(n0 + r1) * D_DIM + k0);
    };
    auto load1 = [&](int k0) {
        const float* a0 = gA + (size_t)(m0 + r0) * D_DIM + k0;
        const float* a1 = gA + (size_t)(m0 + r1) * D_DIM + k0;
        fa10 = *(const float4*)a0; fa11 = *(const float4*)(a0 + 4);
        fa12 = *(const float4*)a1; fa13 = *(const float4*)(a1 + 4);
        pb10 = *(const u16x8*)(gB + (size_t)(n0 + r0) * D_DIM + k0);
        pb11 = *(const u16x8*)(gB + (size_t)(n0 + r1) * D_DIM + k0);
    };
    auto dep0 = [&](int buf) {
        u16x8 o0, o1;
        o0[0] = f2us(fa00.x); o0[1] = f2us(fa00.y); o0[2] = f2us(fa00.z); o0[3] = f2us(fa00.w);
        o0[4] = f2us(fa01.x); o0[5] = f2us(fa01.y); o0[6] = f2us(fa01.z); o0[7] = f2us(fa01.w);
        o1[0] = f2us(fa02.x); o1[1] = f2us(fa02.y); o1[2] = f2us(fa02.z); o1[3] = f2us(fa02.w);
        o1[4] = f2us(fa03.x); o1[5] = f2us(fa03.y); o1[6] = f2us(fa03.z); o1[7] = f2us(fa03.w);
        *(u16x8*)&As[buf][r0][kq] = o0;
        *(u16x8*)&As[buf][r1][kq] = o1;
        *(u16x8*)&Bs[buf][r0][kq] = pb00;
        *(u16x8*)&Bs[buf][r1][kq] = pb01;
    };
    auto dep1 = [&](int buf) {
        u16x8 o0, o1;
        o0[0] = f2us(fa10.x); o0[1] = f2us(fa10.y); o0[2] = f2us(fa10.z); o0[3] = f2us(fa10.w);
        o0[4] = f2us(fa11.x); o0[5] = f2us(fa11.y); o0[6] = f2us(fa11.z); o0[7] = f2us(fa11.w);
        o1[0] = f2us(fa12.x); o1[1] = f2us(fa12.y); o1[2] = f2us(fa12.z); o1[3] = f2us(fa12.w);
        o1[4] = f2us(fa13.x); o1[5] = f2us(fa13.y); o1[6] = f2us(fa13.z); o1[7] = f2us(fa13.w);
        *(u16x8*)&As[buf][r0][kq] = o0;
        *(u16x8*)&As[buf][r1][kq] = o1;
        *(u16x8*)&Bs[buf][r0][kq] = pb10;
        *(u16x8*)&Bs[buf][r1][kq] = pb11;
    };

    f32x4 acc[4][4] = {};
    auto mfma_step = [&](int buf) {
        s16x8 a[4], b[4];
        #pragma unroll
        for (int m = 0; m < 4; m++) a[m] = *(const s16x8*)&As[buf][wtm + m * 16 + lc][qd * 8];
        #pragma unroll
        for (int n = 0; n < 4; n++) b[n] = *(const s16x8*)&Bs[buf][wtn + n * 16 + lc][qd * 8];
        #pragma unroll
        for (int m = 0; m < 4; m++)
            #pragma unroll
            for (int n = 0; n < 4; n++)
                acc[m][n] = __builtin_amdgcn_mfma_f32_16x16x32_bf16(a[m], b[n], acc[m][n], 0, 0, 0);
    };

    const int NIT = D_DIM / 32;   // 6 (even)
    load0(0);
    load1(32);
    dep0(0);
    __syncthreads();
    for (int k = 0; k < NIT; k += 2) {
        if (k + 2 < NIT) load0((k + 2) * 32);
        mfma_step(0);
        if (k + 1 < NIT) dep1(1);
        __syncthreads();
        if (k + 1 < NIT) {
            if (k + 3 < NIT) load1((k + 3) * 32);
            mfma_step(1);
            if (k + 2 < NIT) dep0(0);
            __syncthreads();
        }
    }

    // -------- LDS-staged epilogue --------
    short (*S)[136] = (short(*)[136])pool; // 128 x 136 shorts = 34.8 KB <= 40 KB
    #pragma unroll
    for (int m = 0; m < 4; m++) {
        #pragma unroll
        for (int r = 0; r < 4; r++) {
            int tl = wtm + m * 16 + qd * 4 + r;
            #pragma unroll
            for (int n = 0; n < 4; n++) {
                int cl = wtn + n * 16 + lc;
                S[tl][cl] = (short)f2us(fmaxf(acc[m][n][r], 0.f));
            }
        }
    }
    __syncthreads();
    #pragma unroll
    for (int e = 0; e < 8; e++) {
        int idxe = tid + e * 256;
        int row = idxe >> 4, cg = idxe & 15;
        u16x8 v = *(const u16x8*)&S[row][cg * 8];
        int t = m0 + row, ngg = n0 + cg * 8;
        size_t ci = (size_t)t * HN + ngg;
        if constexpr (EPI == 1) {
            *(u16x8*)(xs + ci) = v;
            if constexpr (WQR) {
                int p0 = (ngg % N_DIM) >> 1;
                u16x8 cs8 = *(const u16x8*)&csT[(size_t)t * NP2 + p0];
                u16x8 o;
                #pragma unroll
                for (int q = 0; q < 4; q++) {
                    float ev = us2f(v[2 * q]), ov = us2f(v[2 * q + 1]);
                    float c = us2f(cs8[2 * q]), s = us2f(cs8[2 * q + 1]);
                    o[2 * q]     = f2us(ev * c - ov * s);
                    o[2 * q + 1] = f2us(ov * c + ev * s);
                }
                *(u16x8*)(qr + ci) = o;
            }
        } else {
            u16x8 g = *(const u16x8*)(xs + ci);
            u16x8 o;
            #pragma unroll
            for (int q = 0; q < 8; q++) o[q] = f2us(us2f(g[q]) * us2f(v[q]));
            *(u16x8*)(xs + ci) = o;
        }
    }
}

// ---------------------------------------------------------------------------
// mfma_gemm (64x64): MODE 0 = plain, 1 = causal split-K=2 WITH dual-A partial
// combine (lower slot + mirror/dbuf partial, fp32 accumulate — replaces
// k_comb), 2 = split-K slabs over z, 3 = causal full (fallback, combined sc).
// 32x32x16 MFMA (1 acc/wave), BK=64, double-buffered LDS + 2-deep register
// prefetch. Rows padded to 72 shorts.
// ---------------------------------------------------------------------------
template <typename TA, int MODE>
__launch_bounds__(256)
__global__ void mfma_gemm(const TA* __restrict__ A, const bf16* __restrict__ Bt,
                          float* __restrict__ C, const bf16* __restrict__ aux,
                          int K, int kSeg, int lda, int ldb, int ldc,
                          long aZ, long bZ, long cZ) {
    constexpr bool DUAL = (MODE == 1);
    constexpr int TILES = DUAL ? 6 : 4;
    __shared__ __align__(16) short pool[TILES * 64 * 72];
    short (*As)[64][72] = (short(*)[64][72])pool;
    short (*Bs)[64][72] = (short(*)[64][72])(pool + 2 * 64 * 72);
    short (*Ms)[64][72] = (short(*)[64][72])(pool + 4 * 64 * 72);

    const int z = blockIdx.z;
    const int tid = threadIdx.x;
    const int n0 = blockIdx.x * 64, m0 = blockIdx.y * 64;
    const int srow = tid >> 2, sk = (tid & 3) * 16;
    const int lane = tid & 63, w = tid >> 6;
    const int l31 = lane & 31, lhi = lane >> 5;
    const int wm = (w >> 1) * 32, wn = (w & 1) * 32;

    int kBeg, kEnd, zh = 0;
    if constexpr (MODE == 1) {
        zh = z >> 1;
        const int seg = z & 1;
        A += aZ * zh;
        C += cZ * zh + bZ * seg;
        const int kc = (m0 + 64 < K) ? m0 + 64 : K;
        const int half0 = ((kc + 127) >> 7) << 6;   // ceil(kc/128)*64
        kBeg = seg ? half0 : 0;
        kEnd = seg ? kc : half0;
    } else if constexpr (MODE == 2) {
        A += aZ * z; Bt += bZ * z; C += cZ * z;
        kBeg = z * kSeg; kEnd = kBeg + kSeg;
    } else if constexpr (MODE == 3) {
        A += aZ * z; Bt += bZ * z; C += cZ * z;
        kBeg = 0; kEnd = (m0 + 64 < K) ? m0 + 64 : K;
    } else {
        A += aZ * z; Bt += bZ * z; C += cZ * z;
        kBeg = 0; kEnd = K;
    }

    const TA*   ga = A  + (size_t)(m0 + srow) * lda + sk;
    const bf16* gb = Bt + (size_t)(n0 + srow) * ldb + sk;

    // mirror-partial source for DUAL (valid only when TA = bf16, MODE 1):
    //   diag block (k0 == m0): dbuf slab (t,s)-oriented, masked.
    //   off-diag: upper slot at sc[(j*64 + t_local)*lda + i*64 + s_local].
    auto msrc = [&](int k0) -> const bf16* {
        if (k0 == m0)
            return aux + (size_t)(zh * 16 + (m0 >> 6)) * 4096
                       + (size_t)srow * 64 + sk;
        return (const bf16*)A + (size_t)(k0 + srow) * lda + m0 + sk;
    };

    // two register sets for 2-deep prefetch
    float4 f00, f01, f02, f03, f10, f11, f12, f13;
    u16x8 pa00, pa01, pa10, pa11, pb00, pb01, pb10, pb11;
    u16x8 pm00, pm01, pm10, pm11;
    auto load0 = [&](int k0) {
        if constexpr (__is_same(TA, float)) {
            f00 = *(const float4*)(ga + k0);
            f01 = *(const float4*)(ga + k0 + 4);
            f02 = *(const float4*)(ga + k0 + 8);
            f03 = *(const float4*)(ga + k0 + 12);
        } else {
            pa00 = *(const u16x8*)(ga + k0);
            pa01 = *(const u16x8*)(ga + k0 + 8);
        }
        pb00 = *(const u16x8*)(gb + k0);
        pb01 = *(const u16x8*)(gb + k0 + 8);
        if constexpr (DUAL) {
            const bf16* ms = msrc(k0);
            pm00 = *(const u16x8*)ms;
            pm01 = *(const u16x8*)(ms + 8);
        }
    };
    auto load1 = [&](int k0) {
        if constexpr (__is_same(TA, float)) {
            f10 = *(const float4*)(ga + k0);
            f11 = *(const float4*)(ga + k0 + 4);
            f12 = *(const float4*)(ga + k0 + 8);
            f13 = *(const float4*)(ga + k0 + 12);
        } else {
            pa10 = *(const u16x8*)(ga + k0);
            pa11 = *(const u16x8*)(ga + k0 + 8);
        }
        pb10 = *(const u16x8*)(gb + k0);
        pb11 = *(const u16x8*)(gb + k0 + 8);
        if constexpr (DUAL) {
            const bf16* ms = msrc(k0);
            pm10 = *(const u16x8*)ms;
            pm11 = *(const u16x8*)(ms + 8);
        }
    };
    auto dep0 = [&](int buf) {
        if constexpr (__is_same(TA, float)) {
            u16x8 o0, o1;
            o0[0] = f2us(f00.x); o0[1] = f2us(f00.y); o0[2] = f2us(f00.z); o0[3] = f2us(f00.w);
            o0[4] = f2us(f01.x); o0[5] = f2us(f01.y); o0[6] = f2us(f01.z); o0[7] = f2us(f01.w);
            o1[0] = f2us(f02.x); o1[1] = f2us(f02.y); o1[2] = f2us(f02.z); o1[3] = f2us(f02.w);
            o1[4] = f2us(f03.x); o1[5] = f2us(f03.y); o1[6] = f2us(f03.z); o1[7] = f2us(f03.w);
            *(u16x8*)&As[buf][srow][sk]     = o0;
            *(u16x8*)&As[buf][srow][sk + 8] = o1;
        } else {
            *(u16x8*)&As[buf][srow][sk]     = pa00;
            *(u16x8*)&As[buf][srow][sk + 8] = pa01;
        }
        *(u16x8*)&Bs[buf][srow][sk]     = pb00;
        *(u16x8*)&Bs[buf][srow][sk + 8] = pb01;
        if constexpr (DUAL) {
            *(u16x8*)&Ms[buf][srow][sk]     = pm00;
            *(u16x8*)&Ms[buf][srow][sk + 8] = pm01;
        }
    };
    auto dep1 = [&](int buf) {
        if constexpr (__is_same(TA, float)) {
            u16x8 o0, o1;
            o0[0] = f2us(f10.x); o0[1] = f2us(f10.y); o0[2] = f2us(f10.z); o0[3] = f2us(f10.w);
            o0[4] = f2us(f11.x); o0[5] = f2us(f11.y); o0[6] = f2us(f11.z); o0[7] = f2us(f11.w);
            o1[0] = f2us(f12.x); o1[1] = f2us(f12.y); o1[2] = f2us(f12.z); o1[3] = f2us(f12.w);
            o1[4] = f2us(f13.x); o1[5] = f2us(f13.y); o1[6] = f2us(f13.z); o1[7] = f2us(f13.w);
            *(u16x8*)&As[buf][srow][sk]     = o0;
            *(u16x8*)&As[buf][srow][sk + 8] = o1;
        } else {
            *(u16x8*)&As[buf][srow][sk]     = pa10;
            *(u16x8*)&As[buf][srow][sk + 8] = pa11;
        }
        *(u16x8*)&Bs[buf][srow][sk]     = pb10;
        *(u16x8*)&Bs[buf][srow][sk + 8] = pb11;
        if constexpr (DUAL) {
            *(u16x8*)&Ms[buf][srow][sk]     = pm10;
            *(u16x8*)&Ms[buf][srow][sk + 8] = pm11;
        }
    };

    f32x16 acc;
    #pragma unroll
    for (int r = 0; r < 16; r++) acc[r] = 0.f;

    auto mfma_step = [&](int buf) {
        #pragma unroll
        for (int ks = 0; ks < 4; ks++) {
            s16x8 a = *(const s16x8*)&As[buf][wm + l31][ks * 16 + lhi * 8];
            s16x8 b = *(const s16x8*)&Bs[buf][wn + l31][ks * 16 + lhi * 8];
            acc = __builtin_amdgcn_mfma_f32_32x32x16_bf16(a, b, acc, 0, 0, 0);
            if constexpr (DUAL) {
                s16x8 m2 = *(const s16x8*)&Ms[buf][wm + l31][ks * 16 + lhi * 8];
                acc = __builtin_amdgcn_mfma_f32_32x32x16_bf16(m2, b, acc, 0, 0, 0);
            }
        }
    };

    const int NIT = (kEnd - kBeg) >> 6;
    // prologue over-reads stay inside live workspace regions; unused when
    // NIT is small.
    load0(kBeg);
    load1(kBeg + 64);
    dep0(0);
    __syncthreads();

    for (int k = 0; k < NIT; k += 2) {
        if (k + 2 < NIT) load0(kBeg + (k + 2) * 64);
        mfma_step(0);
        if (k + 1 < NIT) dep1(1);
        __syncthreads();
        if (k + 1 < NIT) {
            if (k + 3 < NIT) load1(kBeg + (k + 3) * 64);
            mfma_step(1);
            if (k + 2 < NIT) dep0(0);
            __syncthreads();
        }
    }

    #pragma unroll
    for (int r = 0; r < 16; r++) {
        int row = m0 + wm + (r & 3) + 8 * (r >> 2) + 4 * lhi;
        int col = n0 + wn + l31;
        C[(size_t)row * ldc + col] = acc[r];
    }
}

extern "C" void kernel_launch(void* const* d_in, const int* in_sizes, int n_in,
                              void* d_out, int out_size, void* d_ws, size_t ws_size,
                              hipStream_t stream) {
    const int*   idx   = (const int*)  d_in[0];
    const float* dec_x = (const float*)d_in[1];   // (NH, D, N)
    const float* dec_y = (const float*)d_in[2];   // (NH, D, N)
    const float* enc   = (const float*)d_in[3];   // (NH*N, D)
    const float* emb   = (const float*)d_in[4];   // (VOCAB, D)
    const float* pose  = (const float*)d_in[5];   // (BLOCK, D)
    const float* lmh   = (const float*)d_in[6];   // (D, VOCAB)
    float* out = (float*)d_out;                   // (T, VOCAB) fp32

    // workspace layout — identical to passing r11 (ws >= 84,377,600 proven)
    char* wp = (char*)d_ws;
    float*   x    = (float*)wp;              wp += (size_t)T_SEQ * D_DIM * 4;
    bf16*    xs   = (bf16*)wp;               wp += (size_t)T_SEQ * HN * 2;
    ushort2* csT  = (ushort2*)wp;            wp += (size_t)T_SEQ * NP2 * 4;
    bf16*    sc   = (bf16*)wp;               wp += (size_t)NHEAD * T_SEQ * T_SEQ * 2;
    float*   ykv  = (float*)wp;              wp += (size_t)NHEAD * T_SEQ * D_DIM * 4;
    float*   ymlp = (float*)wp;              wp += (size_t)T_SEQ * D_DIM * 4;   // dbuf home
    bf16*    xT   = (bf16*)wp;               wp += (size_t)D_DIM * T_SEQ * 2;
    bf16*    wX   = (bf16*)wp;               wp += (size_t)NHEAD * N_DIM * D_DIM * 2;
    bf16*    wY   = (bf16*)wp;               wp += (size_t)NHEAD * N_DIM * D_DIM * 2;
    bf16*    wE   = (bf16*)wp;               wp += (size_t)D_DIM * HN * 2;
    bf16*    wL   = (bf16*)wp;               wp += (size_t)VOCABSZ * D_DIM * 2;
    const size_t BASE_NEED = (size_t)(wp - (char*)d_ws);
    bf16*    qr   = (bf16*)wp;
    const size_t FULL_NEED = BASE_NEED + (size_t)T_SEQ * HN * 2;
    float* ymlpP = (float*)sc;     // 8 slabs x T*D x 4B overlay on dead sc region
    bf16*  dbuf  = (bf16*)ymlp;    // 512 KB diag partials on idle ymlp keeper
                                   // (must survive through ykv GEMM, so NOT on ykv)

    if (ws_size < BASE_NEED) {
        fill_out<<<(out_size + 255) / 256, 256, 0, stream>>>(out, (float)ws_size, out_size);
        return;
    }
    const bool USE_QR = (ws_size >= FULL_NEED);

    // weight mirrors (bf16, [n][k])
    t_cvt<<<dim3(48, 3, 4), 256, 0, stream>>>(dec_x, wX, D_DIM, N_DIM,
                                              (long)D_DIM * N_DIM, (long)N_DIM * D_DIM);
    t_cvt<<<dim3(48, 3, 4), 256, 0, stream>>>(dec_y, wY, D_DIM, N_DIM,
                                              (long)D_DIM * N_DIM, (long)N_DIM * D_DIM);
    t_cvt<<<dim3(3, 192, 1), 256, 0, stream>>>(enc, wE, HN, D_DIM, 0L, 0L);
    t_cvt<<<dim3(4, 3, 1), 256, 0, stream>>>(lmh, wL, D_DIM, VOCABSZ, 0L, 0L);

    k_tables<<<(T_SEQ * NP2) / 256, 256, 0, stream>>>(csT);
    k_embed<<<T_SEQ, 64, 0, stream>>>(idx, emb, pose, x);

    for (int l = 0; l < NLAYER; ++l) {
        // xT = x^T (bf16) for ykv's B operand
        t_cvt<<<dim3(3, 16, 1), 256, 0, stream>>>(x, xT, T_SEQ, D_DIM, 0L, 0L);
        // xs = relu(x @ dec_x)  (+ fused qr when available)
        if (USE_QR) {
            dgemm128<1, true><<<dim3(96, 8), 256, 0, stream>>>(x, wX, xs, qr, csT);
            scores64<<<dim3(136, 2, NHEAD), 256, 0, stream>>>(qr, sc, dbuf);
            // ykv = sc @ x  (causal, split-K=2; dual-A combines kh0/kh1
            // partials in fp32; slab1 on dead qr region)
            long segZ = (long)((float*)qr - ykv);
            mfma_gemm<bf16, 1><<<dim3(3, 16, NHEAD * 2), 256, 0, stream>>>(
                sc, xT, ykv, dbuf, T_SEQ, 0, T_SEQ, T_SEQ, D_DIM,
                (long)T_SEQ * T_SEQ, segZ, (long)T_SEQ * D_DIM);
            // ykv = LN(slab0 + slab1)
            k_ln2<<<NHEAD * T_SEQ, 64, 0, stream>>>(ykv, (const float*)qr);
        } else {
            dgemm128<1, false><<<dim3(96, 8), 256, 0, stream>>>(x, wX, xs, qr, csT);
            scores_fused<<<dim3(16, 16, NHEAD), 256, 0, stream>>>(xs, csT, sc);
            mfma_gemm<bf16, 3><<<dim3(3, 16, NHEAD), 256, 0, stream>>>(
                sc, xT, ykv, nullptr, T_SEQ, 0, T_SEQ, T_SEQ, D_DIM,
                (long)T_SEQ * T_SEQ, 0L, (long)T_SEQ * D_DIM);
            k_ln<<<NHEAD * T_SEQ, 64, 0, stream>>>(ykv);
        }
        // xs *= relu(ykv @ dec_y)   (gate; head slab picked inside kernel)
        dgemm128<2, false><<<dim3(96, 8), 256, 0, stream>>>(
            (const float*)ykv, wY, xs, nullptr, nullptr);
        // ymlp partials = xy @ enc   (split-K=8 -> slabs in sc region)
        mfma_gemm<bf16, 2><<<dim3(3, 16, 8), 256, 0, stream>>>(
            xs, wE, ymlpP, nullptr, HN, HN / 8, HN, HN, D_DIM,
            0L, 0L, (long)T_SEQ * D_DIM);
        // x = LN(x + LN(sum partials))
        k_resid8<<<T_SEQ, 64, 0, stream>>>(x, ymlpP);
    }

    // logits = x @ lm_head
    mfma_gemm<float, 0><<<dim3(4, 16, 1), 256, 0, stream>>>(
        x, wL, out, nullptr, D_DIM, 0, D_DIM, D_DIM, VOCABSZ, 0L, 0L, 0L);
}